// Round 1
// baseline (1778.094 us; speedup 1.0000x reference)
//
#include <hip/hip_runtime.h>
#include <math.h>

#define B_ 16
#define L_ 2048
#define D_ 256
#define N_ 64
#define NBLK_ 6
#define LC_ 128
#define NC_ 16
#define NGRP_ 256   // B * (D/16)

// ---------------- precompute per-layer SSM params ----------------
// w = exp(dt*A), C2 = 2*(Cre+iCim)*(w-1)/A, wL = w^LC (via exp(LC*dt*A))
__global__ void precompute_kernel(const float* __restrict__ log_dt,
                                  const float* __restrict__ logAre,
                                  const float* __restrict__ Aim,
                                  const float* __restrict__ Cre,
                                  const float* __restrict__ Cim,
                                  float* __restrict__ wbuf,
                                  float* __restrict__ c2buf,
                                  float* __restrict__ wlbuf) {
  int idx = blockIdx.x * blockDim.x + threadIdx.x;
  if (idx >= NBLK_ * D_ * N_) return;
  int blk = idx / (D_ * N_);
  int rem = idx - blk * (D_ * N_);
  int d = rem >> 6;
  float dt   = expf(log_dt[blk * D_ + d]);
  float are  = -expf(logAre[idx]);
  float aim  = Aim[idx];
  float dtar = dt * are, dtai = dt * aim;
  float er = expf(dtar);
  float wr = er * cosf(dtai);
  float wi = er * sinf(dtai);
  float inv = 1.0f / (are * are + aim * aim);
  float wm1r = wr - 1.0f;
  // (w-1)/A = (w-1)*conj(A)/|A|^2
  float br = (wm1r * are + wi * aim) * inv;
  float bi = (wi * are - wm1r * aim) * inv;
  float crv = Cre[idx], civ = Cim[idx];
  float c2r = 2.0f * (crv * br - civ * bi);
  float c2i = 2.0f * (crv * bi + civ * br);
  float eL = expf((float)LC_ * dtar);
  float angL = (float)LC_ * dtai;
  float wlr = eL * cosf(angL);
  float wli = eL * sinf(angL);
  wbuf[2 * idx] = wr;  wbuf[2 * idx + 1] = wi;
  c2buf[2 * idx] = c2r; c2buf[2 * idx + 1] = c2i;
  wlbuf[2 * idx] = wlr; wlbuf[2 * idx + 1] = wli;
}

// ---------------- embedding: h[b,l,d] = x[b,l]*W_emb[d] + b_emb[d] ----------
__global__ void embed_kernel(const float* __restrict__ x, const float* __restrict__ wemb,
                             const float* __restrict__ bemb, float* __restrict__ H) {
  int tid = blockIdx.x * blockDim.x + threadIdx.x;
  if (tid >= B_ * L_ * D_) return;
  int d = tid & (D_ - 1);
  int lg = tid >> 8;
  H[tid] = fmaf(x[lg], wemb[d], bemb[d]);
}

// ---------------- scan pass 1: per-chunk local final states (chunks 0..NC-2) --
// wave: 16 seqs (consecutive d of one b) x 4 sub-lanes x 16 complex states
__global__ __launch_bounds__(256) void scan_pass1(const float* __restrict__ hin,
    const float* __restrict__ gamma_, const float* __restrict__ beta_,
    const float* __restrict__ wbuf, float* __restrict__ sre, float* __restrict__ sim,
    int blk) {
  int wid = blockIdx.x * 4 + (threadIdx.x >> 6);
  int lane = threadIdx.x & 63;
  int s = lane & 15, sub = lane >> 4;
  int chunk = wid >> 8;        // 0..NC-2
  int group = wid & 255;
  int b = group >> 4;
  int d = ((group & 15) << 4) + s;
  float gd = gamma_[blk * D_ + d];
  float bd = beta_[blk * D_ + d];
  const float* wp = wbuf + (size_t)((blk * D_ + d) * N_ + (sub << 4)) * 2;
  float wr[16], wi[16], sr[16], si[16];
#pragma unroll
  for (int j = 0; j < 16; ++j) {
    wr[j] = wp[2 * j]; wi[j] = wp[2 * j + 1]; sr[j] = 0.f; si[j] = 0.f;
  }
  const float* hp = hin + ((b * L_ + chunk * LC_) * D_ + d);
  float cu0 = hp[0], cu1 = hp[D_], cu2 = hp[2 * D_], cu3 = hp[3 * D_];
  for (int l0 = 0; l0 < LC_; l0 += 4) {
    float nu0 = 0.f, nu1 = 0.f, nu2 = 0.f, nu3 = 0.f;
    if (l0 + 4 < LC_) {
      const float* q = hp + 4 * D_;
      nu0 = q[0]; nu1 = q[D_]; nu2 = q[2 * D_]; nu3 = q[3 * D_];
    }
    hp += 4 * D_;
    float us[4] = {cu0, cu1, cu2, cu3};
#pragma unroll
    for (int t = 0; t < 4; ++t) {
      float uu = fmaf(gd, us[t], bd);
#pragma unroll
      for (int j = 0; j < 16; ++j) {
        float nr = fmaf(wr[j], sr[j], uu);
        nr = fmaf(-wi[j], si[j], nr);
        si[j] = fmaf(wi[j], sr[j], wr[j] * si[j]);
        sr[j] = nr;
      }
    }
    cu0 = nu0; cu1 = nu1; cu2 = nu2; cu3 = nu3;
  }
  size_t base = ((size_t)(chunk * NGRP_ + group) * N_ + (sub << 4)) * 16 + s;
#pragma unroll
  for (int j = 0; j < 16; ++j) { sre[base + j * 16] = sr[j]; sim[base + j * 16] = si[j]; }
}

// ---------------- scan pass 2: in-place exclusive combine of chunk states ----
__global__ void scan_pass2(float* __restrict__ sre, float* __restrict__ sim,
                           const float* __restrict__ wlbuf, int blk) {
  int tid = blockIdx.x * blockDim.x + threadIdx.x;  // NGRP_*N_*16 = 262144
  int g = tid >> 10;
  int n = (tid >> 4) & 63;
  int s = tid & 15;
  int d = ((g & 15) << 4) + s;
  float wlr = wlbuf[(((blk * D_ + d) * N_) + n) * 2];
  float wli = wlbuf[(((blk * D_ + d) * N_) + n) * 2 + 1];
  float Sr = 0.f, Si = 0.f;
  for (int c = 0; c < NC_; ++c) {
    size_t a = ((size_t)(c * NGRP_ + g) * N_ + n) * 16 + s;
    float tr = 0.f, ti = 0.f;
    if (c < NC_ - 1) { tr = sre[a]; ti = sim[a]; }
    sre[a] = Sr; sim[a] = Si;          // state entering chunk c
    float nSr = fmaf(wlr, Sr, fmaf(-wli, Si, tr));
    Si = fmaf(wli, Sr, fmaf(wlr, Si, ti));
    Sr = nSr;
  }
}

// ---------------- scan pass 3: full scan per chunk, fused BN+Dskip+GELU ------
__global__ __launch_bounds__(256) void scan_pass3(const float* __restrict__ hin,
    const float* __restrict__ gamma_, const float* __restrict__ beta_,
    const float* __restrict__ dskip, const float* __restrict__ wbuf,
    const float* __restrict__ c2buf, const float* __restrict__ sre,
    const float* __restrict__ sim, float* __restrict__ gout, int blk) {
  int wid = blockIdx.x * 4 + (threadIdx.x >> 6);
  int lane = threadIdx.x & 63;
  int s = lane & 15, sub = lane >> 4;
  int chunk = wid >> 8;        // 0..NC-1
  int group = wid & 255;
  int b = group >> 4;
  int d = ((group & 15) << 4) + s;
  float gd = gamma_[blk * D_ + d], bd = beta_[blk * D_ + d];
  float dval = (sub == 0) ? dskip[blk * D_ + d] : 0.f;
  const float* wp = wbuf + (size_t)((blk * D_ + d) * N_ + (sub << 4)) * 2;
  const float* cp = c2buf + (size_t)((blk * D_ + d) * N_ + (sub << 4)) * 2;
  float wr[16], wi[16], cr[16], ci[16], sr[16], si[16];
  size_t sbase = ((size_t)(chunk * NGRP_ + group) * N_ + (sub << 4)) * 16 + s;
#pragma unroll
  for (int j = 0; j < 16; ++j) {
    wr[j] = wp[2 * j]; wi[j] = wp[2 * j + 1];
    cr[j] = cp[2 * j]; ci[j] = cp[2 * j + 1];
    sr[j] = sre[sbase + j * 16]; si[j] = sim[sbase + j * 16];
  }
  const float* hp = hin + ((b * L_ + chunk * LC_) * D_ + d);
  float* gp = gout + ((b * L_ + chunk * LC_) * D_ + d);
  float cu0 = hp[0], cu1 = hp[D_], cu2 = hp[2 * D_], cu3 = hp[3 * D_];
  for (int l0 = 0; l0 < LC_; l0 += 4) {
    float nu0 = 0.f, nu1 = 0.f, nu2 = 0.f, nu3 = 0.f;
    if (l0 + 4 < LC_) {
      const float* q = hp + 4 * D_;
      nu0 = q[0]; nu1 = q[D_]; nu2 = q[2 * D_]; nu3 = q[3 * D_];
    }
    hp += 4 * D_;
    float us[4] = {cu0, cu1, cu2, cu3};
#pragma unroll
    for (int t = 0; t < 4; ++t) {
      float uu = fmaf(gd, us[t], bd);
      float acc = dval * uu;
#pragma unroll
      for (int j = 0; j < 16; ++j) {
        float nr = fmaf(wr[j], sr[j], uu);
        nr = fmaf(-wi[j], si[j], nr);
        si[j] = fmaf(wi[j], sr[j], wr[j] * si[j]);
        sr[j] = nr;
        acc = fmaf(cr[j], sr[j], acc);
        acc = fmaf(-ci[j], si[j], acc);
      }
      acc += __shfl_xor(acc, 16);
      acc += __shfl_xor(acc, 32);
      // tanh-approx GELU (JAX default approximate=True)
      float xx = acc;
      float x3 = xx * xx * xx;
      float inner = 0.7978845608028654f * fmaf(0.044715f, x3, xx);
      float e = __expf(-2.f * fabsf(inner));
      float th = (1.f - e) / (1.f + e);
      th = copysignf(th, inner);
      float gv = 0.5f * xx * (1.f + th);
      if (sub == 0) gp[t * D_] = gv;
    }
    gp += 4 * D_;
    cu0 = nu0; cu1 = nu1; cu2 = nu2; cu3 = nu3;
  }
}

// ---------------- fp32 tiled GEMM: out = act(A@W + bias [+ res]) -------------
// A: [32768, 256] row-major, W: [256, 256] row-major. 128x128 tile, 8x8/thread.
__global__ __launch_bounds__(256) void gemm_kernel(const float* __restrict__ A,
    const float* __restrict__ W, const float* __restrict__ bias,
    const float* __restrict__ res, float* __restrict__ out, int do_relu) {
  __shared__ __align__(16) float As[8][132];
  __shared__ __align__(16) float Bs[8][132];
  int tid = threadIdx.x;
  int m0 = blockIdx.x * 128;
  int n0 = blockIdx.y * 128;
  int arow = tid >> 1;
  int acol = (tid & 1) << 2;
  int brow = tid >> 5;
  int bcol = (tid & 31) << 2;
  int tx = tid & 15, ty = tid >> 4;
  float acc[8][8];
#pragma unroll
  for (int i = 0; i < 8; i++)
#pragma unroll
    for (int j = 0; j < 8; j++) acc[i][j] = 0.f;

  for (int k0 = 0; k0 < D_; k0 += 8) {
    float4 av = *(const float4*)(A + (size_t)(m0 + arow) * D_ + k0 + acol);
    float4 bv = *(const float4*)(W + (size_t)(k0 + brow) * D_ + n0 + bcol);
    __syncthreads();
    As[acol + 0][arow] = av.x; As[acol + 1][arow] = av.y;
    As[acol + 2][arow] = av.z; As[acol + 3][arow] = av.w;
    *(float4*)&Bs[brow][bcol] = bv;
    __syncthreads();
#pragma unroll
    for (int k = 0; k < 8; ++k) {
      float a[8], b[8];
      *(float4*)&a[0] = *(const float4*)&As[k][ty * 8];
      *(float4*)&a[4] = *(const float4*)&As[k][ty * 8 + 4];
      *(float4*)&b[0] = *(const float4*)&Bs[k][tx * 8];
      *(float4*)&b[4] = *(const float4*)&Bs[k][tx * 8 + 4];
#pragma unroll
      for (int i = 0; i < 8; i++)
#pragma unroll
        for (int j = 0; j < 8; j++) acc[i][j] = fmaf(a[i], b[j], acc[i][j]);
    }
  }
#pragma unroll
  for (int i = 0; i < 8; i++) {
    int m = m0 + ty * 8 + i;
#pragma unroll
    for (int j = 0; j < 8; j++) {
      int n = n0 + tx * 8 + j;
      float v = acc[i][j] + bias[n];
      if (res) v += res[(size_t)m * D_ + n];
      if (do_relu) v = fmaxf(v, 0.f);
      out[(size_t)m * D_ + n] = v;
    }
  }
}

// ---------------- head: mean over L, then [D]x[D,2] ------------------------
__global__ void head1_kernel(const float* __restrict__ H, float* __restrict__ part) {
  int b = blockIdx.x, ls = blockIdx.y, d = threadIdx.x;
  const float* p = H + ((size_t)(b * L_ + ls * 128)) * D_ + d;
  float sum = 0.f;
  for (int l = 0; l < 128; ++l) sum += p[(size_t)l * D_];
  part[(b * 16 + ls) * D_ + d] = sum;
}

__global__ void head2_kernel(const float* __restrict__ part, const float* __restrict__ fcW,
                             const float* __restrict__ fcb, float* __restrict__ out) {
  int b = blockIdx.x, d = threadIdx.x;
  float sum = 0.f;
  for (int i = 0; i < 16; ++i) sum += part[(b * 16 + i) * D_ + d];
  __shared__ float meanv[D_];
  meanv[d] = sum * (1.0f / (float)L_);
  __syncthreads();
  if (d < 2) {
    float accv = fcb[d];
    for (int k = 0; k < D_; ++k) accv = fmaf(meanv[k], fcW[k * 2 + d], accv);
    out[b * 2 + d] = accv;
  }
}

extern "C" void kernel_launch(void* const* d_in, const int* in_sizes, int n_in,
                              void* d_out, int out_size, void* d_ws, size_t ws_size,
                              hipStream_t stream) {
  const float* x      = (const float*)d_in[0];
  const float* W_emb  = (const float*)d_in[1];
  const float* b_emb  = (const float*)d_in[2];
  const float* log_dt = (const float*)d_in[3];
  const float* logAre = (const float*)d_in[4];
  const float* Aim    = (const float*)d_in[5];
  const float* Cre    = (const float*)d_in[6];
  const float* Cim    = (const float*)d_in[7];
  const float* Dskip  = (const float*)d_in[8];
  const float* Wout   = (const float*)d_in[9];
  const float* bout   = (const float*)d_in[10];
  const float* gamma_ = (const float*)d_in[11];
  const float* beta_  = (const float*)d_in[12];
  const float* fW1    = (const float*)d_in[13];
  const float* fb1    = (const float*)d_in[14];
  const float* fW2    = (const float*)d_in[15];
  const float* fb2    = (const float*)d_in[16];
  const float* fcW    = (const float*)d_in[17];
  const float* fcb    = (const float*)d_in[18];
  float* outp = (float*)d_out;

  float* ws = (float*)d_ws;
  const size_t HSZ = (size_t)B_ * L_ * D_;   // 8388608 floats
  float* H   = ws;
  float* R   = H + HSZ;
  float* G   = R + HSZ;
  float* SRE = G + HSZ;
  float* SIM = SRE + HSZ / 2;
  float* WB  = SIM + HSZ / 2;
  float* C2B = WB + (size_t)NBLK_ * D_ * N_ * 2;
  float* WLB = C2B + (size_t)NBLK_ * D_ * N_ * 2;

  precompute_kernel<<<(NBLK_ * D_ * N_ + 255) / 256, 256, 0, stream>>>(
      log_dt, logAre, Aim, Cre, Cim, WB, C2B, WLB);
  embed_kernel<<<(B_ * L_ * D_ + 255) / 256, 256, 0, stream>>>(x, W_emb, b_emb, H);

  const float* hin_t[6]  = {H, H, H, H, R, H};
  float*       hout_t[6] = {H, H, H, R, H, H};
  for (int i = 0; i < 6; ++i) {
    const float* hin = hin_t[i];
    float* hout = hout_t[i];
    scan_pass1<<<(NC_ - 1) * NGRP_ / 4, 256, 0, stream>>>(hin, gamma_, beta_, WB, SRE, SIM, i);
    scan_pass2<<<(NGRP_ * N_ * 16) / 256, 256, 0, stream>>>(SRE, SIM, WLB, i);
    scan_pass3<<<NC_ * NGRP_ / 4, 256, 0, stream>>>(hin, gamma_, beta_, Dskip, WB, C2B,
                                                    SRE, SIM, G, i);
    gemm_kernel<<<dim3(B_ * L_ / 128, 2), 256, 0, stream>>>(
        G, Wout + (size_t)i * D_ * D_, bout + i * D_, hin, hout, 0);
  }
  // feedforward of the FS4Ddeq block + skip from R
  gemm_kernel<<<dim3(B_ * L_ / 128, 2), 256, 0, stream>>>(H, fW1, fb1, nullptr, G, 1);
  gemm_kernel<<<dim3(B_ * L_ / 128, 2), 256, 0, stream>>>(G, fW2, fb2, R, H, 1);
  head1_kernel<<<dim3(16, 16), 256, 0, stream>>>(H, G);
  head2_kernel<<<16, 256, 0, stream>>>(G, fcW, fcb, outp);
}

// Round 2
// 1727.076 us; speedup vs baseline: 1.0295x; 1.0295x over previous
//
#include <hip/hip_runtime.h>
#include <math.h>

#define B_ 16
#define L_ 2048
#define D_ 256
#define N_ 64
#define NBLK_ 6
#define LC_ 128
#define NC_ 16
#define NGRP_ 256   // B * (D/16)

typedef float f2 __attribute__((ext_vector_type(2)));

__device__ __forceinline__ f2 pk_fma(f2 a, f2 b, f2 c) {
  f2 d;
  asm("v_pk_fma_f32 %0, %1, %2, %3" : "=v"(d) : "v"(a), "v"(b), "v"(c));
  return d;
}
__device__ __forceinline__ f2 pk_mul(f2 a, f2 b) {
  f2 d;
  asm("v_pk_mul_f32 %0, %1, %2" : "=v"(d) : "v"(a), "v"(b));
  return d;
}

// ---------------- precompute per-layer SSM params ----------------
// Planar layout per (blk,d):
//   wbuf  stride 192: [0:64)=wr, [64:128)=wi, [128:192)=-wi
//   c2buf stride 128: [0:64)=c2r, [64:128)=c2i
//   wlbuf interleaved [idx][2] as before (pass2 scalar use)
__global__ void precompute_kernel(const float* __restrict__ log_dt,
                                  const float* __restrict__ logAre,
                                  const float* __restrict__ Aim,
                                  const float* __restrict__ Cre,
                                  const float* __restrict__ Cim,
                                  float* __restrict__ wbuf,
                                  float* __restrict__ c2buf,
                                  float* __restrict__ wlbuf) {
  int idx = blockIdx.x * blockDim.x + threadIdx.x;
  if (idx >= NBLK_ * D_ * N_) return;
  int blk = idx >> 14;            // /16384
  int rem = idx & 16383;
  int d = rem >> 6;
  int n = rem & 63;
  float dt   = expf(log_dt[blk * D_ + d]);
  float are  = -expf(logAre[idx]);
  float aim  = Aim[idx];
  float dtar = dt * are, dtai = dt * aim;
  float er = expf(dtar);
  float wr = er * cosf(dtai);
  float wi = er * sinf(dtai);
  float inv = 1.0f / (are * are + aim * aim);
  float wm1r = wr - 1.0f;
  // (w-1)/A = (w-1)*conj(A)/|A|^2
  float br = (wm1r * are + wi * aim) * inv;
  float bi = (wi * are - wm1r * aim) * inv;
  float crv = Cre[idx], civ = Cim[idx];
  float c2r = 2.0f * (crv * br - civ * bi);
  float c2i = 2.0f * (crv * bi + civ * br);
  float eL = expf((float)LC_ * dtar);
  float angL = (float)LC_ * dtai;
  float wlr = eL * cosf(angL);
  float wli = eL * sinf(angL);
  float* wb = wbuf + (size_t)((blk << 8) + d) * 192;
  wb[n] = wr; wb[64 + n] = wi; wb[128 + n] = -wi;
  float* cb = c2buf + (size_t)((blk << 8) + d) * 128;
  cb[n] = c2r; cb[64 + n] = c2i;
  wlbuf[2 * idx] = wlr; wlbuf[2 * idx + 1] = wli;
}

// ---------------- embedding: h[b,l,d] = x[b,l]*W_emb[d] + b_emb[d] ----------
__global__ void embed_kernel(const float* __restrict__ x, const float* __restrict__ wemb,
                             const float* __restrict__ bemb, float* __restrict__ H) {
  int tid = blockIdx.x * blockDim.x + threadIdx.x;
  if (tid >= B_ * L_ * D_) return;
  int d = tid & (D_ - 1);
  int lg = tid >> 8;
  H[tid] = fmaf(x[lg], wemb[d], bemb[d]);
}

// State buffer layout: a = (chunk*NGRP+group)*1024 + sub*256 + s*16 + j
// sim stores NEGATED imaginary part (si' = -si) throughout.

// ---------------- scan pass 1: per-chunk local final states (chunks 0..NC-2) --
// wave: 16 seqs (consecutive d of one b) x 4 sub-lanes x 16 complex states (8 packed pairs)
__global__ __launch_bounds__(256) void scan_pass1(const float* __restrict__ hin,
    const float* __restrict__ gamma_, const float* __restrict__ beta_,
    const float* __restrict__ wbuf, float* __restrict__ sre, float* __restrict__ sim,
    int blk) {
  int wid = blockIdx.x * 4 + (threadIdx.x >> 6);
  int lane = threadIdx.x & 63;
  int s = lane & 15, sub = lane >> 4;
  int chunk = wid >> 8;        // 0..NC-2
  int group = wid & 255;
  int b = group >> 4;
  int d = ((group & 15) << 4) + s;
  float gd = gamma_[blk * D_ + d];
  float bd = beta_[blk * D_ + d];
  const float* wp = wbuf + (size_t)((blk << 8) + d) * 192 + (sub << 4);
  f2 wrp[8], wip[8], mwip[8], srp[8], sjp[8];
#pragma unroll
  for (int j = 0; j < 8; ++j) {
    wrp[j]  = *(const f2*)(wp + 2 * j);
    wip[j]  = *(const f2*)(wp + 64 + 2 * j);
    mwip[j] = *(const f2*)(wp + 128 + 2 * j);
    srp[j] = (f2){0.f, 0.f}; sjp[j] = (f2){0.f, 0.f};
  }
  const float* hp = hin + ((b * L_ + chunk * LC_) * D_ + d);
  float cu0 = hp[0], cu1 = hp[D_], cu2 = hp[2 * D_], cu3 = hp[3 * D_];
  for (int l0 = 0; l0 < LC_; l0 += 4) {
    float nu0 = 0.f, nu1 = 0.f, nu2 = 0.f, nu3 = 0.f;
    if (l0 + 4 < LC_) {
      const float* q = hp + 4 * D_;
      nu0 = q[0]; nu1 = q[D_]; nu2 = q[2 * D_]; nu3 = q[3 * D_];
    }
    hp += 4 * D_;
    float us[4] = {cu0, cu1, cu2, cu3};
#pragma unroll
    for (int t = 0; t < 4; ++t) {
      float uu = fmaf(gd, us[t], bd);
      f2 uup; uup.x = uu; uup.y = uu;
#pragma unroll
      for (int j = 0; j < 8; ++j) {
        f2 nr = pk_fma(wrp[j], srp[j], uup);   // wr*sr + uu
        nr = pk_fma(wip[j], sjp[j], nr);       // + wi*si' (= -wi*si)
        f2 tt = pk_mul(wrp[j], sjp[j]);        // wr*si'
        sjp[j] = pk_fma(mwip[j], srp[j], tt);  // -wi*sr + wr*si'
        srp[j] = nr;
      }
    }
    cu0 = nu0; cu1 = nu1; cu2 = nu2; cu3 = nu3;
  }
  size_t base = (size_t)((chunk * NGRP_ + group) * 4 + sub) * 256 + s * 16;
#pragma unroll
  for (int j = 0; j < 8; ++j) {
    *(f2*)(sre + base + 2 * j) = srp[j];
    *(f2*)(sim + base + 2 * j) = sjp[j];
  }
}

// ---------------- scan pass 2: in-place exclusive combine of chunk states ----
// sim holds si' = -si; combine math done in the negated convention.
__global__ void scan_pass2(float* __restrict__ sre, float* __restrict__ sim,
                           const float* __restrict__ wlbuf, int blk) {
  int tid = blockIdx.x * blockDim.x + threadIdx.x;  // NGRP_*N_*16 = 262144
  int g = tid >> 10;
  int q = tid & 1023;           // sub*256 + s*16 + j
  int sub = q >> 8;
  int j = q & 15;
  int s = (q >> 4) & 15;
  int n = (sub << 4) + j;
  int d = ((g & 15) << 4) + s;
  float wlr = wlbuf[(((blk * D_ + d) * N_) + n) * 2];
  float wli = wlbuf[(((blk * D_ + d) * N_) + n) * 2 + 1];
  float Sr = 0.f, Sj = 0.f;   // Sj = -Si
  for (int c = 0; c < NC_; ++c) {
    size_t a = (size_t)(c * NGRP_ + g) * 1024 + q;
    float tr = 0.f, tj = 0.f;
    if (c < NC_ - 1) { tr = sre[a]; tj = sim[a]; }
    sre[a] = Sr; sim[a] = Sj;          // state entering chunk c
    float nSr = fmaf(wlr, Sr, fmaf(wli, Sj, tr));    // wlr*Sr - wli*Si + tr
    Sj = fmaf(-wli, Sr, fmaf(wlr, Sj, tj));          // -(wli*Sr + wlr*Si + ti)
    Sr = nSr;
  }
}

// ---------------- scan pass 3: full scan per chunk, fused BN+Dskip+GELU ------
__global__ __launch_bounds__(256) void scan_pass3(const float* __restrict__ hin,
    const float* __restrict__ gamma_, const float* __restrict__ beta_,
    const float* __restrict__ dskip, const float* __restrict__ wbuf,
    const float* __restrict__ c2buf, const float* __restrict__ sre,
    const float* __restrict__ sim, float* __restrict__ gout, int blk) {
  int wid = blockIdx.x * 4 + (threadIdx.x >> 6);
  int lane = threadIdx.x & 63;
  int s = lane & 15, sub = lane >> 4;
  int chunk = wid >> 8;        // 0..NC-1
  int group = wid & 255;
  int b = group >> 4;
  int d = ((group & 15) << 4) + s;
  float gd = gamma_[blk * D_ + d], bd = beta_[blk * D_ + d];
  float dval = (sub == 0) ? dskip[blk * D_ + d] : 0.f;
  const float* wp = wbuf + (size_t)((blk << 8) + d) * 192 + (sub << 4);
  const float* cp = c2buf + (size_t)((blk << 8) + d) * 128 + (sub << 4);
  f2 wrp[8], wip[8], mwip[8], crp[8], cip[8], srp[8], sjp[8];
  size_t sbase = (size_t)((chunk * NGRP_ + group) * 4 + sub) * 256 + s * 16;
#pragma unroll
  for (int j = 0; j < 8; ++j) {
    wrp[j]  = *(const f2*)(wp + 2 * j);
    wip[j]  = *(const f2*)(wp + 64 + 2 * j);
    mwip[j] = *(const f2*)(wp + 128 + 2 * j);
    crp[j]  = *(const f2*)(cp + 2 * j);
    cip[j]  = *(const f2*)(cp + 64 + 2 * j);
    srp[j] = *(const f2*)(sre + sbase + 2 * j);
    sjp[j] = *(const f2*)(sim + sbase + 2 * j);
  }
  const float* hp = hin + ((b * L_ + chunk * LC_) * D_ + d);
  float* gp = gout + ((b * L_ + chunk * LC_) * D_ + d);
  float cu0 = hp[0], cu1 = hp[D_], cu2 = hp[2 * D_], cu3 = hp[3 * D_];
  for (int l0 = 0; l0 < LC_; l0 += 4) {
    float nu0 = 0.f, nu1 = 0.f, nu2 = 0.f, nu3 = 0.f;
    if (l0 + 4 < LC_) {
      const float* q = hp + 4 * D_;
      nu0 = q[0]; nu1 = q[D_]; nu2 = q[2 * D_]; nu3 = q[3 * D_];
    }
    hp += 4 * D_;
    float us[4] = {cu0, cu1, cu2, cu3};
#pragma unroll
    for (int t = 0; t < 4; ++t) {
      float uu = fmaf(gd, us[t], bd);
      f2 uup; uup.x = uu; uup.y = uu;
      f2 accp; accp.x = dval * uu; accp.y = 0.f;
#pragma unroll
      for (int j = 0; j < 8; ++j) {
        f2 nr = pk_fma(wrp[j], srp[j], uup);   // wr*sr + uu
        nr = pk_fma(wip[j], sjp[j], nr);       // + wi*si'
        f2 tt = pk_mul(wrp[j], sjp[j]);        // wr*si'
        sjp[j] = pk_fma(mwip[j], srp[j], tt);  // -wi*sr + wr*si'
        srp[j] = nr;
        accp = pk_fma(crp[j], srp[j], accp);   // + cr*sr
        accp = pk_fma(cip[j], sjp[j], accp);   // + ci*si' (= -ci*si)
      }
      float acc = accp.x + accp.y;
      acc += __shfl_xor(acc, 16);
      acc += __shfl_xor(acc, 32);
      // tanh-approx GELU (JAX default approximate=True)
      float xx = acc;
      float x3 = xx * xx * xx;
      float inner = 0.7978845608028654f * fmaf(0.044715f, x3, xx);
      float e = __expf(-2.f * fabsf(inner));
      float th = (1.f - e) / (1.f + e);
      th = copysignf(th, inner);
      float gv = 0.5f * xx * (1.f + th);
      if (sub == 0) gp[t * D_] = gv;
    }
    gp += 4 * D_;
    cu0 = nu0; cu1 = nu1; cu2 = nu2; cu3 = nu3;
  }
}

// ---------------- fp32 tiled GEMM: out = act(A@W + bias [+ res]) -------------
// A: [32768, 256] row-major, W: [256, 256] row-major. 128x128 tile, 8x8/thread.
// Inner product packed: b in f2 pairs, a broadcast.
__global__ __launch_bounds__(256) void gemm_kernel(const float* __restrict__ A,
    const float* __restrict__ W, const float* __restrict__ bias,
    const float* __restrict__ res, float* __restrict__ out, int do_relu) {
  __shared__ __align__(16) float As[8][132];
  __shared__ __align__(16) float Bs[8][132];
  int tid = threadIdx.x;
  int m0 = blockIdx.x * 128;
  int n0 = blockIdx.y * 128;
  int arow = tid >> 1;
  int acol = (tid & 1) << 2;
  int brow = tid >> 5;
  int bcol = (tid & 31) << 2;
  int tx = tid & 15, ty = tid >> 4;
  f2 acc2[8][4];
#pragma unroll
  for (int i = 0; i < 8; i++)
#pragma unroll
    for (int j = 0; j < 4; j++) acc2[i][j] = (f2){0.f, 0.f};

  for (int k0 = 0; k0 < D_; k0 += 8) {
    float4 av = *(const float4*)(A + (size_t)(m0 + arow) * D_ + k0 + acol);
    float4 bv = *(const float4*)(W + (size_t)(k0 + brow) * D_ + n0 + bcol);
    __syncthreads();
    As[acol + 0][arow] = av.x; As[acol + 1][arow] = av.y;
    As[acol + 2][arow] = av.z; As[acol + 3][arow] = av.w;
    *(float4*)&Bs[brow][bcol] = bv;
    __syncthreads();
#pragma unroll
    for (int k = 0; k < 8; ++k) {
      float a8[8]; f2 b2[4];
      *(float4*)&a8[0] = *(const float4*)&As[k][ty * 8];
      *(float4*)&a8[4] = *(const float4*)&As[k][ty * 8 + 4];
      *(float4*)&b2[0] = *(const float4*)&Bs[k][tx * 8];
      *(float4*)&b2[2] = *(const float4*)&Bs[k][tx * 8 + 4];
#pragma unroll
      for (int i = 0; i < 8; i++) {
        f2 ai; ai.x = a8[i]; ai.y = a8[i];
#pragma unroll
        for (int j = 0; j < 4; j++) acc2[i][j] = pk_fma(ai, b2[j], acc2[i][j]);
      }
    }
  }
#pragma unroll
  for (int i = 0; i < 8; i++) {
    int m = m0 + ty * 8 + i;
#pragma unroll
    for (int j = 0; j < 4; j++) {
      int n = n0 + tx * 8 + 2 * j;
      float v0 = acc2[i][j].x + bias[n];
      float v1 = acc2[i][j].y + bias[n + 1];
      if (res) { v0 += res[(size_t)m * D_ + n]; v1 += res[(size_t)m * D_ + n + 1]; }
      if (do_relu) { v0 = fmaxf(v0, 0.f); v1 = fmaxf(v1, 0.f); }
      out[(size_t)m * D_ + n] = v0;
      out[(size_t)m * D_ + n + 1] = v1;
    }
  }
}

// ---------------- head: mean over L, then [D]x[D,2] ------------------------
__global__ void head1_kernel(const float* __restrict__ H, float* __restrict__ part) {
  int b = blockIdx.x, ls = blockIdx.y, d = threadIdx.x;
  const float* p = H + ((size_t)(b * L_ + ls * 128)) * D_ + d;
  float sum = 0.f;
  for (int l = 0; l < 128; ++l) sum += p[(size_t)l * D_];
  part[(b * 16 + ls) * D_ + d] = sum;
}

__global__ void head2_kernel(const float* __restrict__ part, const float* __restrict__ fcW,
                             const float* __restrict__ fcb, float* __restrict__ out) {
  int b = blockIdx.x, d = threadIdx.x;
  float sum = 0.f;
  for (int i = 0; i < 16; ++i) sum += part[(b * 16 + i) * D_ + d];
  __shared__ float meanv[D_];
  meanv[d] = sum * (1.0f / (float)L_);
  __syncthreads();
  if (d < 2) {
    float accv = fcb[d];
    for (int k = 0; k < D_; ++k) accv = fmaf(meanv[k], fcW[k * 2 + d], accv);
    out[b * 2 + d] = accv;
  }
}

extern "C" void kernel_launch(void* const* d_in, const int* in_sizes, int n_in,
                              void* d_out, int out_size, void* d_ws, size_t ws_size,
                              hipStream_t stream) {
  const float* x      = (const float*)d_in[0];
  const float* W_emb  = (const float*)d_in[1];
  const float* b_emb  = (const float*)d_in[2];
  const float* log_dt = (const float*)d_in[3];
  const float* logAre = (const float*)d_in[4];
  const float* Aim    = (const float*)d_in[5];
  const float* Cre    = (const float*)d_in[6];
  const float* Cim    = (const float*)d_in[7];
  const float* Dskip  = (const float*)d_in[8];
  const float* Wout   = (const float*)d_in[9];
  const float* bout   = (const float*)d_in[10];
  const float* gamma_ = (const float*)d_in[11];
  const float* beta_  = (const float*)d_in[12];
  const float* fW1    = (const float*)d_in[13];
  const float* fb1    = (const float*)d_in[14];
  const float* fW2    = (const float*)d_in[15];
  const float* fb2    = (const float*)d_in[16];
  const float* fcW    = (const float*)d_in[17];
  const float* fcb    = (const float*)d_in[18];
  float* outp = (float*)d_out;

  float* ws = (float*)d_ws;
  const size_t HSZ = (size_t)B_ * L_ * D_;   // 8388608 floats
  float* H   = ws;
  float* R   = H + HSZ;
  float* G   = R + HSZ;
  float* SRE = G + HSZ;
  float* SIM = SRE + (size_t)NC_ * NGRP_ * 1024;
  float* WB  = SIM + (size_t)NC_ * NGRP_ * 1024;
  float* C2B = WB + (size_t)NBLK_ * D_ * 192;
  float* WLB = C2B + (size_t)NBLK_ * D_ * 128;

  precompute_kernel<<<(NBLK_ * D_ * N_ + 255) / 256, 256, 0, stream>>>(
      log_dt, logAre, Aim, Cre, Cim, WB, C2B, WLB);
  embed_kernel<<<(B_ * L_ * D_ + 255) / 256, 256, 0, stream>>>(x, W_emb, b_emb, H);

  const float* hin_t[6]  = {H, H, H, H, R, H};
  float*       hout_t[6] = {H, H, H, R, H, H};
  for (int i = 0; i < 6; ++i) {
    const float* hin = hin_t[i];
    float* hout = hout_t[i];
    scan_pass1<<<(NC_ - 1) * NGRP_ / 4, 256, 0, stream>>>(hin, gamma_, beta_, WB, SRE, SIM, i);
    scan_pass2<<<(NGRP_ * N_ * 16) / 256, 256, 0, stream>>>(SRE, SIM, WLB, i);
    scan_pass3<<<NC_ * NGRP_ / 4, 256, 0, stream>>>(hin, gamma_, beta_, Dskip, WB, C2B,
                                                    SRE, SIM, G, i);
    gemm_kernel<<<dim3(B_ * L_ / 128, 2), 256, 0, stream>>>(
        G, Wout + (size_t)i * D_ * D_, bout + i * D_, hin, hout, 0);
  }
  // feedforward of the FS4Ddeq block + skip from R
  gemm_kernel<<<dim3(B_ * L_ / 128, 2), 256, 0, stream>>>(H, fW1, fb1, nullptr, G, 1);
  gemm_kernel<<<dim3(B_ * L_ / 128, 2), 256, 0, stream>>>(G, fW2, fb2, R, H, 1);
  head1_kernel<<<dim3(16, 16), 256, 0, stream>>>(H, G);
  head2_kernel<<<16, 256, 0, stream>>>(G, fcW, fcb, outp);
}

// Round 3
// 1362.920 us; speedup vs baseline: 1.3046x; 1.2672x over previous
//
#include <hip/hip_runtime.h>
#include <hip/hip_bf16.h>
#include <math.h>

#define B_ 16
#define L_ 2048
#define D_ 256
#define N_ 64
#define NBLK_ 6
#define LC_ 128
#define NC_ 16
#define NGRP_ 256   // B * (D/16)

typedef float f2 __attribute__((ext_vector_type(2)));
typedef short short8 __attribute__((ext_vector_type(8)));
typedef float f32x4 __attribute__((ext_vector_type(4)));

__device__ __forceinline__ f2 pk_fma(f2 a, f2 b, f2 c) {
  f2 d;
  asm("v_pk_fma_f32 %0, %1, %2, %3" : "=v"(d) : "v"(a), "v"(b), "v"(c));
  return d;
}
__device__ __forceinline__ f2 pk_mul(f2 a, f2 b) {
  f2 d;
  asm("v_pk_mul_f32 %0, %1, %2" : "=v"(d) : "v"(a), "v"(b));
  return d;
}
__device__ __forceinline__ unsigned short f2bf(float f) {
  unsigned int u = __float_as_uint(f);
  u += 0x7fffu + ((u >> 16) & 1u);
  return (unsigned short)(u >> 16);
}

// ---------------- precompute per-layer SSM params ----------------
// wbuf  stride 192 per (blk,d): [0:64)=wr, [64:128)=wi, [128:192)=-wi
// c2buf stride 128: [0:64)=c2r, [64:128)=c2i ;  wlbuf interleaved [idx][2]
__global__ void precompute_kernel(const float* __restrict__ log_dt,
                                  const float* __restrict__ logAre,
                                  const float* __restrict__ Aim,
                                  const float* __restrict__ Cre,
                                  const float* __restrict__ Cim,
                                  float* __restrict__ wbuf,
                                  float* __restrict__ c2buf,
                                  float* __restrict__ wlbuf) {
  int idx = blockIdx.x * blockDim.x + threadIdx.x;
  if (idx >= NBLK_ * D_ * N_) return;
  int blk = idx >> 14;
  int rem = idx & 16383;
  int d = rem >> 6;
  int n = rem & 63;
  float dt   = expf(log_dt[blk * D_ + d]);
  float are  = -expf(logAre[idx]);
  float aim  = Aim[idx];
  float dtar = dt * are, dtai = dt * aim;
  float er = expf(dtar);
  float wr = er * cosf(dtai);
  float wi = er * sinf(dtai);
  float inv = 1.0f / (are * are + aim * aim);
  float wm1r = wr - 1.0f;
  float br = (wm1r * are + wi * aim) * inv;
  float bi = (wi * are - wm1r * aim) * inv;
  float crv = Cre[idx], civ = Cim[idx];
  float c2r = 2.0f * (crv * br - civ * bi);
  float c2i = 2.0f * (crv * bi + civ * br);
  float eL = expf((float)LC_ * dtar);
  float angL = (float)LC_ * dtai;
  float wlr = eL * cosf(angL);
  float wli = eL * sinf(angL);
  float* wb = wbuf + (size_t)((blk << 8) + d) * 192;
  wb[n] = wr; wb[64 + n] = wi; wb[128 + n] = -wi;
  float* cb = c2buf + (size_t)((blk << 8) + d) * 128;
  cb[n] = c2r; cb[64 + n] = c2i;
  wlbuf[2 * idx] = wlr; wlbuf[2 * idx + 1] = wli;
}

// ---------------- embedding ----------
__global__ void embed_kernel(const float* __restrict__ x, const float* __restrict__ wemb,
                             const float* __restrict__ bemb, float* __restrict__ H) {
  int tid = blockIdx.x * blockDim.x + threadIdx.x;
  if (tid >= B_ * L_ * D_) return;
  int d = tid & (D_ - 1);
  int lg = tid >> 8;
  H[tid] = fmaf(x[lg], wemb[d], bemb[d]);
}

// State buffer layout: a = (chunk*NGRP+group)*1024 + sub*256 + s*16 + j
// sim stores NEGATED imaginary part (si' = -si) throughout.

// ---------------- scan pass 1: per-chunk local final states (chunks 0..NC-2) --
// block = (chunk, b, dblk of 64 d); 4 waves; wave w: d = dblk*64 + w*16 + s,
// 4 sublanes x 16 complex states each. u staged via LDS (32-step dbuf tiles).
__global__ __launch_bounds__(256, 4) void scan_pass1(const float* __restrict__ hin,
    const float* __restrict__ gamma_, const float* __restrict__ beta_,
    const float* __restrict__ wbuf, float* __restrict__ sre, float* __restrict__ sim,
    int blk) {
  __shared__ float ub[2][32 * 64];
  int bi = blockIdx.x;
  int chunk = bi >> 6;          // 0..14
  int b = (bi >> 2) & 15;
  int dblk = bi & 3;
  int tid = threadIdx.x;
  int w = tid >> 6;
  int lane = tid & 63;
  int s = lane & 15, sub = lane >> 4;
  int d = (dblk << 6) + (w << 4) + s;
  int group = (b << 4) + (dblk << 2) + w;
  float gd = gamma_[blk * D_ + d];
  float bd = beta_[blk * D_ + d];
  const float* wp = wbuf + (size_t)((blk << 8) + d) * 192 + (sub << 4);
  f2 wrp[8], wip[8], mwip[8], srp[8], sjp[8];
#pragma unroll
  for (int j = 0; j < 8; ++j) {
    wrp[j]  = *(const f2*)(wp + 2 * j);
    wip[j]  = *(const f2*)(wp + 64 + 2 * j);
    mwip[j] = *(const f2*)(wp + 128 + 2 * j);
    srp[j] = (f2){0.f, 0.f}; sjp[j] = (f2){0.f, 0.f};
  }
  const float* src = hin + (size_t)(b * L_ + chunk * LC_) * D_ + (dblk << 6);
  int r0 = tid >> 3, c0 = (tid & 7) << 3;
  const float* lsrc = src + r0 * D_ + c0;
  float4 p0 = *(const float4*)(lsrc);
  float4 p1 = *(const float4*)(lsrc + 4);
  *(float4*)&ub[0][r0 * 64 + c0] = p0;
  *(float4*)&ub[0][r0 * 64 + c0 + 4] = p1;
  __syncthreads();
  int dloc = (w << 4) + s;
  for (int T = 0; T < 4; ++T) {
    if (T < 3) {
      const float* ns = src + (size_t)(T + 1) * 32 * D_ + r0 * D_ + c0;
      p0 = *(const float4*)(ns);
      p1 = *(const float4*)(ns + 4);
    }
    const float* ubuf = ub[T & 1];
    for (int t0 = 0; t0 < 32; t0 += 4) {
      float u4[4];
#pragma unroll
      for (int q = 0; q < 4; ++q) u4[q] = ubuf[(t0 + q) * 64 + dloc];
#pragma unroll
      for (int q = 0; q < 4; ++q) {
        float uu = fmaf(gd, u4[q], bd);
        f2 uup; uup.x = uu; uup.y = uu;
#pragma unroll
        for (int j = 0; j < 8; ++j) {
          f2 nr = pk_fma(wrp[j], srp[j], uup);
          nr = pk_fma(wip[j], sjp[j], nr);
          f2 tt = pk_mul(wrp[j], sjp[j]);
          sjp[j] = pk_fma(mwip[j], srp[j], tt);
          srp[j] = nr;
        }
      }
    }
    if (T < 3) {
      int nb = (T + 1) & 1;
      *(float4*)&ub[nb][r0 * 64 + c0] = p0;
      *(float4*)&ub[nb][r0 * 64 + c0 + 4] = p1;
      __syncthreads();
    }
  }
  size_t base = (size_t)((chunk * NGRP_ + group) * 4 + sub) * 256 + s * 16;
#pragma unroll
  for (int j = 0; j < 8; ++j) {
    *(f2*)(sre + base + 2 * j) = srp[j];
    *(f2*)(sim + base + 2 * j) = sjp[j];
  }
}

// ---------------- scan pass 2: exclusive combine of chunk states ----
__global__ void scan_pass2(float* __restrict__ sre, float* __restrict__ sim,
                           const float* __restrict__ wlbuf, int blk) {
  int tid = blockIdx.x * blockDim.x + threadIdx.x;  // 262144
  int g = tid >> 10;
  int q = tid & 1023;
  int sub = q >> 8;
  int j = q & 15;
  int s = (q >> 4) & 15;
  int n = (sub << 4) + j;
  int d = ((g & 15) << 4) + s;
  float wlr = wlbuf[(((blk * D_ + d) * N_) + n) * 2];
  float wli = wlbuf[(((blk * D_ + d) * N_) + n) * 2 + 1];
  float Sr = 0.f, Sj = 0.f;
  for (int c = 0; c < NC_; ++c) {
    size_t a = (size_t)(c * NGRP_ + g) * 1024 + q;
    float tr = 0.f, tj = 0.f;
    if (c < NC_ - 1) { tr = sre[a]; tj = sim[a]; }
    sre[a] = Sr; sim[a] = Sj;
    float nSr = fmaf(wlr, Sr, fmaf(wli, Sj, tr));
    Sj = fmaf(-wli, Sr, fmaf(wlr, Sj, tj));
    Sr = nSr;
  }
}

// ---------------- scan pass 3: full scan, fused BN+Dskip+GELU, bf16 out ------
__global__ __launch_bounds__(256, 3) void scan_pass3(const float* __restrict__ hin,
    const float* __restrict__ gamma_, const float* __restrict__ beta_,
    const float* __restrict__ dskip, const float* __restrict__ wbuf,
    const float* __restrict__ c2buf, const float* __restrict__ sre,
    const float* __restrict__ sim, unsigned short* __restrict__ gout_bf, int blk) {
  __shared__ float ub[2][32 * 64];
  int bi = blockIdx.x;
  int chunk = bi >> 6;          // 0..15
  int b = (bi >> 2) & 15;
  int dblk = bi & 3;
  int tid = threadIdx.x;
  int w = tid >> 6;
  int lane = tid & 63;
  int s = lane & 15, sub = lane >> 4;
  int d = (dblk << 6) + (w << 4) + s;
  int group = (b << 4) + (dblk << 2) + w;
  float gd = gamma_[blk * D_ + d], bd = beta_[blk * D_ + d];
  float dval = (sub == 0) ? dskip[blk * D_ + d] : 0.f;
  const float* wp = wbuf + (size_t)((blk << 8) + d) * 192 + (sub << 4);
  const float* cp = c2buf + (size_t)((blk << 8) + d) * 128 + (sub << 4);
  f2 wrp[8], wip[8], mwip[8], crp[8], cip[8], srp[8], sjp[8];
  size_t sbase = (size_t)((chunk * NGRP_ + group) * 4 + sub) * 256 + s * 16;
#pragma unroll
  for (int j = 0; j < 8; ++j) {
    wrp[j]  = *(const f2*)(wp + 2 * j);
    wip[j]  = *(const f2*)(wp + 64 + 2 * j);
    mwip[j] = *(const f2*)(wp + 128 + 2 * j);
    crp[j]  = *(const f2*)(cp + 2 * j);
    cip[j]  = *(const f2*)(cp + 64 + 2 * j);
    srp[j] = *(const f2*)(sre + sbase + 2 * j);
    sjp[j] = *(const f2*)(sim + sbase + 2 * j);
  }
  const float* src = hin + (size_t)(b * L_ + chunk * LC_) * D_ + (dblk << 6);
  int r0 = tid >> 3, c0 = (tid & 7) << 3;
  const float* lsrc = src + r0 * D_ + c0;
  float4 p0 = *(const float4*)(lsrc);
  float4 p1 = *(const float4*)(lsrc + 4);
  *(float4*)&ub[0][r0 * 64 + c0] = p0;
  *(float4*)&ub[0][r0 * 64 + c0 + 4] = p1;
  __syncthreads();
  int dloc = (w << 4) + s;
  unsigned short* gp = gout_bf + (size_t)(b * L_ + chunk * LC_) * D_ + d;
  for (int T = 0; T < 4; ++T) {
    if (T < 3) {
      const float* ns = src + (size_t)(T + 1) * 32 * D_ + r0 * D_ + c0;
      p0 = *(const float4*)(ns);
      p1 = *(const float4*)(ns + 4);
    }
    const float* ubuf = ub[T & 1];
    for (int t0 = 0; t0 < 32; t0 += 4) {
      float u4[4];
#pragma unroll
      for (int q = 0; q < 4; ++q) u4[q] = ubuf[(t0 + q) * 64 + dloc];
#pragma unroll
      for (int q = 0; q < 4; ++q) {
        float uu = fmaf(gd, u4[q], bd);
        f2 uup; uup.x = uu; uup.y = uu;
        f2 accp; accp.x = dval * uu; accp.y = 0.f;
#pragma unroll
        for (int j = 0; j < 8; ++j) {
          f2 nr = pk_fma(wrp[j], srp[j], uup);
          nr = pk_fma(wip[j], sjp[j], nr);
          f2 tt = pk_mul(wrp[j], sjp[j]);
          sjp[j] = pk_fma(mwip[j], srp[j], tt);
          srp[j] = nr;
          accp = pk_fma(crp[j], srp[j], accp);
          accp = pk_fma(cip[j], sjp[j], accp);
        }
        float acc = accp.x + accp.y;
        acc += __shfl_xor(acc, 16);
        acc += __shfl_xor(acc, 32);
        float xx = acc;
        float x3 = xx * xx * xx;
        float inner = 0.7978845608028654f * fmaf(0.044715f, x3, xx);
        float e = __expf(-2.f * fabsf(inner));
        float th = (1.f - e) / (1.f + e);
        th = copysignf(th, inner);
        float gv = 0.5f * xx * (1.f + th);
        if (sub == 0) gp[(size_t)(T * 32 + t0 + q) * D_] = f2bf(gv);
      }
    }
    if (T < 3) {
      int nb = (T + 1) & 1;
      *(float4*)&ub[nb][r0 * 64 + c0] = p0;
      *(float4*)&ub[nb][r0 * 64 + c0 + 4] = p1;
      __syncthreads();
    }
  }
}

// ---------------- W prep: WT[w][n][k] = W_w[k][n] as bf16 --------------------
__global__ void wprep_kernel(const float* __restrict__ Wout, const float* __restrict__ fW1,
                             const float* __restrict__ fW2, unsigned short* __restrict__ WT) {
  __shared__ float tile[64][65];
  int wv = blockIdx.x >> 4;
  int tk = (blockIdx.x >> 2) & 3;
  int tn = blockIdx.x & 3;
  const float* src = (wv < 6) ? (Wout + (size_t)wv * 65536) : (wv == 6 ? fW1 : fW2);
  int r = threadIdx.x >> 4;
  int c = (threadIdx.x & 15) << 2;
  for (int rr = 0; rr < 64; rr += 16) {
    float4 v = *(const float4*)(src + (size_t)(tk * 64 + r + rr) * 256 + tn * 64 + c);
    tile[r + rr][c] = v.x; tile[r + rr][c + 1] = v.y;
    tile[r + rr][c + 2] = v.z; tile[r + rr][c + 3] = v.w;
  }
  __syncthreads();
  for (int rr = 0; rr < 64; rr += 16) {
    int n = r + rr;
    ushort4 o;
    o.x = f2bf(tile[c + 0][n]); o.y = f2bf(tile[c + 1][n]);
    o.z = f2bf(tile[c + 2][n]); o.w = f2bf(tile[c + 3][n]);
    *(ushort4*)(WT + (size_t)wv * 65536 + (size_t)(tn * 64 + n) * 256 + tk * 64 + c) = o;
  }
}

// ---------------- bf16 MFMA GEMM: out = act(A@W + bias [+ res]) --------------
// A: [32768,256] bf16 row-major; WT: [256 n][256 k] bf16; 128x128 tile.
__global__ __launch_bounds__(256, 2) void gemm_bf16(const unsigned short* __restrict__ A,
    const unsigned short* __restrict__ Wt, const float* __restrict__ bias,
    const float* __restrict__ res, float* __restrict__ outf,
    unsigned short* __restrict__ outbf, int do_relu) {
  __shared__ unsigned short As[128][72];
  __shared__ unsigned short Bs[128][72];
  int tid = threadIdx.x;
  int m0 = blockIdx.x * 128, n0 = blockIdx.y * 128;
  int lane = tid & 63, w = tid >> 6;
  int wm = (w & 1) << 6, wn = (w >> 1) << 6;
  int r0 = tid >> 3;          // 0..31
  int c0 = (tid & 7) << 3;    // 0..56
  f32x4 acc[4][4];
#pragma unroll
  for (int mf = 0; mf < 4; ++mf)
#pragma unroll
    for (int nf = 0; nf < 4; ++nf) acc[mf][nf] = (f32x4){0.f, 0.f, 0.f, 0.f};

  for (int kb = 0; kb < 4; ++kb) {
    int k0 = kb << 6;
    __syncthreads();
#pragma unroll
    for (int rr = 0; rr < 4; ++rr) {
      int r = r0 + rr * 32;
      uint4 av = *(const uint4*)(A + (size_t)(m0 + r) * 256 + k0 + c0);
      uint4 bv = *(const uint4*)(Wt + (size_t)(n0 + r) * 256 + k0 + c0);
      *(uint4*)&As[r][c0] = av;
      *(uint4*)&Bs[r][c0] = bv;
    }
    __syncthreads();
#pragma unroll
    for (int kw = 0; kw < 2; ++kw) {
      int ko = (kw << 5) + ((lane >> 4) << 3);
      short8 af[4], bfr[4];
#pragma unroll
      for (int mf = 0; mf < 4; ++mf)
        af[mf] = *(const short8*)&As[wm + (mf << 4) + (lane & 15)][ko];
#pragma unroll
      for (int nf = 0; nf < 4; ++nf)
        bfr[nf] = *(const short8*)&Bs[wn + (nf << 4) + (lane & 15)][ko];
#pragma unroll
      for (int mf = 0; mf < 4; ++mf)
#pragma unroll
        for (int nf = 0; nf < 4; ++nf)
          acc[mf][nf] = __builtin_amdgcn_mfma_f32_16x16x32_bf16(af[mf], bfr[nf], acc[mf][nf], 0, 0, 0);
    }
  }
  int cn = lane & 15, rq = lane >> 4;
#pragma unroll
  for (int mf = 0; mf < 4; ++mf) {
#pragma unroll
    for (int nf = 0; nf < 4; ++nf) {
      int n = n0 + wn + (nf << 4) + cn;
      float bv = bias[n];
#pragma unroll
      for (int r = 0; r < 4; ++r) {
        int m = m0 + wm + (mf << 4) + (rq << 2) + r;
        float v = acc[mf][nf][r] + bv;
        if (res) v += res[(size_t)m * 256 + n];
        if (do_relu) v = fmaxf(v, 0.f);
        if (outf) outf[(size_t)m * 256 + n] = v;
        if (outbf) outbf[(size_t)m * 256 + n] = f2bf(v);
      }
    }
  }
}

// ---------------- head ------------------------
__global__ void head1_kernel(const float* __restrict__ H, float* __restrict__ part) {
  int b = blockIdx.x, ls = blockIdx.y, d = threadIdx.x;
  const float* p = H + ((size_t)(b * L_ + ls * 128)) * D_ + d;
  float sum = 0.f;
  for (int l = 0; l < 128; ++l) sum += p[(size_t)l * D_];
  part[(b * 16 + ls) * D_ + d] = sum;
}

__global__ void head2_kernel(const float* __restrict__ part, const float* __restrict__ fcW,
                             const float* __restrict__ fcb, float* __restrict__ out) {
  int b = blockIdx.x, d = threadIdx.x;
  float sum = 0.f;
  for (int i = 0; i < 16; ++i) sum += part[(b * 16 + i) * D_ + d];
  __shared__ float meanv[D_];
  meanv[d] = sum * (1.0f / (float)L_);
  __syncthreads();
  if (d < 2) {
    float accv = fcb[d];
    for (int k = 0; k < D_; ++k) accv = fmaf(meanv[k], fcW[k * 2 + d], accv);
    out[b * 2 + d] = accv;
  }
}

extern "C" void kernel_launch(void* const* d_in, const int* in_sizes, int n_in,
                              void* d_out, int out_size, void* d_ws, size_t ws_size,
                              hipStream_t stream) {
  const float* x      = (const float*)d_in[0];
  const float* W_emb  = (const float*)d_in[1];
  const float* b_emb  = (const float*)d_in[2];
  const float* log_dt = (const float*)d_in[3];
  const float* logAre = (const float*)d_in[4];
  const float* Aim    = (const float*)d_in[5];
  const float* Cre    = (const float*)d_in[6];
  const float* Cim    = (const float*)d_in[7];
  const float* Dskip  = (const float*)d_in[8];
  const float* Wout   = (const float*)d_in[9];
  const float* bout   = (const float*)d_in[10];
  const float* gamma_ = (const float*)d_in[11];
  const float* beta_  = (const float*)d_in[12];
  const float* fW1    = (const float*)d_in[13];
  const float* fb1    = (const float*)d_in[14];
  const float* fW2    = (const float*)d_in[15];
  const float* fb2    = (const float*)d_in[16];
  const float* fcW    = (const float*)d_in[17];
  const float* fcb    = (const float*)d_in[18];
  float* outp = (float*)d_out;

  float* ws = (float*)d_ws;
  const size_t HSZ = (size_t)B_ * L_ * D_;   // 8388608
  float* H   = ws;
  float* R   = H + HSZ;
  float* SRE = R + HSZ;
  float* SIM = SRE + (size_t)NC_ * NGRP_ * 1024;
  float* WB  = SIM + (size_t)NC_ * NGRP_ * 1024;
  float* C2B = WB + (size_t)NBLK_ * D_ * 192;
  float* WLB = C2B + (size_t)NBLK_ * D_ * 128;
  unsigned short* Gbf = (unsigned short*)(WLB + (size_t)NBLK_ * D_ * N_ * 2);
  unsigned short* Hbf = Gbf + HSZ;
  unsigned short* WT  = Hbf + HSZ;

  precompute_kernel<<<(NBLK_ * D_ * N_ + 255) / 256, 256, 0, stream>>>(
      log_dt, logAre, Aim, Cre, Cim, WB, C2B, WLB);
  wprep_kernel<<<128, 256, 0, stream>>>(Wout, fW1, fW2, WT);
  embed_kernel<<<(B_ * L_ * D_ + 255) / 256, 256, 0, stream>>>(x, W_emb, b_emb, H);

  const float* hin_t[6]  = {H, H, H, H, R, H};
  float*       hout_t[6] = {H, H, H, R, H, H};
  for (int i = 0; i < 6; ++i) {
    const float* hin = hin_t[i];
    float* hout = hout_t[i];
    scan_pass1<<<(NC_ - 1) * 64, 256, 0, stream>>>(hin, gamma_, beta_, WB, SRE, SIM, i);
    scan_pass2<<<(NGRP_ * N_ * 16) / 256, 256, 0, stream>>>(SRE, SIM, WLB, i);
    scan_pass3<<<NC_ * 64, 256, 0, stream>>>(hin, gamma_, beta_, Dskip, WB, C2B,
                                             SRE, SIM, Gbf, i);
    gemm_bf16<<<dim3(B_ * L_ / 128, 2), 256, 0, stream>>>(
        Gbf, WT + (size_t)i * 65536, bout + i * D_, hin, hout,
        (i == 5) ? Hbf : nullptr, 0);
  }
  // feedforward of the FS4Ddeq block + skip from R
  gemm_bf16<<<dim3(B_ * L_ / 128, 2), 256, 0, stream>>>(
      Hbf, WT + (size_t)6 * 65536, fb1, nullptr, nullptr, Gbf, 1);
  gemm_bf16<<<dim3(B_ * L_ / 128, 2), 256, 0, stream>>>(
      Gbf, WT + (size_t)7 * 65536, fb2, R, H, nullptr, 1);
  head1_kernel<<<dim3(16, 16), 256, 0, stream>>>(H, SRE);
  head2_kernel<<<16, 256, 0, stream>>>(SRE, fcW, fcb, outp);
}

// Round 5
// 1063.936 us; speedup vs baseline: 1.6712x; 1.2810x over previous
//
#include <hip/hip_runtime.h>
#include <hip/hip_bf16.h>
#include <hip/hip_fp16.h>
#include <math.h>

#define B_ 16
#define L_ 2048
#define D_ 256
#define N_ 64
#define NBLK_ 6
#define LC_ 128
#define NC_ 16

typedef _Float16 half8 __attribute__((ext_vector_type(8)));
typedef float f32x4 __attribute__((ext_vector_type(4)));
typedef short short8 __attribute__((ext_vector_type(8)));

__device__ __forceinline__ unsigned short f2bf(float f) {
  unsigned int u = __float_as_uint(f);
  u += 0x7fffu + ((u >> 16) & 1u);
  return (unsigned short)(u >> 16);
}
__device__ __forceinline__ unsigned short f2h(float f) {
  _Float16 h = (_Float16)f;
  return *(unsigned short*)&h;
}
__device__ __forceinline__ float h2f(unsigned short u) {
  _Float16 h = *(_Float16*)&u;
  return (float)h;
}

// ---------------- precompute per-layer SSM params ----------------
// wbuf  stride 128 per (blk,d): [0:64)=wr, [64:128)=wi
// c2buf stride 128: [0:64)=c2r, [64:128)=c2i ;  wlbuf interleaved [blk*D+d][n][2]
__global__ void precompute_kernel(const float* __restrict__ log_dt,
                                  const float* __restrict__ logAre,
                                  const float* __restrict__ Aim,
                                  const float* __restrict__ Cre,
                                  const float* __restrict__ Cim,
                                  float* __restrict__ wbuf,
                                  float* __restrict__ c2buf,
                                  float* __restrict__ wlbuf) {
  int idx = blockIdx.x * blockDim.x + threadIdx.x;
  if (idx >= NBLK_ * D_ * N_) return;
  int blk = idx >> 14;
  int rem = idx & 16383;
  int d = rem >> 6;
  int n = rem & 63;
  float dt   = expf(log_dt[blk * D_ + d]);
  float are  = -expf(logAre[idx]);
  float aim  = Aim[idx];
  float dtar = dt * are, dtai = dt * aim;
  float er = expf(dtar);
  float wr = er * cosf(dtai);
  float wi = er * sinf(dtai);
  float inv = 1.0f / (are * are + aim * aim);
  float wm1r = wr - 1.0f;
  float br = (wm1r * are + wi * aim) * inv;
  float bi = (wi * are - wm1r * aim) * inv;
  float crv = Cre[idx], civ = Cim[idx];
  float c2r = 2.0f * (crv * br - civ * bi);
  float c2i = 2.0f * (crv * bi + civ * br);
  float eL = expf((float)LC_ * dtar);
  float angL = (float)LC_ * dtai;
  float wlr = eL * cosf(angL);
  float wli = eL * sinf(angL);
  float* wb = wbuf + (size_t)((blk << 8) + d) * 128;
  wb[n] = wr; wb[64 + n] = wi;
  float* cb = c2buf + (size_t)((blk << 8) + d) * 128;
  cb[n] = c2r; cb[64 + n] = c2i;
  wlbuf[2 * idx] = wlr; wlbuf[2 * idx + 1] = wli;
}

// ---------------- per-layer matrix build -------------------------------------
// Tn[d][t][tau] = fp16(gamma_d * Ktilde[t-tau]) (tau<=t), Ktilde[0] includes Dskip
// En[d][t][n]   = fp16(Re(c2 w^{t+1})),  En[d][t][64+n] = fp16(Im(c2 w^{t+1}))
// Fn[d][n][tau] = fp16(gamma*Re(w^{127-tau})), Fn[d][64+n][tau] = fp16(-gamma*Im(...))
// Pbeta[d][t] = beta*prefixsum(Ktilde), Sbeta[d][n2] = beta*(w^128-1)/(w-1) comps
__global__ __launch_bounds__(128) void build_kernel(
    const float* __restrict__ wbuf, const float* __restrict__ c2buf,
    const float* __restrict__ wlbuf,
    const float* __restrict__ gamma_, const float* __restrict__ beta_,
    const float* __restrict__ dskip,
    unsigned short* __restrict__ Tn, unsigned short* __restrict__ En,
    unsigned short* __restrict__ Fn, float* __restrict__ Pbeta,
    float* __restrict__ Sbeta, int blk) {
  __shared__ float Ksh[128];
  int d = blockIdx.x;
  int j = threadIdx.x;   // 0..127
  const float* wp = wbuf + (size_t)((blk << 8) + d) * 128;
  const float* cp = c2buf + (size_t)((blk << 8) + d) * 128;
  float gd = gamma_[blk * D_ + d], bd = beta_[blk * D_ + d], dsk = dskip[blk * D_ + d];
  float Kj = 0.f;
  for (int n = 0; n < 64; ++n) {
    float wr = wp[n], wi = wp[64 + n];
    float c2r = cp[n], c2i = cp[64 + n];
    // w^j by binary pow (fp32)
    float pr = 1.f, pi = 0.f, br2 = wr, bi2 = wi;
    int e = j;
    while (e) {
      if (e & 1) { float t = pr * br2 - pi * bi2; pi = pr * bi2 + pi * br2; pr = t; }
      float t2 = br2 * br2 - bi2 * bi2; bi2 = 2.f * br2 * bi2; br2 = t2;
      e >>= 1;
    }
    Kj += c2r * pr - c2i * pi;
    float qr = pr * wr - pi * wi, qi = pr * wi + pi * wr;   // w^{j+1}
    En[((size_t)d * 128 + j) * 128 + n]      = f2h(c2r * qr - c2i * qi);
    En[((size_t)d * 128 + j) * 128 + 64 + n] = f2h(c2r * qi + c2i * qr);
    Fn[((size_t)d * 128 + n) * 128 + (127 - j)]      = f2h(gd * pr);
    Fn[((size_t)d * 128 + 64 + n) * 128 + (127 - j)] = f2h(-gd * pi);
  }
  Ksh[j] = Kj + (j == 0 ? dsk : 0.f);
  __syncthreads();
  float ps = 0.f;
  for (int t2 = 0; t2 <= j; ++t2) ps += Ksh[t2];
  Pbeta[d * 128 + j] = bd * ps;
  unsigned short* tr = Tn + ((size_t)d * 128 + j) * 128;
  for (int tau = 0; tau < 128; ++tau)
    tr[tau] = (tau <= j) ? f2h(gd * Ksh[j - tau]) : (unsigned short)0;
  if (j < 64) {
    int n = j;
    float wr = wp[n], wi = wp[64 + n];
    const float* wlp = wlbuf + (((size_t)((blk << 8) + d)) * 64 + n) * 2;
    float wlr = wlp[0], wli = wlp[1];
    float nr = wlr - 1.f, ni = wli;
    float dr = wr - 1.f, di = wi;
    float iv = 1.f / (dr * dr + di * di);
    float Srr = (nr * dr + ni * di) * iv;
    float Sii = (ni * dr - nr * di) * iv;
    Sbeta[d * 128 + n]      = bd * Srr;
    Sbeta[d * 128 + 64 + n] = bd * (-Sii);
  }
}

// ---------------- embedding ----------
__global__ void embed_kernel(const float* __restrict__ x, const float* __restrict__ wemb,
                             const float* __restrict__ bemb, float* __restrict__ H) {
  int tid = blockIdx.x * blockDim.x + threadIdx.x;
  if (tid >= B_ * L_ * D_) return;
  int d = tid & (D_ - 1);
  int lg = tid >> 8;
  H[tid] = fmaf(x[lg], wemb[d], bemb[d]);
}

// ---------------- transpose H [b][l][d] fp32 -> UT [d][bc][tau] fp16 ---------
__global__ __launch_bounds__(256) void trans_h_ut(const float* __restrict__ H,
                                                  unsigned short* __restrict__ UT) {
  __shared__ __align__(16) unsigned short lds[64][136];
  int bi = blockIdx.x;          // bc*4 + dq
  int bc = bi >> 2, dq = bi & 3;
  int b = bc >> 4, ch = bc & 15;
  int tid = threadIdx.x;
  const float* src = H + ((size_t)(b * L_ + ch * 128)) * D_ + dq * 64;
  int tau0 = tid >> 4;          // 0..15
  int dl = (tid & 15) << 2;
  for (int tt = 0; tt < 128; tt += 16) {
    float4 v = *(const float4*)(src + (size_t)(tt + tau0) * D_ + dl);
    lds[dl + 0][tt + tau0] = f2h(v.x);
    lds[dl + 1][tt + tau0] = f2h(v.y);
    lds[dl + 2][tt + tau0] = f2h(v.z);
    lds[dl + 3][tt + tau0] = f2h(v.w);
  }
  __syncthreads();
  int r = tid >> 2, seg = (tid & 3) << 5;   // r 0..63, seg 0/32/64/96
  unsigned short* dst = UT + ((size_t)((dq * 64 + r) * 256 + bc)) * 128 + seg;
  const unsigned short* srow = &lds[r][seg];
  *(uint4*)(dst + 0)  = *(const uint4*)(srow + 0);
  *(uint4*)(dst + 8)  = *(const uint4*)(srow + 8);
  *(uint4*)(dst + 16) = *(const uint4*)(srow + 16);
  *(uint4*)(dst + 24) = *(const uint4*)(srow + 24);
}

// ---------------- scanA: SL[d][bc][n2] = fp16(UT[d] @ Fn[d]^T + Sbeta) -------
__global__ __launch_bounds__(256) void scan_gemm_state(
    const unsigned short* __restrict__ UT, const unsigned short* __restrict__ Fn,
    const float* __restrict__ Sbeta, unsigned short* __restrict__ SL) {
  __shared__ __align__(16) _Float16 As[128][40];
  __shared__ __align__(16) _Float16 Bs[128][40];
  int bx = blockIdx.x;
  int d = bx >> 1, mh = bx & 1;
  int tid = threadIdx.x, lane = tid & 63, w = tid >> 6;
  int wm = (w & 1) << 6, wn = (w >> 1) << 6;
  const unsigned short* Abase = UT + ((size_t)d * 256 + mh * 128) * 128;
  const unsigned short* Bbase = Fn + (size_t)d * 16384;
  f32x4 acc[4][4];
#pragma unroll
  for (int a = 0; a < 4; ++a)
#pragma unroll
    for (int b2 = 0; b2 < 4; ++b2) acc[a][b2] = (f32x4){0.f, 0.f, 0.f, 0.f};
  int r = tid & 127, sg = (tid >> 7) << 4;
  for (int kc = 0; kc < 128; kc += 32) {
    __syncthreads();
    const uint4* pa = (const uint4*)(Abase + (size_t)r * 128 + kc + sg);
    uint4 a0 = pa[0], a1 = pa[1];
    const uint4* pb = (const uint4*)(Bbase + (size_t)r * 128 + kc + sg);
    uint4 b0 = pb[0], b1 = pb[1];
    *(uint4*)&As[r][sg] = a0; *(uint4*)&As[r][sg + 8] = a1;
    *(uint4*)&Bs[r][sg] = b0; *(uint4*)&Bs[r][sg + 8] = b1;
    __syncthreads();
    int ko = (lane >> 4) << 3;
    half8 af[4], bf4[4];
#pragma unroll
    for (int mf = 0; mf < 4; ++mf) af[mf] = *(const half8*)&As[wm + (mf << 4) + (lane & 15)][ko];
#pragma unroll
    for (int nf = 0; nf < 4; ++nf) bf4[nf] = *(const half8*)&Bs[wn + (nf << 4) + (lane & 15)][ko];
#pragma unroll
    for (int mf = 0; mf < 4; ++mf)
#pragma unroll
      for (int nf = 0; nf < 4; ++nf)
        acc[mf][nf] = __builtin_amdgcn_mfma_f32_16x16x32_f16(af[mf], bf4[nf], acc[mf][nf], 0, 0, 0);
  }
  int cn = lane & 15, rq = lane >> 4;
#pragma unroll
  for (int nf = 0; nf < 4; ++nf) {
    int n = wn + (nf << 4) + cn;
    float sb = Sbeta[d * 128 + n];
#pragma unroll
    for (int mf = 0; mf < 4; ++mf)
#pragma unroll
      for (int rr = 0; rr < 4; ++rr) {
        int m = mh * 128 + wm + (mf << 4) + (rq << 2) + rr;
        SL[((size_t)d * 256 + m) * 128 + n] = f2h(acc[mf][nf][rr] + sb);
      }
  }
}

// ---------------- pass2: in-place exclusive chunk-state combine --------------
__global__ void pass2_kernel(unsigned short* __restrict__ SL,
                             const float* __restrict__ wlbuf, int blk) {
  int tid = blockIdx.x * blockDim.x + threadIdx.x;  // 262144
  int d = tid >> 10, rest = tid & 1023, b = rest >> 6, n = rest & 63;
  const float* wlp = wlbuf + (((size_t)((blk << 8) + d)) * 64 + n) * 2;
  float wlr = wlp[0], wli = wlp[1];
  float Sr = 0.f, Sj = 0.f;   // Sj = -Si (negated-imag convention)
  for (int c = 0; c < NC_; ++c) {
    size_t base = ((size_t)d * 256 + b * 16 + c) * 128;
    float tr2 = h2f(SL[base + n]);
    float tj  = h2f(SL[base + 64 + n]);
    SL[base + n]      = f2h(Sr);          // state ENTERING chunk c
    SL[base + 64 + n] = f2h(Sj);
    float nSr = fmaf(wlr, Sr, fmaf(wli, Sj, tr2));
    Sj = fmaf(-wli, Sr, fmaf(wlr, Sj, tj));
    Sr = nSr;
  }
}

// ---------------- scanB: GT[d][bc][t] = gelu(UT@Tn^T + SL@En^T + Pbeta) ------
__global__ __launch_bounds__(256) void scan_gemm_out(
    const unsigned short* __restrict__ UT, const unsigned short* __restrict__ Sin,
    const unsigned short* __restrict__ Tn, const unsigned short* __restrict__ En,
    const float* __restrict__ Pbeta, unsigned short* __restrict__ GT) {
  __shared__ __align__(16) _Float16 As[128][40];
  __shared__ __align__(16) _Float16 Bs[128][40];
  int bx = blockIdx.x;
  int d = bx >> 1, mh = bx & 1;
  int tid = threadIdx.x, lane = tid & 63, w = tid >> 6;
  int wm = (w & 1) << 6, wn = (w >> 1) << 6;
  f32x4 acc[4][4];
#pragma unroll
  for (int a = 0; a < 4; ++a)
#pragma unroll
    for (int b2 = 0; b2 < 4; ++b2) acc[a][b2] = (f32x4){0.f, 0.f, 0.f, 0.f};
  int r = tid & 127, sg = (tid >> 7) << 4;
  for (int kb = 0; kb < 8; ++kb) {
    int kc = (kb & 3) << 5;
    const unsigned short* Abase = ((kb < 4) ? UT : Sin) + ((size_t)d * 256 + mh * 128) * 128 + kc;
    const unsigned short* Bbase = ((kb < 4) ? Tn : En) + (size_t)d * 16384 + kc;
    __syncthreads();
    const uint4* pa = (const uint4*)(Abase + (size_t)r * 128 + sg);
    uint4 a0 = pa[0], a1 = pa[1];
    const uint4* pb = (const uint4*)(Bbase + (size_t)r * 128 + sg);
    uint4 b0 = pb[0], b1 = pb[1];
    *(uint4*)&As[r][sg] = a0; *(uint4*)&As[r][sg + 8] = a1;
    *(uint4*)&Bs[r][sg] = b0; *(uint4*)&Bs[r][sg + 8] = b1;
    __syncthreads();
    int ko = (lane >> 4) << 3;
    half8 af[4], bf4[4];
#pragma unroll
    for (int mf = 0; mf < 4; ++mf) af[mf] = *(const half8*)&As[wm + (mf << 4) + (lane & 15)][ko];
#pragma unroll
    for (int nf = 0; nf < 4; ++nf) bf4[nf] = *(const half8*)&Bs[wn + (nf << 4) + (lane & 15)][ko];
#pragma unroll
    for (int mf = 0; mf < 4; ++mf)
#pragma unroll
      for (int nf = 0; nf < 4; ++nf)
        acc[mf][nf] = __builtin_amdgcn_mfma_f32_16x16x32_f16(af[mf], bf4[nf], acc[mf][nf], 0, 0, 0);
  }
  int cn = lane & 15, rq = lane >> 4;
#pragma unroll
  for (int nf = 0; nf < 4; ++nf) {
    int n = wn + (nf << 4) + cn;
    float pb2 = Pbeta[d * 128 + n];
#pragma unroll
    for (int mf = 0; mf < 4; ++mf)
#pragma unroll
      for (int rr = 0; rr < 4; ++rr) {
        int m = mh * 128 + wm + (mf << 4) + (rq << 2) + rr;
        float xx = acc[mf][nf][rr] + pb2;
        float x3 = xx * xx * xx;
        float inner = 0.7978845608028654f * fmaf(0.044715f, x3, xx);
        float e = __expf(-2.f * fabsf(inner));
        float th = (1.f - e) / (1.f + e);
        th = copysignf(th, inner);
        float gv = 0.5f * xx * (1.f + th);
        GT[((size_t)d * 256 + m) * 128 + n] = f2bf(gv);
      }
  }
}

// ---------------- transpose GT [d][bc][t] bf16 -> G [b*l][d] bf16 ------------
__global__ __launch_bounds__(256) void trans_gt_g(const unsigned short* __restrict__ GT,
                                                  unsigned short* __restrict__ G) {
  __shared__ __align__(16) unsigned short lds[128][72];
  int bi = blockIdx.x;
  int bc = bi >> 2, dq = bi & 3;
  int tid = threadIdx.x;
  int r = tid >> 2, seg = (tid & 3) << 5;
  const unsigned short* srow = GT + ((size_t)((dq * 64 + r) * 256 + bc)) * 128 + seg;
  uint4 v[4];
  v[0] = *(const uint4*)(srow + 0);
  v[1] = *(const uint4*)(srow + 8);
  v[2] = *(const uint4*)(srow + 16);
  v[3] = *(const uint4*)(srow + 24);
  const unsigned short* pv = (const unsigned short*)v;
#pragma unroll
  for (int i = 0; i < 32; ++i) lds[seg + i][r] = pv[i];
  __syncthreads();
  int t = tid >> 1, hf = (tid & 1) << 5;
  unsigned short* dst = G + ((size_t)(bc * 128 + t)) * D_ + dq * 64 + hf;
  const unsigned short* lrow = &lds[t][hf];
  *(uint4*)(dst + 0)  = *(const uint4*)(lrow + 0);
  *(uint4*)(dst + 8)  = *(const uint4*)(lrow + 8);
  *(uint4*)(dst + 16) = *(const uint4*)(lrow + 16);
  *(uint4*)(dst + 24) = *(const uint4*)(lrow + 24);
}

// ---------------- W prep: WT[w][n][k] = W_w[k][n] as bf16 --------------------
__global__ void wprep_kernel(const float* __restrict__ Wout, const float* __restrict__ fW1,
                             const float* __restrict__ fW2, unsigned short* __restrict__ WT) {
  __shared__ float tile[64][65];
  int wv = blockIdx.x >> 4;
  int tk = (blockIdx.x >> 2) & 3;
  int tn = blockIdx.x & 3;
  const float* src = (wv < 6) ? (Wout + (size_t)wv * 65536) : (wv == 6 ? fW1 : fW2);
  int r = threadIdx.x >> 4;
  int c = (threadIdx.x & 15) << 2;
  for (int rr = 0; rr < 64; rr += 16) {
    float4 v = *(const float4*)(src + (size_t)(tk * 64 + r + rr) * 256 + tn * 64 + c);
    tile[r + rr][c] = v.x; tile[r + rr][c + 1] = v.y;
    tile[r + rr][c + 2] = v.z; tile[r + rr][c + 3] = v.w;
  }
  __syncthreads();
  for (int rr = 0; rr < 64; rr += 16) {
    int n = r + rr;
    ushort4 o;
    o.x = f2bf(tile[c + 0][n]); o.y = f2bf(tile[c + 1][n]);
    o.z = f2bf(tile[c + 2][n]); o.w = f2bf(tile[c + 3][n]);
    *(ushort4*)(WT + (size_t)wv * 65536 + (size_t)(tn * 64 + n) * 256 + tk * 64 + c) = o;
  }
}

// ---------------- bf16 MFMA GEMM: out = act(A@W + bias [+ res]) --------------
__global__ __launch_bounds__(256, 2) void gemm_bf16(const unsigned short* __restrict__ A,
    const unsigned short* __restrict__ Wt, const float* __restrict__ bias,
    const float* __restrict__ res, float* __restrict__ outf,
    unsigned short* __restrict__ outbf, int do_relu) {
  __shared__ __align__(16) unsigned short As[128][72];
  __shared__ __align__(16) unsigned short Bs[128][72];
  int tid = threadIdx.x;
  int m0 = blockIdx.x * 128, n0 = blockIdx.y * 128;
  int lane = tid & 63, w = tid >> 6;
  int wm = (w & 1) << 6, wn = (w >> 1) << 6;
  int r0 = tid >> 3;
  int c0 = (tid & 7) << 3;
  f32x4 acc[4][4];
#pragma unroll
  for (int mf = 0; mf < 4; ++mf)
#pragma unroll
    for (int nf = 0; nf < 4; ++nf) acc[mf][nf] = (f32x4){0.f, 0.f, 0.f, 0.f};

  for (int kb = 0; kb < 4; ++kb) {
    int k0 = kb << 6;
    __syncthreads();
#pragma unroll
    for (int rr = 0; rr < 4; ++rr) {
      int r = r0 + rr * 32;
      uint4 av = *(const uint4*)(A + (size_t)(m0 + r) * 256 + k0 + c0);
      uint4 bv = *(const uint4*)(Wt + (size_t)(n0 + r) * 256 + k0 + c0);
      *(uint4*)&As[r][c0] = av;
      *(uint4*)&Bs[r][c0] = bv;
    }
    __syncthreads();
#pragma unroll
    for (int kw = 0; kw < 2; ++kw) {
      int ko = (kw << 5) + ((lane >> 4) << 3);
      short8 af[4], bfr[4];
#pragma unroll
      for (int mf = 0; mf < 4; ++mf)
        af[mf] = *(const short8*)&As[wm + (mf << 4) + (lane & 15)][ko];
#pragma unroll
      for (int nf = 0; nf < 4; ++nf)
        bfr[nf] = *(const short8*)&Bs[wn + (nf << 4) + (lane & 15)][ko];
#pragma unroll
      for (int mf = 0; mf < 4; ++mf)
#pragma unroll
        for (int nf = 0; nf < 4; ++nf)
          acc[mf][nf] = __builtin_amdgcn_mfma_f32_16x16x32_bf16(af[mf], bfr[nf], acc[mf][nf], 0, 0, 0);
    }
  }
  int cn = lane & 15, rq = lane >> 4;
#pragma unroll
  for (int mf = 0; mf < 4; ++mf) {
#pragma unroll
    for (int nf = 0; nf < 4; ++nf) {
      int n = n0 + wn + (nf << 4) + cn;
      float bv = bias[n];
#pragma unroll
      for (int r = 0; r < 4; ++r) {
        int m = m0 + wm + (mf << 4) + (rq << 2) + r;
        float v = acc[mf][nf][r] + bv;
        if (res) v += res[(size_t)m * 256 + n];
        if (do_relu) v = fmaxf(v, 0.f);
        if (outf) outf[(size_t)m * 256 + n] = v;
        if (outbf) outbf[(size_t)m * 256 + n] = f2bf(v);
      }
    }
  }
}

// ---------------- head ------------------------
__global__ void head1_kernel(const float* __restrict__ H, float* __restrict__ part) {
  int b = blockIdx.x, ls = blockIdx.y, d = threadIdx.x;
  const float* p = H + ((size_t)(b * L_ + ls * 128)) * D_ + d;
  float sum = 0.f;
  for (int l = 0; l < 128; ++l) sum += p[(size_t)l * D_];
  part[(b * 16 + ls) * D_ + d] = sum;
}

__global__ void head2_kernel(const float* __restrict__ part, const float* __restrict__ fcW,
                             const float* __restrict__ fcb, float* __restrict__ out) {
  int b = blockIdx.x, d = threadIdx.x;
  float sum = 0.f;
  for (int i = 0; i < 16; ++i) sum += part[(b * 16 + i) * D_ + d];
  __shared__ float meanv[D_];
  meanv[d] = sum * (1.0f / (float)L_);
  __syncthreads();
  if (d < 2) {
    float accv = fcb[d];
    for (int k = 0; k < D_; ++k) accv = fmaf(meanv[k], fcW[k * 2 + d], accv);
    out[b * 2 + d] = accv;
  }
}

extern "C" void kernel_launch(void* const* d_in, const int* in_sizes, int n_in,
                              void* d_out, int out_size, void* d_ws, size_t ws_size,
                              hipStream_t stream) {
  const float* x      = (const float*)d_in[0];
  const float* W_emb  = (const float*)d_in[1];
  const float* b_emb  = (const float*)d_in[2];
  const float* log_dt = (const float*)d_in[3];
  const float* logAre = (const float*)d_in[4];
  const float* Aim    = (const float*)d_in[5];
  const float* Cre    = (const float*)d_in[6];
  const float* Cim    = (const float*)d_in[7];
  const float* Dskip  = (const float*)d_in[8];
  const float* Wout   = (const float*)d_in[9];
  const float* bout   = (const float*)d_in[10];
  const float* gamma_ = (const float*)d_in[11];
  const float* beta_  = (const float*)d_in[12];
  const float* fW1    = (const float*)d_in[13];
  const float* fb1    = (const float*)d_in[14];
  const float* fW2    = (const float*)d_in[15];
  const float* fb2    = (const float*)d_in[16];
  const float* fcW    = (const float*)d_in[17];
  const float* fcb    = (const float*)d_in[18];
  float* outp = (float*)d_out;

  float* ws = (float*)d_ws;
  const size_t HSZ = (size_t)B_ * L_ * D_;   // 8388608
  // ---- workspace layout (total ~137.9 MB) ----
  float* H     = ws;                                   // 8388608 f
  float* R     = H + HSZ;                              // 8388608 f
  float* WB    = R + HSZ;                              // 196608 f
  float* C2B   = WB + (size_t)NBLK_ * D_ * 128;        // 196608 f
  float* WLB   = C2B + (size_t)NBLK_ * D_ * 128;       // 196608 f
  float* Pbeta = WLB + (size_t)NBLK_ * D_ * N_ * 2;    // 32768 f
  float* Sbeta = Pbeta + 32768;                        // 32768 f
  unsigned short* UT  = (unsigned short*)(Sbeta + 32768);  // 8388608 us
  unsigned short* Hbf = UT;        // alias: UT dead (after scanB L5) before Hbf written
  unsigned short* SL  = UT + HSZ;                      // 8388608 us (local/entering states fp16)
  unsigned short* Gbf = SL;        // alias: SL dead (after scanB) before Gbf written
  unsigned short* Tn  = SL + HSZ;                      // 4194304 us
  unsigned short* En  = Tn + (size_t)4194304;          // 4194304 us
  unsigned short* GT  = En + (size_t)4194304;          // 8388608 us (FULL size!)
  unsigned short* Fn  = GT;        // alias: Fn (4.19M, scanA input) = first half of GT;
                                   // GT written by scanB strictly after scanA reads Fn
  unsigned short* WT  = GT + HSZ;                      // 524288 us

  precompute_kernel<<<(NBLK_ * D_ * N_ + 255) / 256, 256, 0, stream>>>(
      log_dt, logAre, Aim, Cre, Cim, WB, C2B, WLB);
  wprep_kernel<<<128, 256, 0, stream>>>(Wout, fW1, fW2, WT);
  embed_kernel<<<(B_ * L_ * D_ + 255) / 256, 256, 0, stream>>>(x, W_emb, b_emb, H);

  const float* hin_t[6]  = {H, H, H, H, R, H};
  float*       hout_t[6] = {H, H, H, R, H, H};
  for (int i = 0; i < 6; ++i) {
    const float* hin = hin_t[i];
    float* hout = hout_t[i];
    build_kernel<<<256, 128, 0, stream>>>(WB, C2B, WLB, gamma_, beta_, Dskip,
                                          Tn, En, Fn, Pbeta, Sbeta, i);
    trans_h_ut<<<1024, 256, 0, stream>>>(hin, UT);
    scan_gemm_state<<<512, 256, 0, stream>>>(UT, Fn, Sbeta, SL);
    pass2_kernel<<<1024, 256, 0, stream>>>(SL, WLB, i);
    scan_gemm_out<<<512, 256, 0, stream>>>(UT, SL, Tn, En, Pbeta, GT);
    trans_gt_g<<<1024, 256, 0, stream>>>(GT, Gbf);
    gemm_bf16<<<dim3(B_ * L_ / 128, 2), 256, 0, stream>>>(
        Gbf, WT + (size_t)i * 65536, bout + i * D_, hin, hout,
        (i == 5) ? Hbf : nullptr, 0);
  }
  // feedforward of the FS4Ddeq block + skip from R
  gemm_bf16<<<dim3(B_ * L_ / 128, 2), 256, 0, stream>>>(
      Hbf, WT + (size_t)6 * 65536, fb1, nullptr, nullptr, Gbf, 1);
  gemm_bf16<<<dim3(B_ * L_ / 128, 2), 256, 0, stream>>>(
      Gbf, WT + (size_t)7 * 65536, fb2, R, H, nullptr, 1);
  head1_kernel<<<dim3(16, 16), 256, 0, stream>>>(H, (float*)UT);
  head2_kernel<<<16, 256, 0, stream>>>((float*)UT, fcW, fcb, outp);
}

// Round 6
// 866.252 us; speedup vs baseline: 2.0526x; 1.2282x over previous
//
#include <hip/hip_runtime.h>
#include <hip/hip_bf16.h>
#include <hip/hip_fp16.h>
#include <math.h>

#define B_ 16
#define L_ 2048
#define D_ 256
#define N_ 64
#define NBLK_ 6
#define LC_ 128
#define NC_ 16

typedef _Float16 half8 __attribute__((ext_vector_type(8)));
typedef float f32x4 __attribute__((ext_vector_type(4)));
typedef short short8 __attribute__((ext_vector_type(8)));

__device__ __forceinline__ unsigned short f2bf(float f) {
  unsigned int u = __float_as_uint(f);
  u += 0x7fffu + ((u >> 16) & 1u);
  return (unsigned short)(u >> 16);
}
__device__ __forceinline__ unsigned short f2h(float f) {
  _Float16 h = (_Float16)f;
  return *(unsigned short*)&h;
}
__device__ __forceinline__ float h2f(unsigned short u) {
  _Float16 h = *(_Float16*)&u;
  return (float)h;
}

// ---------------- precompute per-layer SSM params ----------------
// wbuf stride 128 per (blk,d): [0:64)=wr, [64:128)=wi
// c2buf stride 128: [0:64)=c2r, [64:128)=c2i ;  wlbuf interleaved [blk*D+d][n][2]
__global__ void precompute_kernel(const float* __restrict__ log_dt,
                                  const float* __restrict__ logAre,
                                  const float* __restrict__ Aim,
                                  const float* __restrict__ Cre,
                                  const float* __restrict__ Cim,
                                  float* __restrict__ wbuf,
                                  float* __restrict__ c2buf,
                                  float* __restrict__ wlbuf) {
  int idx = blockIdx.x * blockDim.x + threadIdx.x;
  if (idx >= NBLK_ * D_ * N_) return;
  int blk = idx >> 14;
  int rem = idx & 16383;
  int d = rem >> 6;
  int n = rem & 63;
  float dt   = expf(log_dt[blk * D_ + d]);
  float are  = -expf(logAre[idx]);
  float aim  = Aim[idx];
  float dtar = dt * are, dtai = dt * aim;
  float er = expf(dtar);
  float wr = er * cosf(dtai);
  float wi = er * sinf(dtai);
  float inv = 1.0f / (are * are + aim * aim);
  float wm1r = wr - 1.0f;
  float br = (wm1r * are + wi * aim) * inv;
  float bi = (wi * are - wm1r * aim) * inv;
  float crv = Cre[idx], civ = Cim[idx];
  float c2r = 2.0f * (crv * br - civ * bi);
  float c2i = 2.0f * (crv * bi + civ * br);
  float eL = expf((float)LC_ * dtar);
  float angL = (float)LC_ * dtai;
  float wlr = eL * cosf(angL);
  float wli = eL * sinf(angL);
  float* wb = wbuf + (size_t)((blk << 8) + d) * 128;
  wb[n] = wr; wb[64 + n] = wi;
  float* cb = c2buf + (size_t)((blk << 8) + d) * 128;
  cb[n] = c2r; cb[64 + n] = c2i;
  wlbuf[2 * idx] = wlr; wlbuf[2 * idx + 1] = wli;
}

// ---------------- build stage 1: powers, En, Fn, K, Sbeta --------------------
// One wave per (d, j): lane n handles mode n. 8192 blocks x 256 threads.
// En[d][j][n2]  = fp16 components of c2*w^{j+1}
// Fn[d][n2][127-j] = fp16(gamma*Re/-Im(w^j))
// Kbuf[d][j] = sum_n Re(c2*w^j)
// Sbeta (j==0 wave): bd * components of (wL-1)/(w-1)
__global__ __launch_bounds__(256) void build_pow(
    const float* __restrict__ wbuf, const float* __restrict__ c2buf,
    const float* __restrict__ wlbuf,
    const float* __restrict__ gamma_, const float* __restrict__ beta_,
    unsigned short* __restrict__ En, unsigned short* __restrict__ Fn,
    float* __restrict__ Kbuf, float* __restrict__ Sbeta, int blk) {
  int bid = blockIdx.x;           // d*32 + jg
  int d = bid >> 5, jg = bid & 31;
  int w = threadIdx.x >> 6, n = threadIdx.x & 63;
  int j = (jg << 2) + w;          // 0..127 (wave-uniform)
  const float* wp = wbuf + (size_t)((blk << 8) + d) * 128;
  const float* cp = c2buf + (size_t)((blk << 8) + d) * 128;
  float wr = wp[n], wi = wp[64 + n];
  float c2r = cp[n], c2i = cp[64 + n];
  float gd = gamma_[blk * D_ + d];
  // w^j by binary pow (uniform exponent -> no divergence)
  float pr = 1.f, pi = 0.f, br = wr, bi = wi;
  int e = j;
  while (e) {
    if (e & 1) { float t = pr * br - pi * bi; pi = pr * bi + pi * br; pr = t; }
    float t2 = br * br - bi * bi; bi = 2.f * br * bi; br = t2;
    e >>= 1;
  }
  float qr = pr * wr - pi * wi, qi = pr * wi + pi * wr;   // w^{j+1}
  size_t eb = ((size_t)d * 128 + j) * 128;
  En[eb + n]      = f2h(c2r * qr - c2i * qi);
  En[eb + 64 + n] = f2h(c2r * qi + c2i * qr);
  Fn[((size_t)d * 128 + n) * 128 + (127 - j)]      = f2h(gd * pr);
  Fn[((size_t)d * 128 + 64 + n) * 128 + (127 - j)] = f2h(-gd * pi);
  float kc = c2r * pr - c2i * pi;
#pragma unroll
  for (int off = 1; off < 64; off <<= 1) kc += __shfl_xor(kc, off);
  if (n == 0) Kbuf[d * 128 + j] = kc;
  if (j == 0) {
    float bd = beta_[blk * D_ + d];
    const float* wlp = wlbuf + (((size_t)((blk << 8) + d)) * 64 + n) * 2;
    float wlr = wlp[0], wli = wlp[1];
    float nr = wlr - 1.f, ni = wli;
    float dr2 = wr - 1.f, di = wi;
    float iv = 1.f / (dr2 * dr2 + di * di);
    float Srr = (nr * dr2 + ni * di) * iv;
    float Sii = (ni * dr2 - nr * di) * iv;
    Sbeta[d * 128 + n]      = bd * Srr;
    Sbeta[d * 128 + 64 + n] = bd * (-Sii);
  }
}

// ---------------- build stage 2: Toeplitz Tn + Pbeta -------------------------
// one block per d; Ktilde = K + dsk@0; Tn[d][t][tau] = tau<=t ? gd*Kt[t-tau] : 0
__global__ __launch_bounds__(256) void build_T(
    const float* __restrict__ Kbuf, const float* __restrict__ gamma_,
    const float* __restrict__ beta_, const float* __restrict__ dskip,
    unsigned short* __restrict__ Tn, float* __restrict__ Pbeta, int blk) {
  __shared__ float Kt[128];
  int d = blockIdx.x;
  int tid = threadIdx.x;
  float gd = gamma_[blk * D_ + d], bd = beta_[blk * D_ + d], dsk = dskip[blk * D_ + d];
  if (tid < 128) Kt[tid] = Kbuf[d * 128 + tid] + (tid == 0 ? dsk : 0.f);
  __syncthreads();
  if (tid < 128) {
    float ps = 0.f;
    for (int t2 = 0; t2 <= tid; ++t2) ps += Kt[t2];
    Pbeta[d * 128 + tid] = bd * ps;
  }
  int chunk = tid & 15;           // 16 chunks of 8 tau
  int rg = tid >> 4;              // 16 rows per iteration
  for (int it = 0; it < 8; ++it) {
    int t = it * 16 + rg;
    int tau0 = chunk << 3;
    unsigned short v[8];
#pragma unroll
    for (int i = 0; i < 8; ++i) {
      int tau = tau0 + i;
      v[i] = (tau <= t) ? f2h(gd * Kt[t - tau]) : (unsigned short)0;
    }
    *(uint4*)(Tn + (size_t)d * 16384 + (size_t)t * 128 + tau0) = *(uint4*)v;
  }
}

// ---------------- embedding ----------
__global__ void embed_kernel(const float* __restrict__ x, const float* __restrict__ wemb,
                             const float* __restrict__ bemb, float* __restrict__ H) {
  int tid = blockIdx.x * blockDim.x + threadIdx.x;
  if (tid >= B_ * L_ * D_) return;
  int d = tid & (D_ - 1);
  int lg = tid >> 8;
  H[tid] = fmaf(x[lg], wemb[d], bemb[d]);
}

// ---------------- transpose H [b][l][d] fp32 -> UT [d][bc][tau] fp16 ---------
__global__ __launch_bounds__(256) void trans_h_ut(const float* __restrict__ H,
                                                  unsigned short* __restrict__ UT) {
  __shared__ __align__(16) unsigned short lds[64][136];
  int bi = blockIdx.x;          // bc*4 + dq
  int bc = bi >> 2, dq = bi & 3;
  int b = bc >> 4, ch = bc & 15;
  int tid = threadIdx.x;
  const float* src = H + ((size_t)(b * L_ + ch * 128)) * D_ + dq * 64;
  int tau0 = tid >> 4;          // 0..15
  int dl = (tid & 15) << 2;
  for (int tt = 0; tt < 128; tt += 16) {
    float4 v = *(const float4*)(src + (size_t)(tt + tau0) * D_ + dl);
    lds[dl + 0][tt + tau0] = f2h(v.x);
    lds[dl + 1][tt + tau0] = f2h(v.y);
    lds[dl + 2][tt + tau0] = f2h(v.z);
    lds[dl + 3][tt + tau0] = f2h(v.w);
  }
  __syncthreads();
  int r = tid >> 2, seg = (tid & 3) << 5;   // r 0..63, seg 0/32/64/96
  unsigned short* dst = UT + ((size_t)((dq * 64 + r) * 256 + bc)) * 128 + seg;
  const unsigned short* srow = &lds[r][seg];
  *(uint4*)(dst + 0)  = *(const uint4*)(srow + 0);
  *(uint4*)(dst + 8)  = *(const uint4*)(srow + 8);
  *(uint4*)(dst + 16) = *(const uint4*)(srow + 16);
  *(uint4*)(dst + 24) = *(const uint4*)(srow + 24);
}

// ---------------- scanA: SL[d][bc][n2] = fp16(UT[d] @ Fn[d]^T + Sbeta) -------
__global__ __launch_bounds__(256) void scan_gemm_state(
    const unsigned short* __restrict__ UT, const unsigned short* __restrict__ Fn,
    const float* __restrict__ Sbeta, unsigned short* __restrict__ SL) {
  __shared__ __align__(16) _Float16 As[128][40];
  __shared__ __align__(16) _Float16 Bs[128][40];
  int bx = blockIdx.x;
  int d = bx >> 1, mh = bx & 1;
  int tid = threadIdx.x, lane = tid & 63, w = tid >> 6;
  int wm = (w & 1) << 6, wn = (w >> 1) << 6;
  const unsigned short* Abase = UT + ((size_t)d * 256 + mh * 128) * 128;
  const unsigned short* Bbase = Fn + (size_t)d * 16384;
  f32x4 acc[4][4];
#pragma unroll
  for (int a = 0; a < 4; ++a)
#pragma unroll
    for (int b2 = 0; b2 < 4; ++b2) acc[a][b2] = (f32x4){0.f, 0.f, 0.f, 0.f};
  int r = tid & 127, sg = (tid >> 7) << 4;
  for (int kc = 0; kc < 128; kc += 32) {
    __syncthreads();
    const uint4* pa = (const uint4*)(Abase + (size_t)r * 128 + kc + sg);
    uint4 a0 = pa[0], a1 = pa[1];
    const uint4* pb = (const uint4*)(Bbase + (size_t)r * 128 + kc + sg);
    uint4 b0 = pb[0], b1 = pb[1];
    *(uint4*)&As[r][sg] = a0; *(uint4*)&As[r][sg + 8] = a1;
    *(uint4*)&Bs[r][sg] = b0; *(uint4*)&Bs[r][sg + 8] = b1;
    __syncthreads();
    int ko = (lane >> 4) << 3;
    half8 af[4], bf4[4];
#pragma unroll
    for (int mf = 0; mf < 4; ++mf) af[mf] = *(const half8*)&As[wm + (mf << 4) + (lane & 15)][ko];
#pragma unroll
    for (int nf = 0; nf < 4; ++nf) bf4[nf] = *(const half8*)&Bs[wn + (nf << 4) + (lane & 15)][ko];
#pragma unroll
    for (int mf = 0; mf < 4; ++mf)
#pragma unroll
      for (int nf = 0; nf < 4; ++nf)
        acc[mf][nf] = __builtin_amdgcn_mfma_f32_16x16x32_f16(af[mf], bf4[nf], acc[mf][nf], 0, 0, 0);
  }
  int cn = lane & 15, rq = lane >> 4;
#pragma unroll
  for (int nf = 0; nf < 4; ++nf) {
    int n = wn + (nf << 4) + cn;
    float sb = Sbeta[d * 128 + n];
#pragma unroll
    for (int mf = 0; mf < 4; ++mf)
#pragma unroll
      for (int rr = 0; rr < 4; ++rr) {
        int m = mh * 128 + wm + (mf << 4) + (rq << 2) + rr;
        SL[((size_t)d * 256 + m) * 128 + n] = f2h(acc[mf][nf][rr] + sb);
      }
  }
}

// ---------------- pass2: in-place exclusive chunk-state combine --------------
__global__ void pass2_kernel(unsigned short* __restrict__ SL,
                             const float* __restrict__ wlbuf, int blk) {
  int tid = blockIdx.x * blockDim.x + threadIdx.x;  // 262144
  int d = tid >> 10, rest = tid & 1023, b = rest >> 6, n = rest & 63;
  const float* wlp = wlbuf + (((size_t)((blk << 8) + d)) * 64 + n) * 2;
  float wlr = wlp[0], wli = wlp[1];
  float Sr = 0.f, Sj = 0.f;   // Sj = -Si (negated-imag convention)
  for (int c = 0; c < NC_; ++c) {
    size_t base = ((size_t)d * 256 + b * 16 + c) * 128;
    float tr2 = h2f(SL[base + n]);
    float tj  = h2f(SL[base + 64 + n]);
    SL[base + n]      = f2h(Sr);          // state ENTERING chunk c
    SL[base + 64 + n] = f2h(Sj);
    float nSr = fmaf(wlr, Sr, fmaf(wli, Sj, tr2));
    Sj = fmaf(-wli, Sr, fmaf(wlr, Sj, tj));
    Sr = nSr;
  }
}

// ---------------- scanB: GT[d][bc][t] = gelu(UT@Tn^T + SL@En^T + Pbeta) ------
__global__ __launch_bounds__(256) void scan_gemm_out(
    const unsigned short* __restrict__ UT, const unsigned short* __restrict__ Sin,
    const unsigned short* __restrict__ Tn, const unsigned short* __restrict__ En,
    const float* __restrict__ Pbeta, unsigned short* __restrict__ GT) {
  __shared__ __align__(16) _Float16 As[128][40];
  __shared__ __align__(16) _Float16 Bs[128][40];
  int bx = blockIdx.x;
  int d = bx >> 1, mh = bx & 1;
  int tid = threadIdx.x, lane = tid & 63, w = tid >> 6;
  int wm = (w & 1) << 6, wn = (w >> 1) << 6;
  f32x4 acc[4][4];
#pragma unroll
  for (int a = 0; a < 4; ++a)
#pragma unroll
    for (int b2 = 0; b2 < 4; ++b2) acc[a][b2] = (f32x4){0.f, 0.f, 0.f, 0.f};
  int r = tid & 127, sg = (tid >> 7) << 4;
  for (int kb = 0; kb < 8; ++kb) {
    int kc = (kb & 3) << 5;
    const unsigned short* Abase = ((kb < 4) ? UT : Sin) + ((size_t)d * 256 + mh * 128) * 128 + kc;
    const unsigned short* Bbase = ((kb < 4) ? Tn : En) + (size_t)d * 16384 + kc;
    __syncthreads();
    const uint4* pa = (const uint4*)(Abase + (size_t)r * 128 + sg);
    uint4 a0 = pa[0], a1 = pa[1];
    const uint4* pb = (const uint4*)(Bbase + (size_t)r * 128 + sg);
    uint4 b0 = pb[0], b1 = pb[1];
    *(uint4*)&As[r][sg] = a0; *(uint4*)&As[r][sg + 8] = a1;
    *(uint4*)&Bs[r][sg] = b0; *(uint4*)&Bs[r][sg + 8] = b1;
    __syncthreads();
    int ko = (lane >> 4) << 3;
    half8 af[4], bf4[4];
#pragma unroll
    for (int mf = 0; mf < 4; ++mf) af[mf] = *(const half8*)&As[wm + (mf << 4) + (lane & 15)][ko];
#pragma unroll
    for (int nf = 0; nf < 4; ++nf) bf4[nf] = *(const half8*)&Bs[wn + (nf << 4) + (lane & 15)][ko];
#pragma unroll
    for (int mf = 0; mf < 4; ++mf)
#pragma unroll
      for (int nf = 0; nf < 4; ++nf)
        acc[mf][nf] = __builtin_amdgcn_mfma_f32_16x16x32_f16(af[mf], bf4[nf], acc[mf][nf], 0, 0, 0);
  }
  int cn = lane & 15, rq = lane >> 4;
#pragma unroll
  for (int nf = 0; nf < 4; ++nf) {
    int n = wn + (nf << 4) + cn;
    float pb2 = Pbeta[d * 128 + n];
#pragma unroll
    for (int mf = 0; mf < 4; ++mf)
#pragma unroll
      for (int rr = 0; rr < 4; ++rr) {
        int m = mh * 128 + wm + (mf << 4) + (rq << 2) + rr;
        float xx = acc[mf][nf][rr] + pb2;
        float x3 = xx * xx * xx;
        float inner = 0.7978845608028654f * fmaf(0.044715f, x3, xx);
        float e = __expf(-2.f * fabsf(inner));
        float th = (1.f - e) / (1.f + e);
        th = copysignf(th, inner);
        float gv = 0.5f * xx * (1.f + th);
        GT[((size_t)d * 256 + m) * 128 + n] = f2bf(gv);
      }
  }
}

// ---------------- W prep: WT[w][n][k] = W_w[k][n] as bf16 --------------------
__global__ void wprep_kernel(const float* __restrict__ Wout, const float* __restrict__ fW1,
                             const float* __restrict__ fW2, unsigned short* __restrict__ WT) {
  __shared__ float tile[64][65];
  int wv = blockIdx.x >> 4;
  int tk = (blockIdx.x >> 2) & 3;
  int tn = blockIdx.x & 3;
  const float* src = (wv < 6) ? (Wout + (size_t)wv * 65536) : (wv == 6 ? fW1 : fW2);
  int r = threadIdx.x >> 4;
  int c = (threadIdx.x & 15) << 2;
  for (int rr = 0; rr < 64; rr += 16) {
    float4 v = *(const float4*)(src + (size_t)(tk * 64 + r + rr) * 256 + tn * 64 + c);
    tile[r + rr][c] = v.x; tile[r + rr][c + 1] = v.y;
    tile[r + rr][c + 2] = v.z; tile[r + rr][c + 3] = v.w;
  }
  __syncthreads();
  for (int rr = 0; rr < 64; rr += 16) {
    int n = r + rr;
    ushort4 o;
    o.x = f2bf(tile[c + 0][n]); o.y = f2bf(tile[c + 1][n]);
    o.z = f2bf(tile[c + 2][n]); o.w = f2bf(tile[c + 3][n]);
    *(ushort4*)(WT + (size_t)wv * 65536 + (size_t)(tn * 64 + n) * 256 + tk * 64 + c) = o;
  }
}

// ---------------- projection GEMM reading GT directly (fused transpose) ------
// A[m][k] = GT[k][bc][t] with m = bc*128 + t (bc = blockIdx.x). out = A@W + bias + res.
__global__ __launch_bounds__(256, 2) void gemm_gt(const unsigned short* __restrict__ GT,
    const unsigned short* __restrict__ Wt, const float* __restrict__ bias,
    const float* __restrict__ res, float* __restrict__ outf,
    unsigned short* __restrict__ outbf) {
  __shared__ __align__(16) unsigned short As[128][72];
  __shared__ __align__(16) unsigned short Bs[128][72];
  int tid = threadIdx.x;
  int bc = blockIdx.x;
  int m0 = bc * 128, n0 = blockIdx.y * 128;
  int lane = tid & 63, w = tid >> 6;
  int wm = (w & 1) << 6, wn = (w >> 1) << 6;
  int rb = tid >> 3, cb = (tid & 7) << 3;     // B staging coords
  int dr = tid >> 2, sg = (tid & 3) << 5;     // A staging coords
  f32x4 acc[4][4];
#pragma unroll
  for (int mf = 0; mf < 4; ++mf)
#pragma unroll
    for (int nf = 0; nf < 4; ++nf) acc[mf][nf] = (f32x4){0.f, 0.f, 0.f, 0.f};

  for (int kb = 0; kb < 4; ++kb) {
    int k0 = kb << 6;
    __syncthreads();
    // A: read GT rows (d = k0+dr), transpose into As[t][dr]
    uint4 gv[4];
    const uint4* grow = (const uint4*)(GT + ((size_t)((k0 + dr) * 256 + bc)) * 128 + sg);
    gv[0] = grow[0]; gv[1] = grow[1]; gv[2] = grow[2]; gv[3] = grow[3];
    // B: Wt rows
    uint4 bv[4];
#pragma unroll
    for (int rr = 0; rr < 4; ++rr)
      bv[rr] = *(const uint4*)(Wt + (size_t)(n0 + rb + rr * 32) * 256 + k0 + cb);
    const unsigned short* pv = (const unsigned short*)gv;
#pragma unroll
    for (int i = 0; i < 32; ++i) As[sg + i][dr] = pv[i];
#pragma unroll
    for (int rr = 0; rr < 4; ++rr) *(uint4*)&Bs[rb + rr * 32][cb] = bv[rr];
    __syncthreads();
#pragma unroll
    for (int kw = 0; kw < 2; ++kw) {
      int ko = (kw << 5) + ((lane >> 4) << 3);
      short8 af[4], bfr[4];
#pragma unroll
      for (int mf = 0; mf < 4; ++mf)
        af[mf] = *(const short8*)&As[wm + (mf << 4) + (lane & 15)][ko];
#pragma unroll
      for (int nf = 0; nf < 4; ++nf)
        bfr[nf] = *(const short8*)&Bs[wn + (nf << 4) + (lane & 15)][ko];
#pragma unroll
      for (int mf = 0; mf < 4; ++mf)
#pragma unroll
        for (int nf = 0; nf < 4; ++nf)
          acc[mf][nf] = __builtin_amdgcn_mfma_f32_16x16x32_bf16(af[mf], bfr[nf], acc[mf][nf], 0, 0, 0);
    }
  }
  int cn = lane & 15, rq = lane >> 4;
#pragma unroll
  for (int mf = 0; mf < 4; ++mf) {
#pragma unroll
    for (int nf = 0; nf < 4; ++nf) {
      int n = n0 + wn + (nf << 4) + cn;
      float bv2 = bias[n];
#pragma unroll
      for (int r = 0; r < 4; ++r) {
        int m = m0 + wm + (mf << 4) + (rq << 2) + r;
        float v = acc[mf][nf][r] + bv2;
        v += res[(size_t)m * 256 + n];
        if (outf) outf[(size_t)m * 256 + n] = v;
        if (outbf) outbf[(size_t)m * 256 + n] = f2bf(v);
      }
    }
  }
}

// ---------------- bf16 MFMA GEMM (row-major A): out = act(A@W + bias [+res]) -
__global__ __launch_bounds__(256, 2) void gemm_bf16(const unsigned short* __restrict__ A,
    const unsigned short* __restrict__ Wt, const float* __restrict__ bias,
    const float* __restrict__ res, float* __restrict__ outf,
    unsigned short* __restrict__ outbf, int do_relu) {
  __shared__ __align__(16) unsigned short As[128][72];
  __shared__ __align__(16) unsigned short Bs[128][72];
  int tid = threadIdx.x;
  int m0 = blockIdx.x * 128, n0 = blockIdx.y * 128;
  int lane = tid & 63, w = tid >> 6;
  int wm = (w & 1) << 6, wn = (w >> 1) << 6;
  int r0 = tid >> 3;
  int c0 = (tid & 7) << 3;
  f32x4 acc[4][4];
#pragma unroll
  for (int mf = 0; mf < 4; ++mf)
#pragma unroll
    for (int nf = 0; nf < 4; ++nf) acc[mf][nf] = (f32x4){0.f, 0.f, 0.f, 0.f};

  for (int kb = 0; kb < 4; ++kb) {
    int k0 = kb << 6;
    __syncthreads();
#pragma unroll
    for (int rr = 0; rr < 4; ++rr) {
      int r = r0 + rr * 32;
      uint4 av = *(const uint4*)(A + (size_t)(m0 + r) * 256 + k0 + c0);
      uint4 bv = *(const uint4*)(Wt + (size_t)(n0 + r) * 256 + k0 + c0);
      *(uint4*)&As[r][c0] = av;
      *(uint4*)&Bs[r][c0] = bv;
    }
    __syncthreads();
#pragma unroll
    for (int kw = 0; kw < 2; ++kw) {
      int ko = (kw << 5) + ((lane >> 4) << 3);
      short8 af[4], bfr[4];
#pragma unroll
      for (int mf = 0; mf < 4; ++mf)
        af[mf] = *(const short8*)&As[wm + (mf << 4) + (lane & 15)][ko];
#pragma unroll
      for (int nf = 0; nf < 4; ++nf)
        bfr[nf] = *(const short8*)&Bs[wn + (nf << 4) + (lane & 15)][ko];
#pragma unroll
      for (int mf = 0; mf < 4; ++mf)
#pragma unroll
        for (int nf = 0; nf < 4; ++nf)
          acc[mf][nf] = __builtin_amdgcn_mfma_f32_16x16x32_bf16(af[mf], bfr[nf], acc[mf][nf], 0, 0, 0);
    }
  }
  int cn = lane & 15, rq = lane >> 4;
#pragma unroll
  for (int mf = 0; mf < 4; ++mf) {
#pragma unroll
    for (int nf = 0; nf < 4; ++nf) {
      int n = n0 + wn + (nf << 4) + cn;
      float bv = bias[n];
#pragma unroll
      for (int r = 0; r < 4; ++r) {
        int m = m0 + wm + (mf << 4) + (rq << 2) + r;
        float v = acc[mf][nf][r] + bv;
        if (res) v += res[(size_t)m * 256 + n];
        if (do_relu) v = fmaxf(v, 0.f);
        if (outf) outf[(size_t)m * 256 + n] = v;
        if (outbf) outbf[(size_t)m * 256 + n] = f2bf(v);
      }
    }
  }
}

// ---------------- head ------------------------
__global__ void head1_kernel(const float* __restrict__ H, float* __restrict__ part) {
  int b = blockIdx.x, ls = blockIdx.y, d = threadIdx.x;
  const float* p = H + ((size_t)(b * L_ + ls * 128)) * D_ + d;
  float sum = 0.f;
  for (int l = 0; l < 128; ++l) sum += p[(size_t)l * D_];
  part[(b * 16 + ls) * D_ + d] = sum;
}

__global__ void head2_kernel(const float* __restrict__ part, const float* __restrict__ fcW,
                             const float* __restrict__ fcb, float* __restrict__ out) {
  int b = blockIdx.x, d = threadIdx.x;
  float sum = 0.f;
  for (int i = 0; i < 16; ++i) sum += part[(b * 16 + i) * D_ + d];
  __shared__ float meanv[D_];
  meanv[d] = sum * (1.0f / (float)L_);
  __syncthreads();
  if (d < 2) {
    float accv = fcb[d];
    for (int k = 0; k < D_; ++k) accv = fmaf(meanv[k], fcW[k * 2 + d], accv);
    out[b * 2 + d] = accv;
  }
}

extern "C" void kernel_launch(void* const* d_in, const int* in_sizes, int n_in,
                              void* d_out, int out_size, void* d_ws, size_t ws_size,
                              hipStream_t stream) {
  const float* x      = (const float*)d_in[0];
  const float* W_emb  = (const float*)d_in[1];
  const float* b_emb  = (const float*)d_in[2];
  const float* log_dt = (const float*)d_in[3];
  const float* logAre = (const float*)d_in[4];
  const float* Aim    = (const float*)d_in[5];
  const float* Cre    = (const float*)d_in[6];
  const float* Cim    = (const float*)d_in[7];
  const float* Dskip  = (const float*)d_in[8];
  const float* Wout   = (const float*)d_in[9];
  const float* bout   = (const float*)d_in[10];
  const float* gamma_ = (const float*)d_in[11];
  const float* beta_  = (const float*)d_in[12];
  const float* fW1    = (const float*)d_in[13];
  const float* fb1    = (const float*)d_in[14];
  const float* fW2    = (const float*)d_in[15];
  const float* fb2    = (const float*)d_in[16];
  const float* fcW    = (const float*)d_in[17];
  const float* fcb    = (const float*)d_in[18];
  float* outp = (float*)d_out;

  float* ws = (float*)d_ws;
  const size_t HSZ = (size_t)B_ * L_ * D_;   // 8388608
  // ---- workspace layout ----
  float* H     = ws;                                   // 8388608 f
  float* R     = H + HSZ;                              // 8388608 f
  float* WB    = R + HSZ;                              // 196608 f
  float* C2B   = WB + (size_t)NBLK_ * D_ * 128;        // 196608 f
  float* WLB   = C2B + (size_t)NBLK_ * D_ * 128;       // 196608 f
  float* Pbeta = WLB + (size_t)NBLK_ * D_ * N_ * 2;    // 32768 f
  float* Sbeta = Pbeta + 32768;                        // 32768 f
  float* Kbuf  = Sbeta + 32768;                        // 32768 f
  unsigned short* UT  = (unsigned short*)(Kbuf + 32768);   // 8388608 us
  unsigned short* Hbf = UT;        // alias: UT dead (after scanB L5) before Hbf written
  unsigned short* SL  = UT + HSZ;                      // 8388608 us
  unsigned short* Gbf = SL;        // alias: SL dead after scanB; used for FFN intermediate
  unsigned short* Tn  = SL + HSZ;                      // 4194304 us
  unsigned short* En  = Tn + (size_t)4194304;          // 4194304 us
  unsigned short* GT  = En + (size_t)4194304;          // 8388608 us (FULL size)
  unsigned short* Fn  = GT;        // alias: Fn (4.19M) = first half of GT;
                                   // GT written by scanB strictly after scanA reads Fn
  unsigned short* WT  = GT + HSZ;                      // 524288 us

  precompute_kernel<<<(NBLK_ * D_ * N_ + 255) / 256, 256, 0, stream>>>(
      log_dt, logAre, Aim, Cre, Cim, WB, C2B, WLB);
  wprep_kernel<<<128, 256, 0, stream>>>(Wout, fW1, fW2, WT);
  embed_kernel<<<(B_ * L_ * D_ + 255) / 256, 256, 0, stream>>>(x, W_emb, b_emb, H);

  const float* hin_t[6]  = {H, H, H, H, R, H};
  float*       hout_t[6] = {H, H, H, R, H, H};
  for (int i = 0; i < 6; ++i) {
    const float* hin = hin_t[i];
    float* hout = hout_t[i];
    build_pow<<<8192, 256, 0, stream>>>(WB, C2B, WLB, gamma_, beta_,
                                        En, Fn, Kbuf, Sbeta, i);
    build_T<<<256, 256, 0, stream>>>(Kbuf, gamma_, beta_, Dskip, Tn, Pbeta, i);
    trans_h_ut<<<1024, 256, 0, stream>>>(hin, UT);
    scan_gemm_state<<<512, 256, 0, stream>>>(UT, Fn, Sbeta, SL);
    pass2_kernel<<<1024, 256, 0, stream>>>(SL, WLB, i);
    scan_gemm_out<<<512, 256, 0, stream>>>(UT, SL, Tn, En, Pbeta, GT);
    gemm_gt<<<dim3(256, 2), 256, 0, stream>>>(
        GT, WT + (size_t)i * 65536, bout + i * D_, hin, hout,
        (i == 5) ? Hbf : nullptr);
  }
  // feedforward of the FS4Ddeq block + skip from R
  gemm_bf16<<<dim3(B_ * L_ / 128, 2), 256, 0, stream>>>(
      Hbf, WT + (size_t)6 * 65536, fb1, nullptr, nullptr, Gbf, 1);
  gemm_bf16<<<dim3(B_ * L_ / 128, 2), 256, 0, stream>>>(
      Gbf, WT + (size_t)7 * 65536, fb2, R, H, nullptr, 1);
  head1_kernel<<<dim3(16, 16), 256, 0, stream>>>(H, (float*)UT);
  head2_kernel<<<16, 256, 0, stream>>>((float*)UT, fcW, fcb, outp);
}

// Round 7
// 745.855 us; speedup vs baseline: 2.3840x; 1.1614x over previous
//
#include <hip/hip_runtime.h>
#include <hip/hip_bf16.h>
#include <hip/hip_fp16.h>
#include <math.h>

#define B_ 16
#define L_ 2048
#define D_ 256
#define N_ 64
#define NBLK_ 6
#define LC_ 128
#define NC_ 16

typedef _Float16 half8 __attribute__((ext_vector_type(8)));
typedef float f32x4 __attribute__((ext_vector_type(4)));
typedef short short8 __attribute__((ext_vector_type(8)));

__device__ __forceinline__ unsigned short f2bf(float f) {
  unsigned int u = __float_as_uint(f);
  u += 0x7fffu + ((u >> 16) & 1u);
  return (unsigned short)(u >> 16);
}
__device__ __forceinline__ unsigned short f2h(float f) {
  _Float16 h = (_Float16)f;
  return *(unsigned short*)&h;
}
__device__ __forceinline__ float h2f(unsigned short u) {
  _Float16 h = *(_Float16*)&u;
  return (float)h;
}

// ---------------- precompute per-layer SSM params ----------------
// wbuf stride 128 per (blk,d): [0:64)=wr, [64:128)=wi
// c2buf stride 128: [0:64)=c2r, [64:128)=c2i ;  wlbuf interleaved [blk*D+d][n][2]
__global__ void precompute_kernel(const float* __restrict__ log_dt,
                                  const float* __restrict__ logAre,
                                  const float* __restrict__ Aim,
                                  const float* __restrict__ Cre,
                                  const float* __restrict__ Cim,
                                  float* __restrict__ wbuf,
                                  float* __restrict__ c2buf,
                                  float* __restrict__ wlbuf) {
  int idx = blockIdx.x * blockDim.x + threadIdx.x;
  if (idx >= NBLK_ * D_ * N_) return;
  int blk = idx >> 14;
  int rem = idx & 16383;
  int d = rem >> 6;
  int n = rem & 63;
  float dt   = expf(log_dt[blk * D_ + d]);
  float are  = -expf(logAre[idx]);
  float aim  = Aim[idx];
  float dtar = dt * are, dtai = dt * aim;
  float er = expf(dtar);
  float wr = er * cosf(dtai);
  float wi = er * sinf(dtai);
  float inv = 1.0f / (are * are + aim * aim);
  float wm1r = wr - 1.0f;
  float br = (wm1r * are + wi * aim) * inv;
  float bi = (wi * are - wm1r * aim) * inv;
  float crv = Cre[idx], civ = Cim[idx];
  float c2r = 2.0f * (crv * br - civ * bi);
  float c2i = 2.0f * (crv * bi + civ * br);
  float eL = expf((float)LC_ * dtar);
  float angL = (float)LC_ * dtai;
  float wlr = eL * cosf(angL);
  float wli = eL * sinf(angL);
  float* wb = wbuf + (size_t)((blk << 8) + d) * 128;
  wb[n] = wr; wb[64 + n] = wi;
  float* cb = c2buf + (size_t)((blk << 8) + d) * 128;
  cb[n] = c2r; cb[64 + n] = c2i;
  wlbuf[2 * idx] = wlr; wlbuf[2 * idx + 1] = wli;
}

// ---------------- build ALL layers' scan matrices in one dispatch ------------
// block = (blk, d). LDS powers w^j (pad-65, conflict-free), coalesced ushort8
// stores for Tn/En/Fn. Also Pbeta (beta*prefix(K)), Sbeta.
__global__ __launch_bounds__(256) void build_all(
    const float* __restrict__ WB, const float* __restrict__ C2B,
    const float* __restrict__ WLB,
    const float* __restrict__ gamma_, const float* __restrict__ beta_,
    const float* __restrict__ dskip,
    unsigned short* __restrict__ TnA, unsigned short* __restrict__ EnA,
    unsigned short* __restrict__ FnA, float* __restrict__ PbetaA,
    float* __restrict__ SbetaA) {
  __shared__ float Pr[128][65];
  __shared__ float Pi_[128][65];
  __shared__ float wc[256];    // wr[64] wi[64] c2r[64] c2i[64]
  __shared__ float Kt[128];
  int bid = blockIdx.x;        // 0..1535
  int blk = bid >> 8, d = bid & 255;
  int t = threadIdx.x;
  if (t < 128) wc[t] = WB[(size_t)((blk << 8) + d) * 128 + t];
  else         wc[t] = C2B[(size_t)((blk << 8) + d) * 128 + (t - 128)];
  __syncthreads();
  int n = t & 63, tj = t >> 6;
  float wr = wc[n], wi = wc[64 + n];
  float gd = gamma_[blk * D_ + d], bd = beta_[blk * D_ + d], dsk = dskip[blk * D_ + d];
  // phase A: powers w^j for j = tj*32 .. +31 (wave-uniform start exponent)
  {
    int j0 = tj << 5;
    float pr = 1.f, pi = 0.f, br = wr, bi = wi;
    int e = j0;
    while (e) {
      if (e & 1) { float tt = pr * br - pi * bi; pi = pr * bi + pi * br; pr = tt; }
      float t2 = br * br - bi * bi; bi = 2.f * br * bi; br = t2;
      e >>= 1;
    }
#pragma unroll 4
    for (int k = 0; k < 32; ++k) {
      Pr[j0 + k][n] = pr; Pi_[j0 + k][n] = pi;
      float tt = pr * wr - pi * wi; pi = pr * wi + pi * wr; pr = tt;
    }
  }
  __syncthreads();
  // phase K: Kt[j] = sum_n (c2r*Pr - c2i*Pi), + dskip at j=0
  if (t < 128) {
    float kc = 0.f;
    for (int nn = 0; nn < 64; ++nn)
      kc += wc[128 + nn] * Pr[t][nn] - wc[192 + nn] * Pi_[t][nn];
    Kt[t] = kc + (t == 0 ? dsk : 0.f);
  }
  // phase En: En[d][j][n2], n2 = [Re 0..63 | Im 64..127], value c2*w^{j+1}
  size_t mbase = (size_t)(blk * 256 + d) * 16384;
#pragma unroll
  for (int r8 = 0; r8 < 8; ++r8) {
    int task = t + (r8 << 8);
    int j = task >> 4, g = task & 15;
    int half = g >> 3, n0 = (g & 7) << 3;
    unsigned short v[8];
#pragma unroll
    for (int i = 0; i < 8; ++i) {
      int nn = n0 + i;
      float pr = Pr[j][nn], pi = Pi_[j][nn];
      float wwr = wc[nn], wwi = wc[64 + nn];
      float qr = pr * wwr - pi * wwi, qi = pr * wwi + pi * wwr;
      float cr = wc[128 + nn], ci = wc[192 + nn];
      v[i] = f2h(half == 0 ? (cr * qr - ci * qi) : (cr * qi + ci * qr));
    }
    *(uint4*)(EnA + mbase + (size_t)j * 128 + (half << 6) + n0) = *(uint4*)v;
  }
  // phase Fn: Fn[d][n2][tau] = gd*{Re,-Im}(w^{127-tau})
#pragma unroll
  for (int r8 = 0; r8 < 8; ++r8) {
    int task = t + (r8 << 8);
    int n2 = task >> 4, tb = task & 15;
    int half = n2 >> 6, nn = n2 & 63;
    int tau0 = tb << 3;
    unsigned short v[8];
#pragma unroll
    for (int i = 0; i < 8; ++i) {
      int j = 127 - (tau0 + i);
      v[i] = f2h(half == 0 ? (gd * Pr[j][nn]) : (-gd * Pi_[j][nn]));
    }
    *(uint4*)(FnA + mbase + (size_t)n2 * 128 + tau0) = *(uint4*)v;
  }
  __syncthreads();
  // Pbeta (prefix) and Sbeta
  if (t < 128) {
    float ps = 0.f;
    for (int t2 = 0; t2 <= t; ++t2) ps += Kt[t2];
    PbetaA[((size_t)blk * 256 + d) * 128 + t] = bd * ps;
  }
  if (t >= 128 && t < 192) {
    int nn = t - 128;
    const float* wlp = WLB + (((size_t)((blk << 8) + d)) * 64 + nn) * 2;
    float wlr = wlp[0], wli = wlp[1];
    float wwr = wc[nn], wwi = wc[64 + nn];
    float nr = wlr - 1.f, ni = wli, dr2 = wwr - 1.f, di = wwi;
    float iv = 1.f / (dr2 * dr2 + di * di);
    SbetaA[((size_t)blk * 256 + d) * 128 + nn]      = bd * ((nr * dr2 + ni * di) * iv);
    SbetaA[((size_t)blk * 256 + d) * 128 + 64 + nn] = bd * (-((ni * dr2 - nr * di) * iv));
  }
  // Tn: Toeplitz rows, coalesced ushort8
  int chunk = t & 15, rg = t >> 4;
#pragma unroll
  for (int it = 0; it < 8; ++it) {
    int trow = (it << 4) + rg;
    int tau0 = chunk << 3;
    unsigned short v[8];
#pragma unroll
    for (int i = 0; i < 8; ++i) {
      int tau = tau0 + i;
      v[i] = (tau <= trow) ? f2h(gd * Kt[trow - tau]) : (unsigned short)0;
    }
    *(uint4*)(TnA + mbase + (size_t)trow * 128 + tau0) = *(uint4*)v;
  }
}

// ---------------- embedding ----------
__global__ void embed_kernel(const float* __restrict__ x, const float* __restrict__ wemb,
                             const float* __restrict__ bemb, float* __restrict__ H) {
  int tid = blockIdx.x * blockDim.x + threadIdx.x;
  if (tid >= B_ * L_ * D_) return;
  int d = tid & (D_ - 1);
  int lg = tid >> 8;
  H[tid] = fmaf(x[lg], wemb[d], bemb[d]);
}

// ---------------- transpose H [b][l][d] fp32 -> UT [d][bc][tau] fp16 (layer 0)
__global__ __launch_bounds__(256) void trans_h_ut(const float* __restrict__ H,
                                                  unsigned short* __restrict__ UT) {
  __shared__ __align__(16) unsigned short lds[64][136];
  int bi = blockIdx.x;          // bc*4 + dq
  int bc = bi >> 2, dq = bi & 3;
  int b = bc >> 4, ch = bc & 15;
  int tid = threadIdx.x;
  const float* src = H + ((size_t)(b * L_ + ch * 128)) * D_ + dq * 64;
  int tau0 = tid >> 4;
  int dl = (tid & 15) << 2;
  for (int tt = 0; tt < 128; tt += 16) {
    float4 v = *(const float4*)(src + (size_t)(tt + tau0) * D_ + dl);
    lds[dl + 0][tt + tau0] = f2h(v.x);
    lds[dl + 1][tt + tau0] = f2h(v.y);
    lds[dl + 2][tt + tau0] = f2h(v.z);
    lds[dl + 3][tt + tau0] = f2h(v.w);
  }
  __syncthreads();
  int r = tid >> 2, seg = (tid & 3) << 5;
  unsigned short* dst = UT + ((size_t)((dq * 64 + r) * 256 + bc)) * 128 + seg;
  const unsigned short* srow = &lds[r][seg];
  *(uint4*)(dst + 0)  = *(const uint4*)(srow + 0);
  *(uint4*)(dst + 8)  = *(const uint4*)(srow + 8);
  *(uint4*)(dst + 16) = *(const uint4*)(srow + 16);
  *(uint4*)(dst + 24) = *(const uint4*)(srow + 24);
}

// ---------------- scanA: SL[d][bc][n2] = fp16(UT[d] @ Fn[d]^T + Sbeta) -------
__global__ __launch_bounds__(256) void scan_gemm_state(
    const unsigned short* __restrict__ UT, const unsigned short* __restrict__ FnA,
    const float* __restrict__ SbetaA, unsigned short* __restrict__ SL, int blk) {
  __shared__ __align__(16) _Float16 As[128][40];
  __shared__ __align__(16) _Float16 Bs[128][40];
  int bx = blockIdx.x;
  int d = bx >> 1, mh = bx & 1;
  int tid = threadIdx.x, lane = tid & 63, w = tid >> 6;
  int wm = (w & 1) << 6, wn = (w >> 1) << 6;
  const unsigned short* Abase = UT + ((size_t)d * 256 + mh * 128) * 128;
  const unsigned short* Bbase = FnA + (size_t)(blk * 256 + d) * 16384;
  f32x4 acc[4][4];
#pragma unroll
  for (int a = 0; a < 4; ++a)
#pragma unroll
    for (int b2 = 0; b2 < 4; ++b2) acc[a][b2] = (f32x4){0.f, 0.f, 0.f, 0.f};
  int r = tid & 127, sg = (tid >> 7) << 4;
  // prefetch stage 0
  uint4 a0 = *(const uint4*)(Abase + (size_t)r * 128 + sg);
  uint4 a1 = *(const uint4*)(Abase + (size_t)r * 128 + sg + 8);
  uint4 b0 = *(const uint4*)(Bbase + (size_t)r * 128 + sg);
  uint4 b1 = *(const uint4*)(Bbase + (size_t)r * 128 + sg + 8);
  for (int kc = 0; kc < 128; kc += 32) {
    __syncthreads();
    *(uint4*)&As[r][sg] = a0; *(uint4*)&As[r][sg + 8] = a1;
    *(uint4*)&Bs[r][sg] = b0; *(uint4*)&Bs[r][sg + 8] = b1;
    __syncthreads();
    if (kc < 96) {
      a0 = *(const uint4*)(Abase + (size_t)r * 128 + kc + 32 + sg);
      a1 = *(const uint4*)(Abase + (size_t)r * 128 + kc + 32 + sg + 8);
      b0 = *(const uint4*)(Bbase + (size_t)r * 128 + kc + 32 + sg);
      b1 = *(const uint4*)(Bbase + (size_t)r * 128 + kc + 32 + sg + 8);
    }
    int ko = (lane >> 4) << 3;
    half8 af[4], bf4[4];
#pragma unroll
    for (int mf = 0; mf < 4; ++mf) af[mf] = *(const half8*)&As[wm + (mf << 4) + (lane & 15)][ko];
#pragma unroll
    for (int nf = 0; nf < 4; ++nf) bf4[nf] = *(const half8*)&Bs[wn + (nf << 4) + (lane & 15)][ko];
#pragma unroll
    for (int mf = 0; mf < 4; ++mf)
#pragma unroll
      for (int nf = 0; nf < 4; ++nf)
        acc[mf][nf] = __builtin_amdgcn_mfma_f32_16x16x32_f16(af[mf], bf4[nf], acc[mf][nf], 0, 0, 0);
  }
  int cn = lane & 15, rq = lane >> 4;
#pragma unroll
  for (int nf = 0; nf < 4; ++nf) {
    int n = wn + (nf << 4) + cn;
    float sb = SbetaA[((size_t)blk * 256 + d) * 128 + n];
#pragma unroll
    for (int mf = 0; mf < 4; ++mf)
#pragma unroll
      for (int rr = 0; rr < 4; ++rr) {
        int m = mh * 128 + wm + (mf << 4) + (rq << 2) + rr;
        SL[((size_t)d * 256 + m) * 128 + n] = f2h(acc[mf][nf][rr] + sb);
      }
  }
}

// ---------------- pass2: in-place exclusive chunk-state combine --------------
__global__ void pass2_kernel(unsigned short* __restrict__ SL,
                             const float* __restrict__ wlbuf, int blk) {
  int tid = blockIdx.x * blockDim.x + threadIdx.x;  // 262144
  int d = tid >> 10, rest = tid & 1023, b = rest >> 6, n = rest & 63;
  const float* wlp = wlbuf + (((size_t)((blk << 8) + d)) * 64 + n) * 2;
  float wlr = wlp[0], wli = wlp[1];
  float Sr = 0.f, Sj = 0.f;   // Sj = -Si
  for (int c = 0; c < NC_; ++c) {
    size_t base = ((size_t)d * 256 + b * 16 + c) * 128;
    float tr2 = h2f(SL[base + n]);
    float tj  = h2f(SL[base + 64 + n]);
    SL[base + n]      = f2h(Sr);
    SL[base + 64 + n] = f2h(Sj);
    float nSr = fmaf(wlr, Sr, fmaf(wli, Sj, tr2));
    Sj = fmaf(-wli, Sr, fmaf(wlr, Sj, tj));
    Sr = nSr;
  }
}

// ---------------- scanB: GT[d][bc][t] = gelu(UT@Tn^T + SL@En^T + Pbeta) ------
// GT aliases SL (identical per-block footprint; all SL reads drain at the
// final staging barrier before any GT write).
__global__ __launch_bounds__(256) void scan_gemm_out(
    const unsigned short* __restrict__ UT, const unsigned short* __restrict__ Sin,
    const unsigned short* __restrict__ TnA, const unsigned short* __restrict__ EnA,
    const float* __restrict__ PbetaA, unsigned short* __restrict__ GT, int blk) {
  __shared__ __align__(16) _Float16 As[128][40];
  __shared__ __align__(16) _Float16 Bs[128][40];
  int bx = blockIdx.x;
  int d = bx >> 1, mh = bx & 1;
  int tid = threadIdx.x, lane = tid & 63, w = tid >> 6;
  int wm = (w & 1) << 6, wn = (w >> 1) << 6;
  const unsigned short* Au = UT + ((size_t)d * 256 + mh * 128) * 128;
  const unsigned short* Asin = Sin + ((size_t)d * 256 + mh * 128) * 128;
  const unsigned short* Bt = TnA + (size_t)(blk * 256 + d) * 16384;
  const unsigned short* Be = EnA + (size_t)(blk * 256 + d) * 16384;
  f32x4 acc[4][4];
#pragma unroll
  for (int a = 0; a < 4; ++a)
#pragma unroll
    for (int b2 = 0; b2 < 4; ++b2) acc[a][b2] = (f32x4){0.f, 0.f, 0.f, 0.f};
  int r = tid & 127, sg = (tid >> 7) << 4;
  // prefetch stage 0
  uint4 a0 = *(const uint4*)(Au + (size_t)r * 128 + sg);
  uint4 a1 = *(const uint4*)(Au + (size_t)r * 128 + sg + 8);
  uint4 b0 = *(const uint4*)(Bt + (size_t)r * 128 + sg);
  uint4 b1 = *(const uint4*)(Bt + (size_t)r * 128 + sg + 8);
  for (int kb = 0; kb < 8; ++kb) {
    __syncthreads();
    *(uint4*)&As[r][sg] = a0; *(uint4*)&As[r][sg + 8] = a1;
    *(uint4*)&Bs[r][sg] = b0; *(uint4*)&Bs[r][sg + 8] = b1;
    __syncthreads();
    if (kb < 7) {
      int k2 = kb + 1;
      int kc = (k2 & 3) << 5;
      const unsigned short* An = (k2 < 4) ? Au : Asin;
      const unsigned short* Bn = (k2 < 4) ? Bt : Be;
      a0 = *(const uint4*)(An + (size_t)r * 128 + kc + sg);
      a1 = *(const uint4*)(An + (size_t)r * 128 + kc + sg + 8);
      b0 = *(const uint4*)(Bn + (size_t)r * 128 + kc + sg);
      b1 = *(const uint4*)(Bn + (size_t)r * 128 + kc + sg + 8);
    }
    int ko = (lane >> 4) << 3;
    half8 af[4], bf4[4];
#pragma unroll
    for (int mf = 0; mf < 4; ++mf) af[mf] = *(const half8*)&As[wm + (mf << 4) + (lane & 15)][ko];
#pragma unroll
    for (int nf = 0; nf < 4; ++nf) bf4[nf] = *(const half8*)&Bs[wn + (nf << 4) + (lane & 15)][ko];
#pragma unroll
    for (int mf = 0; mf < 4; ++mf)
#pragma unroll
      for (int nf = 0; nf < 4; ++nf)
        acc[mf][nf] = __builtin_amdgcn_mfma_f32_16x16x32_f16(af[mf], bf4[nf], acc[mf][nf], 0, 0, 0);
  }
  int cn = lane & 15, rq = lane >> 4;
#pragma unroll
  for (int nf = 0; nf < 4; ++nf) {
    int n = wn + (nf << 4) + cn;
    float pb2 = PbetaA[((size_t)blk * 256 + d) * 128 + n];
#pragma unroll
    for (int mf = 0; mf < 4; ++mf)
#pragma unroll
      for (int rr = 0; rr < 4; ++rr) {
        int m = mh * 128 + wm + (mf << 4) + (rq << 2) + rr;
        float xx = acc[mf][nf][rr] + pb2;
        float x3 = xx * xx * xx;
        float inner = 0.7978845608028654f * fmaf(0.044715f, x3, xx);
        float e = __expf(-2.f * fabsf(inner));
        float th = (1.f - e) / (1.f + e);
        th = copysignf(th, inner);
        float gv = 0.5f * xx * (1.f + th);
        GT[((size_t)d * 256 + m) * 128 + n] = f2bf(gv);
      }
  }
}

// ---------------- W prep: WT[w][n][k] = W_w[k][n] as bf16 --------------------
__global__ void wprep_kernel(const float* __restrict__ Wout, const float* __restrict__ fW1,
                             const float* __restrict__ fW2, unsigned short* __restrict__ WT) {
  __shared__ float tile[64][65];
  int wv = blockIdx.x >> 4;
  int tk = (blockIdx.x >> 2) & 3;
  int tn = blockIdx.x & 3;
  const float* src = (wv < 6) ? (Wout + (size_t)wv * 65536) : (wv == 6 ? fW1 : fW2);
  int r = threadIdx.x >> 4;
  int c = (threadIdx.x & 15) << 2;
  for (int rr = 0; rr < 64; rr += 16) {
    float4 v = *(const float4*)(src + (size_t)(tk * 64 + r + rr) * 256 + tn * 64 + c);
    tile[r + rr][c] = v.x; tile[r + rr][c + 1] = v.y;
    tile[r + rr][c + 2] = v.z; tile[r + rr][c + 3] = v.w;
  }
  __syncthreads();
  for (int rr = 0; rr < 64; rr += 16) {
    int n = r + rr;
    ushort4 o;
    o.x = f2bf(tile[c + 0][n]); o.y = f2bf(tile[c + 1][n]);
    o.z = f2bf(tile[c + 2][n]); o.w = f2bf(tile[c + 3][n]);
    *(ushort4*)(WT + (size_t)wv * 65536 + (size_t)(tn * 64 + n) * 256 + tk * 64 + c) = o;
  }
}

// ---------------- projection GEMM reading GT directly (fused transpose) ------
// A[m][k] = GT[k][bc][t], m = bc*128 + t. out = A@W + bias + res.
// Optionally writes next layer's UT (fp16, [d][bc][t]) in the epilogue.
__global__ __launch_bounds__(256, 2) void gemm_gt(const unsigned short* __restrict__ GT,
    const unsigned short* __restrict__ Wt, const float* __restrict__ bias,
    const float* __restrict__ res, float* __restrict__ outf,
    unsigned short* __restrict__ outbf, unsigned short* __restrict__ ut_next) {
  __shared__ __align__(16) unsigned short As[128][72];
  __shared__ __align__(16) unsigned short Bs[128][72];
  int tid = threadIdx.x;
  int bc = blockIdx.x;
  int m0 = bc * 128, n0 = blockIdx.y * 128;
  int lane = tid & 63, w = tid >> 6;
  int wm = (w & 1) << 6, wn = (w >> 1) << 6;
  int rb = tid >> 3, cb = (tid & 7) << 3;
  int dr = tid >> 2, sg = (tid & 3) << 5;
  f32x4 acc[4][4];
#pragma unroll
  for (int mf = 0; mf < 4; ++mf)
#pragma unroll
    for (int nf = 0; nf < 4; ++nf) acc[mf][nf] = (f32x4){0.f, 0.f, 0.f, 0.f};

  uint4 gv[4], bv[4];
  {
    const uint4* grow = (const uint4*)(GT + ((size_t)(dr * 256 + bc)) * 128 + sg);
    gv[0] = grow[0]; gv[1] = grow[1]; gv[2] = grow[2]; gv[3] = grow[3];
#pragma unroll
    for (int rr = 0; rr < 4; ++rr)
      bv[rr] = *(const uint4*)(Wt + (size_t)(n0 + rb + rr * 32) * 256 + cb);
  }
  for (int kb = 0; kb < 4; ++kb) {
    __syncthreads();
    const unsigned short* pv = (const unsigned short*)gv;
#pragma unroll
    for (int i = 0; i < 32; ++i) As[sg + i][dr] = pv[i];
#pragma unroll
    for (int rr = 0; rr < 4; ++rr) *(uint4*)&Bs[rb + rr * 32][cb] = bv[rr];
    __syncthreads();
    if (kb < 3) {
      int k0 = (kb + 1) << 6;
      const uint4* grow = (const uint4*)(GT + ((size_t)((k0 + dr) * 256 + bc)) * 128 + sg);
      gv[0] = grow[0]; gv[1] = grow[1]; gv[2] = grow[2]; gv[3] = grow[3];
#pragma unroll
      for (int rr = 0; rr < 4; ++rr)
        bv[rr] = *(const uint4*)(Wt + (size_t)(n0 + rb + rr * 32) * 256 + k0 + cb);
    }
#pragma unroll
    for (int kw = 0; kw < 2; ++kw) {
      int ko = (kw << 5) + ((lane >> 4) << 3);
      short8 af[4], bfr[4];
#pragma unroll
      for (int mf = 0; mf < 4; ++mf)
        af[mf] = *(const short8*)&As[wm + (mf << 4) + (lane & 15)][ko];
#pragma unroll
      for (int nf = 0; nf < 4; ++nf)
        bfr[nf] = *(const short8*)&Bs[wn + (nf << 4) + (lane & 15)][ko];
#pragma unroll
      for (int mf = 0; mf < 4; ++mf)
#pragma unroll
        for (int nf = 0; nf < 4; ++nf)
          acc[mf][nf] = __builtin_amdgcn_mfma_f32_16x16x32_bf16(af[mf], bfr[nf], acc[mf][nf], 0, 0, 0);
    }
  }
  int cn = lane & 15, rq = lane >> 4;
#pragma unroll
  for (int mf = 0; mf < 4; ++mf) {
#pragma unroll
    for (int nf = 0; nf < 4; ++nf) {
      int n = n0 + wn + (nf << 4) + cn;
      float bv2 = bias[n];
      float v4[4];
#pragma unroll
      for (int r = 0; r < 4; ++r) {
        int m = m0 + wm + (mf << 4) + (rq << 2) + r;
        float v = acc[mf][nf][r] + bv2;
        v += res[(size_t)m * 256 + n];
        outf[(size_t)m * 256 + n] = v;
        if (outbf) outbf[(size_t)m * 256 + n] = f2bf(v);
        v4[r] = v;
      }
      if (ut_next) {
        int t0 = wm + (mf << 4) + (rq << 2);
        ushort4 h4;
        h4.x = f2h(v4[0]); h4.y = f2h(v4[1]); h4.z = f2h(v4[2]); h4.w = f2h(v4[3]);
        *(ushort4*)(ut_next + ((size_t)(n * 256 + bc)) * 128 + t0) = h4;
      }
    }
  }
}

// ---------------- bf16 MFMA GEMM (row-major A): out = act(A@W + bias [+res]) -
__global__ __launch_bounds__(256, 2) void gemm_bf16(const unsigned short* __restrict__ A,
    const unsigned short* __restrict__ Wt, const float* __restrict__ bias,
    const float* __restrict__ res, float* __restrict__ outf,
    unsigned short* __restrict__ outbf, int do_relu) {
  __shared__ __align__(16) unsigned short As[128][72];
  __shared__ __align__(16) unsigned short Bs[128][72];
  int tid = threadIdx.x;
  int m0 = blockIdx.x * 128, n0 = blockIdx.y * 128;
  int lane = tid & 63, w = tid >> 6;
  int wm = (w & 1) << 6, wn = (w >> 1) << 6;
  int r0 = tid >> 3;
  int c0 = (tid & 7) << 3;
  f32x4 acc[4][4];
#pragma unroll
  for (int mf = 0; mf < 4; ++mf)
#pragma unroll
    for (int nf = 0; nf < 4; ++nf) acc[mf][nf] = (f32x4){0.f, 0.f, 0.f, 0.f};

  uint4 av[4], bv[4];
#pragma unroll
  for (int rr = 0; rr < 4; ++rr) {
    int r = r0 + rr * 32;
    av[rr] = *(const uint4*)(A + (size_t)(m0 + r) * 256 + c0);
    bv[rr] = *(const uint4*)(Wt + (size_t)(n0 + r) * 256 + c0);
  }
  for (int kb = 0; kb < 4; ++kb) {
    __syncthreads();
#pragma unroll
    for (int rr = 0; rr < 4; ++rr) {
      int r = r0 + rr * 32;
      *(uint4*)&As[r][c0] = av[rr];
      *(uint4*)&Bs[r][c0] = bv[rr];
    }
    __syncthreads();
    if (kb < 3) {
      int k0 = (kb + 1) << 6;
#pragma unroll
      for (int rr = 0; rr < 4; ++rr) {
        int r = r0 + rr * 32;
        av[rr] = *(const uint4*)(A + (size_t)(m0 + r) * 256 + k0 + c0);
        bv[rr] = *(const uint4*)(Wt + (size_t)(n0 + r) * 256 + k0 + c0);
      }
    }
#pragma unroll
    for (int kw = 0; kw < 2; ++kw) {
      int ko = (kw << 5) + ((lane >> 4) << 3);
      short8 af[4], bfr[4];
#pragma unroll
      for (int mf = 0; mf < 4; ++mf)
        af[mf] = *(const short8*)&As[wm + (mf << 4) + (lane & 15)][ko];
#pragma unroll
      for (int nf = 0; nf < 4; ++nf)
        bfr[nf] = *(const short8*)&Bs[wn + (nf << 4) + (lane & 15)][ko];
#pragma unroll
      for (int mf = 0; mf < 4; ++mf)
#pragma unroll
        for (int nf = 0; nf < 4; ++nf)
          acc[mf][nf] = __builtin_amdgcn_mfma_f32_16x16x32_bf16(af[mf], bfr[nf], acc[mf][nf], 0, 0, 0);
    }
  }
  int cn = lane & 15, rq = lane >> 4;
#pragma unroll
  for (int mf = 0; mf < 4; ++mf) {
#pragma unroll
    for (int nf = 0; nf < 4; ++nf) {
      int n = n0 + wn + (nf << 4) + cn;
      float bv2 = bias[n];
#pragma unroll
      for (int r = 0; r < 4; ++r) {
        int m = m0 + wm + (mf << 4) + (rq << 2) + r;
        float v = acc[mf][nf][r] + bv2;
        if (res) v += res[(size_t)m * 256 + n];
        if (do_relu) v = fmaxf(v, 0.f);
        if (outf) outf[(size_t)m * 256 + n] = v;
        if (outbf) outbf[(size_t)m * 256 + n] = f2bf(v);
      }
    }
  }
}

// ---------------- head ------------------------
__global__ void head1_kernel(const float* __restrict__ H, float* __restrict__ part) {
  int b = blockIdx.x, ls = blockIdx.y, d = threadIdx.x;
  const float* p = H + ((size_t)(b * L_ + ls * 128)) * D_ + d;
  float sum = 0.f;
  for (int l = 0; l < 128; ++l) sum += p[(size_t)l * D_];
  part[(b * 16 + ls) * D_ + d] = sum;
}

__global__ void head2_kernel(const float* __restrict__ part, const float* __restrict__ fcW,
                             const float* __restrict__ fcb, float* __restrict__ out) {
  int b = blockIdx.x, d = threadIdx.x;
  float sum = 0.f;
  for (int i = 0; i < 16; ++i) sum += part[(b * 16 + i) * D_ + d];
  __shared__ float meanv[D_];
  meanv[d] = sum * (1.0f / (float)L_);
  __syncthreads();
  if (d < 2) {
    float accv = fcb[d];
    for (int k = 0; k < D_; ++k) accv = fmaf(meanv[k], fcW[k * 2 + d], accv);
    out[b * 2 + d] = accv;
  }
}

extern "C" void kernel_launch(void* const* d_in, const int* in_sizes, int n_in,
                              void* d_out, int out_size, void* d_ws, size_t ws_size,
                              hipStream_t stream) {
  const float* x      = (const float*)d_in[0];
  const float* W_emb  = (const float*)d_in[1];
  const float* b_emb  = (const float*)d_in[2];
  const float* log_dt = (const float*)d_in[3];
  const float* logAre = (const float*)d_in[4];
  const float* Aim    = (const float*)d_in[5];
  const float* Cre    = (const float*)d_in[6];
  const float* Cim    = (const float*)d_in[7];
  const float* Dskip  = (const float*)d_in[8];
  const float* Wout   = (const float*)d_in[9];
  const float* bout   = (const float*)d_in[10];
  const float* gamma_ = (const float*)d_in[11];
  const float* beta_  = (const float*)d_in[12];
  const float* fW1    = (const float*)d_in[13];
  const float* fb1    = (const float*)d_in[14];
  const float* fW2    = (const float*)d_in[15];
  const float* fb2    = (const float*)d_in[16];
  const float* fcW    = (const float*)d_in[17];
  const float* fcb    = (const float*)d_in[18];
  float* outp = (float*)d_out;

  float* ws = (float*)d_ws;
  const size_t HSZ = (size_t)B_ * L_ * D_;   // 8388608
  // ---- workspace layout (~256.6 MB of the 256 MiB d_ws) ----
  float* H      = ws;                                   // 8,388,608 f
  float* R      = H + HSZ;                              // 8,388,608 f
  float* WB     = R + HSZ;                              // 196,608 f
  float* C2B    = WB + (size_t)NBLK_ * D_ * 128;        // 196,608 f
  float* WLB    = C2B + (size_t)NBLK_ * D_ * 128;       // 196,608 f
  float* PbetaA = WLB + (size_t)NBLK_ * D_ * N_ * 2;    // 196,608 f (6 layers)
  float* SbetaA = PbetaA + (size_t)NBLK_ * 32768;       // 196,608 f
  unsigned short* UT  = (unsigned short*)(SbetaA + (size_t)NBLK_ * 32768); // 8,388,608 us
  unsigned short* Hbf = UT;        // alias: UT dead (after scanB L5) before Hbf written
  unsigned short* SL  = UT + HSZ;                       // 8,388,608 us
  unsigned short* GT  = SL;        // alias: scanB reads SL, writes GT to the SAME
                                   // per-block footprint after all SL reads drain
  unsigned short* Gbf = SL;        // alias: FFN intermediate after GT dead
  unsigned short* TnA = SL + HSZ;                       // 6 x 4,194,304 us
  unsigned short* EnA = TnA + (size_t)NBLK_ * 4194304;  // 6 x 4,194,304 us
  unsigned short* FnA = EnA + (size_t)NBLK_ * 4194304;  // 6 x 4,194,304 us
  unsigned short* WT  = FnA + (size_t)NBLK_ * 4194304;  // 524,288 us

  precompute_kernel<<<(NBLK_ * D_ * N_ + 255) / 256, 256, 0, stream>>>(
      log_dt, logAre, Aim, Cre, Cim, WB, C2B, WLB);
  wprep_kernel<<<128, 256, 0, stream>>>(Wout, fW1, fW2, WT);
  build_all<<<NBLK_ * 256, 256, 0, stream>>>(WB, C2B, WLB, gamma_, beta_, Dskip,
                                             TnA, EnA, FnA, PbetaA, SbetaA);
  embed_kernel<<<(B_ * L_ * D_ + 255) / 256, 256, 0, stream>>>(x, W_emb, b_emb, H);
  trans_h_ut<<<1024, 256, 0, stream>>>(H, UT);

  const float* hin_t[6]  = {H, H, H, H, R, H};
  float*       hout_t[6] = {H, H, H, R, H, H};
  for (int i = 0; i < 6; ++i) {
    const float* hin = hin_t[i];
    float* hout = hout_t[i];
    scan_gemm_state<<<512, 256, 0, stream>>>(UT, FnA, SbetaA, SL, i);
    pass2_kernel<<<1024, 256, 0, stream>>>(SL, WLB, i);
    scan_gemm_out<<<512, 256, 0, stream>>>(UT, SL, TnA, EnA, PbetaA, GT, i);
    gemm_gt<<<dim3(256, 2), 256, 0, stream>>>(
        GT, WT + (size_t)i * 65536, bout + i * D_, hin, hout,
        (i == 5) ? Hbf : nullptr, (i < 5) ? UT : nullptr);
  }
  // feedforward of the FS4Ddeq block + skip from R
  gemm_bf16<<<dim3(B_ * L_ / 128, 2), 256, 0, stream>>>(
      Hbf, WT + (size_t)6 * 65536, fb1, nullptr, nullptr, Gbf, 1);
  gemm_bf16<<<dim3(B_ * L_ / 128, 2), 256, 0, stream>>>(
      Gbf, WT + (size_t)7 * 65536, fb2, R, H, nullptr, 1);
  head1_kernel<<<dim3(16, 16), 256, 0, stream>>>(H, R);
  head2_kernel<<<16, 256, 0, stream>>>(R, fcW, fcb, outp);
}

// Round 8
// 694.931 us; speedup vs baseline: 2.5587x; 1.0733x over previous
//
#include <hip/hip_runtime.h>
#include <hip/hip_fp16.h>
#include <math.h>

#define B_ 16
#define L_ 2048
#define D_ 256
#define N_ 64
#define NBLK_ 6
#define LC_ 128
#define NC_ 16

typedef _Float16 half8 __attribute__((ext_vector_type(8)));
typedef float f32x4 __attribute__((ext_vector_type(4)));

__device__ __forceinline__ unsigned short f2h(float f) {
  _Float16 h = (_Float16)f;
  return *(unsigned short*)&h;
}
__device__ __forceinline__ float h2f(unsigned short u) {
  _Float16 h = *(_Float16*)&u;
  return (float)h;
}

// ---------------- precompute per-layer SSM params ----------------
__global__ void precompute_kernel(const float* __restrict__ log_dt,
                                  const float* __restrict__ logAre,
                                  const float* __restrict__ Aim,
                                  const float* __restrict__ Cre,
                                  const float* __restrict__ Cim,
                                  float* __restrict__ wbuf,
                                  float* __restrict__ c2buf,
                                  float* __restrict__ wlbuf) {
  int idx = blockIdx.x * blockDim.x + threadIdx.x;
  if (idx >= NBLK_ * D_ * N_) return;
  int blk = idx >> 14;
  int rem = idx & 16383;
  int d = rem >> 6;
  int n = rem & 63;
  float dt   = expf(log_dt[blk * D_ + d]);
  float are  = -expf(logAre[idx]);
  float aim  = Aim[idx];
  float dtar = dt * are, dtai = dt * aim;
  float er = expf(dtar);
  float wr = er * cosf(dtai);
  float wi = er * sinf(dtai);
  float inv = 1.0f / (are * are + aim * aim);
  float wm1r = wr - 1.0f;
  float br = (wm1r * are + wi * aim) * inv;
  float bi = (wi * are - wm1r * aim) * inv;
  float crv = Cre[idx], civ = Cim[idx];
  float c2r = 2.0f * (crv * br - civ * bi);
  float c2i = 2.0f * (crv * bi + civ * br);
  float eL = expf((float)LC_ * dtar);
  float angL = (float)LC_ * dtai;
  float* wb = wbuf + (size_t)((blk << 8) + d) * 128;
  wb[n] = wr; wb[64 + n] = wi;
  float* cb = c2buf + (size_t)((blk << 8) + d) * 128;
  cb[n] = c2r; cb[64 + n] = c2i;
  wlbuf[2 * idx] = eL * cosf(angL); wlbuf[2 * idx + 1] = eL * sinf(angL);
}

// ---------------- build ALL layers' scan matrices in one dispatch ------------
__global__ __launch_bounds__(256) void build_all(
    const float* __restrict__ WB, const float* __restrict__ C2B,
    const float* __restrict__ WLB,
    const float* __restrict__ gamma_, const float* __restrict__ beta_,
    const float* __restrict__ dskip,
    unsigned short* __restrict__ TnA, unsigned short* __restrict__ EnA,
    unsigned short* __restrict__ FnA, float* __restrict__ PbetaA,
    float* __restrict__ SbetaA) {
  __shared__ float Pr[128][65];
  __shared__ float Pi_[128][65];
  __shared__ float wc[256];
  __shared__ float Kt[128];
  int bid = blockIdx.x;
  int blk = bid >> 8, d = bid & 255;
  int t = threadIdx.x;
  if (t < 128) wc[t] = WB[(size_t)((blk << 8) + d) * 128 + t];
  else         wc[t] = C2B[(size_t)((blk << 8) + d) * 128 + (t - 128)];
  __syncthreads();
  int n = t & 63, tj = t >> 6;
  float wr = wc[n], wi = wc[64 + n];
  float gd = gamma_[blk * D_ + d], bd = beta_[blk * D_ + d], dsk = dskip[blk * D_ + d];
  {
    int j0 = tj << 5;
    float pr = 1.f, pi = 0.f, br = wr, bi = wi;
    int e = j0;
    while (e) {
      if (e & 1) { float tt = pr * br - pi * bi; pi = pr * bi + pi * br; pr = tt; }
      float t2 = br * br - bi * bi; bi = 2.f * br * bi; br = t2;
      e >>= 1;
    }
#pragma unroll 4
    for (int k = 0; k < 32; ++k) {
      Pr[j0 + k][n] = pr; Pi_[j0 + k][n] = pi;
      float tt = pr * wr - pi * wi; pi = pr * wi + pi * wr; pr = tt;
    }
  }
  __syncthreads();
  if (t < 128) {
    float kc = 0.f;
    for (int nn = 0; nn < 64; ++nn)
      kc += wc[128 + nn] * Pr[t][nn] - wc[192 + nn] * Pi_[t][nn];
    Kt[t] = kc + (t == 0 ? dsk : 0.f);
  }
  size_t mbase = (size_t)(blk * 256 + d) * 16384;
#pragma unroll
  for (int r8 = 0; r8 < 8; ++r8) {
    int task = t + (r8 << 8);
    int j = task >> 4, g = task & 15;
    int half = g >> 3, n0 = (g & 7) << 3;
    unsigned short v[8];
#pragma unroll
    for (int i = 0; i < 8; ++i) {
      int nn = n0 + i;
      float pr = Pr[j][nn], pi = Pi_[j][nn];
      float wwr = wc[nn], wwi = wc[64 + nn];
      float qr = pr * wwr - pi * wwi, qi = pr * wwi + pi * wwr;
      float cr = wc[128 + nn], ci = wc[192 + nn];
      v[i] = f2h(half == 0 ? (cr * qr - ci * qi) : (cr * qi + ci * qr));
    }
    *(uint4*)(EnA + mbase + (size_t)j * 128 + (half << 6) + n0) = *(uint4*)v;
  }
#pragma unroll
  for (int r8 = 0; r8 < 8; ++r8) {
    int task = t + (r8 << 8);
    int n2 = task >> 4, tb = task & 15;
    int half = n2 >> 6, nn = n2 & 63;
    int tau0 = tb << 3;
    unsigned short v[8];
#pragma unroll
    for (int i = 0; i < 8; ++i) {
      int j = 127 - (tau0 + i);
      v[i] = f2h(half == 0 ? (gd * Pr[j][nn]) : (-gd * Pi_[j][nn]));
    }
    *(uint4*)(FnA + mbase + (size_t)n2 * 128 + tau0) = *(uint4*)v;
  }
  __syncthreads();
  if (t < 128) {
    float ps = 0.f;
    for (int t2 = 0; t2 <= t; ++t2) ps += Kt[t2];
    PbetaA[((size_t)blk * 256 + d) * 128 + t] = bd * ps;
  }
  if (t >= 128 && t < 192) {
    int nn = t - 128;
    const float* wlp = WLB + (((size_t)((blk << 8) + d)) * 64 + nn) * 2;
    float wlr = wlp[0], wli = wlp[1];
    float wwr = wc[nn], wwi = wc[64 + nn];
    float nr = wlr - 1.f, ni = wli, dr2 = wwr - 1.f, di = wwi;
    float iv = 1.f / (dr2 * dr2 + di * di);
    SbetaA[((size_t)blk * 256 + d) * 128 + nn]      = bd * ((nr * dr2 + ni * di) * iv);
    SbetaA[((size_t)blk * 256 + d) * 128 + 64 + nn] = bd * (-((ni * dr2 - nr * di) * iv));
  }
  int chunk = t & 15, rg = t >> 4;
#pragma unroll
  for (int it = 0; it < 8; ++it) {
    int trow = (it << 4) + rg;
    int tau0 = chunk << 3;
    unsigned short v[8];
#pragma unroll
    for (int i = 0; i < 8; ++i) {
      int tau = tau0 + i;
      v[i] = (tau <= trow) ? f2h(gd * Kt[trow - tau]) : (unsigned short)0;
    }
    *(uint4*)(TnA + mbase + (size_t)trow * 128 + tau0) = *(uint4*)v;
  }
}

// ---------------- embedding -> fp16 H ----------
__global__ void embed_kernel(const float* __restrict__ x, const float* __restrict__ wemb,
                             const float* __restrict__ bemb, unsigned short* __restrict__ H) {
  int tid = blockIdx.x * blockDim.x + threadIdx.x;
  if (tid >= B_ * L_ * D_) return;
  int d = tid & (D_ - 1);
  int lg = tid >> 8;
  H[tid] = f2h(fmaf(x[lg], wemb[d], bemb[d]));
}

// ---------------- transpose H [b][l][d] fp16 -> UT [d][bc][tau] fp16 ---------
__global__ __launch_bounds__(256) void trans_h_ut(const unsigned short* __restrict__ H,
                                                  unsigned short* __restrict__ UT) {
  __shared__ __align__(16) unsigned short lds[64][136];
  int bi = blockIdx.x;
  int bc = bi >> 2, dq = bi & 3;
  int b = bc >> 4, ch = bc & 15;
  int tid = threadIdx.x;
  const unsigned short* src = H + ((size_t)(b * L_ + ch * 128)) * D_ + dq * 64;
  int tau0 = tid >> 4;
  int dl = (tid & 15) << 2;
  for (int tt = 0; tt < 128; tt += 16) {
    ushort4 v = *(const ushort4*)(src + (size_t)(tt + tau0) * D_ + dl);
    lds[dl + 0][tt + tau0] = v.x;
    lds[dl + 1][tt + tau0] = v.y;
    lds[dl + 2][tt + tau0] = v.z;
    lds[dl + 3][tt + tau0] = v.w;
  }
  __syncthreads();
  int r = tid >> 2, seg = (tid & 3) << 5;
  unsigned short* dst = UT + ((size_t)((dq * 64 + r) * 256 + bc)) * 128 + seg;
  const unsigned short* srow = &lds[r][seg];
  *(uint4*)(dst + 0)  = *(const uint4*)(srow + 0);
  *(uint4*)(dst + 8)  = *(const uint4*)(srow + 8);
  *(uint4*)(dst + 16) = *(const uint4*)(srow + 16);
  *(uint4*)(dst + 24) = *(const uint4*)(srow + 24);
}

// ---------------- scanA: SL[d][bc][n2] = fp16(UT[d] @ Fn[d]^T + Sbeta) -------
__global__ __launch_bounds__(256) void scan_gemm_state(
    const unsigned short* __restrict__ UT, const unsigned short* __restrict__ FnA,
    const float* __restrict__ SbetaA, unsigned short* __restrict__ SL, int blk) {
  __shared__ __align__(16) unsigned short smem[17408];
  _Float16* As = (_Float16*)smem;          // [128][40]
  _Float16* Bs = (_Float16*)smem + 5120;   // [128][40]
  int bx = blockIdx.x;
  int d = bx >> 1, mh = bx & 1;
  int tid = threadIdx.x, lane = tid & 63, w = tid >> 6;
  int wm = (w & 1) << 6, wn = (w >> 1) << 6;
  const unsigned short* Abase = UT + ((size_t)d * 256 + mh * 128) * 128;
  const unsigned short* Bbase = FnA + (size_t)(blk * 256 + d) * 16384;
  f32x4 acc[4][4];
#pragma unroll
  for (int a = 0; a < 4; ++a)
#pragma unroll
    for (int b2 = 0; b2 < 4; ++b2) acc[a][b2] = (f32x4){0.f, 0.f, 0.f, 0.f};
  int r = tid & 127, sg = (tid >> 7) << 4;
  uint4 a0 = *(const uint4*)(Abase + (size_t)r * 128 + sg);
  uint4 a1 = *(const uint4*)(Abase + (size_t)r * 128 + sg + 8);
  uint4 b0 = *(const uint4*)(Bbase + (size_t)r * 128 + sg);
  uint4 b1 = *(const uint4*)(Bbase + (size_t)r * 128 + sg + 8);
  for (int kc = 0; kc < 128; kc += 32) {
    __syncthreads();
    *(uint4*)&As[r * 40 + sg] = a0; *(uint4*)&As[r * 40 + sg + 8] = a1;
    *(uint4*)&Bs[r * 40 + sg] = b0; *(uint4*)&Bs[r * 40 + sg + 8] = b1;
    __syncthreads();
    if (kc < 96) {
      a0 = *(const uint4*)(Abase + (size_t)r * 128 + kc + 32 + sg);
      a1 = *(const uint4*)(Abase + (size_t)r * 128 + kc + 32 + sg + 8);
      b0 = *(const uint4*)(Bbase + (size_t)r * 128 + kc + 32 + sg);
      b1 = *(const uint4*)(Bbase + (size_t)r * 128 + kc + 32 + sg + 8);
    }
    int ko = (lane >> 4) << 3;
    half8 af[4], bf4[4];
#pragma unroll
    for (int mf = 0; mf < 4; ++mf) af[mf] = *(const half8*)&As[(wm + (mf << 4) + (lane & 15)) * 40 + ko];
#pragma unroll
    for (int nf = 0; nf < 4; ++nf) bf4[nf] = *(const half8*)&Bs[(wn + (nf << 4) + (lane & 15)) * 40 + ko];
#pragma unroll
    for (int mf = 0; mf < 4; ++mf)
#pragma unroll
      for (int nf = 0; nf < 4; ++nf)
        acc[mf][nf] = __builtin_amdgcn_mfma_f32_16x16x32_f16(af[mf], bf4[nf], acc[mf][nf], 0, 0, 0);
  }
  int cn = lane & 15, rq = lane >> 4;
  __syncthreads();
  unsigned short* epi = smem;   // [128][136]
#pragma unroll
  for (int nf = 0; nf < 4; ++nf) {
    int nl = wn + (nf << 4) + cn;
    float sb = SbetaA[((size_t)blk * 256 + d) * 128 + nl];
#pragma unroll
    for (int mf = 0; mf < 4; ++mf)
#pragma unroll
      for (int rr = 0; rr < 4; ++rr) {
        int ml = wm + (mf << 4) + (rq << 2) + rr;
        epi[ml * 136 + nl] = f2h(acc[mf][nf][rr] + sb);
      }
  }
  __syncthreads();
  int mr = tid >> 1, hf = (tid & 1) << 6;
  size_t gb = ((size_t)d * 256 + mh * 128 + mr) * 128 + hf;
#pragma unroll
  for (int k = 0; k < 8; ++k)
    *(uint4*)(SL + gb + k * 8) = *(const uint4*)&epi[mr * 136 + hf + k * 8];
}

// ---------------- pass2: in-place exclusive chunk-state combine --------------
__global__ void pass2_kernel(unsigned short* __restrict__ SL,
                             const float* __restrict__ wlbuf, int blk) {
  int tid = blockIdx.x * blockDim.x + threadIdx.x;
  int d = tid >> 10, rest = tid & 1023, b = rest >> 6, n = rest & 63;
  const float* wlp = wlbuf + (((size_t)((blk << 8) + d)) * 64 + n) * 2;
  float wlr = wlp[0], wli = wlp[1];
  float Sr = 0.f, Sj = 0.f;
  for (int c = 0; c < NC_; ++c) {
    size_t base = ((size_t)d * 256 + b * 16 + c) * 128;
    float tr2 = h2f(SL[base + n]);
    float tj  = h2f(SL[base + 64 + n]);
    SL[base + n]      = f2h(Sr);
    SL[base + 64 + n] = f2h(Sj);
    float nSr = fmaf(wlr, Sr, fmaf(wli, Sj, tr2));
    Sj = fmaf(-wli, Sr, fmaf(wlr, Sj, tj));
    Sr = nSr;
  }
}

// ---------------- scanB: GT[d][bc][t] = gelu(UT@Tn^T + SL@En^T + Pbeta) ------
__global__ __launch_bounds__(256) void scan_gemm_out(
    const unsigned short* __restrict__ UT, const unsigned short* __restrict__ Sin,
    const unsigned short* __restrict__ TnA, const unsigned short* __restrict__ EnA,
    const float* __restrict__ PbetaA, unsigned short* __restrict__ GT, int blk) {
  __shared__ __align__(16) unsigned short smem[17408];
  _Float16* As = (_Float16*)smem;
  _Float16* Bs = (_Float16*)smem + 5120;
  int bx = blockIdx.x;
  int d = bx >> 1, mh = bx & 1;
  int tid = threadIdx.x, lane = tid & 63, w = tid >> 6;
  int wm = (w & 1) << 6, wn = (w >> 1) << 6;
  const unsigned short* Au = UT + ((size_t)d * 256 + mh * 128) * 128;
  const unsigned short* Asin = Sin + ((size_t)d * 256 + mh * 128) * 128;
  const unsigned short* Bt = TnA + (size_t)(blk * 256 + d) * 16384;
  const unsigned short* Be = EnA + (size_t)(blk * 256 + d) * 16384;
  f32x4 acc[4][4];
#pragma unroll
  for (int a = 0; a < 4; ++a)
#pragma unroll
    for (int b2 = 0; b2 < 4; ++b2) acc[a][b2] = (f32x4){0.f, 0.f, 0.f, 0.f};
  int r = tid & 127, sg = (tid >> 7) << 4;
  uint4 a0 = *(const uint4*)(Au + (size_t)r * 128 + sg);
  uint4 a1 = *(const uint4*)(Au + (size_t)r * 128 + sg + 8);
  uint4 b0 = *(const uint4*)(Bt + (size_t)r * 128 + sg);
  uint4 b1 = *(const uint4*)(Bt + (size_t)r * 128 + sg + 8);
  for (int kb = 0; kb < 8; ++kb) {
    __syncthreads();
    *(uint4*)&As[r * 40 + sg] = a0; *(uint4*)&As[r * 40 + sg + 8] = a1;
    *(uint4*)&Bs[r * 40 + sg] = b0; *(uint4*)&Bs[r * 40 + sg + 8] = b1;
    __syncthreads();
    if (kb < 7) {
      int k2 = kb + 1;
      int kc = (k2 & 3) << 5;
      const unsigned short* An = (k2 < 4) ? Au : Asin;
      const unsigned short* Bn = (k2 < 4) ? Bt : Be;
      a0 = *(const uint4*)(An + (size_t)r * 128 + kc + sg);
      a1 = *(const uint4*)(An + (size_t)r * 128 + kc + sg + 8);
      b0 = *(const uint4*)(Bn + (size_t)r * 128 + kc + sg);
      b1 = *(const uint4*)(Bn + (size_t)r * 128 + kc + sg + 8);
    }
    int ko = (lane >> 4) << 3;
    half8 af[4], bf4[4];
#pragma unroll
    for (int mf = 0; mf < 4; ++mf) af[mf] = *(const half8*)&As[(wm + (mf << 4) + (lane & 15)) * 40 + ko];
#pragma unroll
    for (int nf = 0; nf < 4; ++nf) bf4[nf] = *(const half8*)&Bs[(wn + (nf << 4) + (lane & 15)) * 40 + ko];
#pragma unroll
    for (int mf = 0; mf < 4; ++mf)
#pragma unroll
      for (int nf = 0; nf < 4; ++nf)
        acc[mf][nf] = __builtin_amdgcn_mfma_f32_16x16x32_f16(af[mf], bf4[nf], acc[mf][nf], 0, 0, 0);
  }
  int cn = lane & 15, rq = lane >> 4;
  __syncthreads();
  unsigned short* epi = smem;   // [128][136]
#pragma unroll
  for (int nf = 0; nf < 4; ++nf) {
    int nl = wn + (nf << 4) + cn;
    float pb2 = PbetaA[((size_t)blk * 256 + d) * 128 + nl];
#pragma unroll
    for (int mf = 0; mf < 4; ++mf)
#pragma unroll
      for (int rr = 0; rr < 4; ++rr) {
        int ml = wm + (mf << 4) + (rq << 2) + rr;
        float xx = acc[mf][nf][rr] + pb2;
        float x3 = xx * xx * xx;
        float inner = 0.7978845608028654f * fmaf(0.044715f, x3, xx);
        float e = __expf(-2.f * fabsf(inner));
        float th = (1.f - e) / (1.f + e);
        th = copysignf(th, inner);
        epi[ml * 136 + nl] = f2h(0.5f * xx * (1.f + th));
      }
  }
  __syncthreads();
  int mr = tid >> 1, hf = (tid & 1) << 6;
  size_t gb = ((size_t)d * 256 + mh * 128 + mr) * 128 + hf;
#pragma unroll
  for (int k = 0; k < 8; ++k)
    *(uint4*)(GT + gb + k * 8) = *(const uint4*)&epi[mr * 136 + hf + k * 8];
}

// ---------------- W prep: WT[w][n][k] = fp16(W_w[k][n]) ----------------------
__global__ void wprep_kernel(const float* __restrict__ Wout, const float* __restrict__ fW1,
                             const float* __restrict__ fW2, unsigned short* __restrict__ WT) {
  __shared__ float tile[64][65];
  int wv = blockIdx.x >> 4;
  int tk = (blockIdx.x >> 2) & 3;
  int tn = blockIdx.x & 3;
  const float* src = (wv < 6) ? (Wout + (size_t)wv * 65536) : (wv == 6 ? fW1 : fW2);
  int r = threadIdx.x >> 4;
  int c = (threadIdx.x & 15) << 2;
  for (int rr = 0; rr < 64; rr += 16) {
    float4 v = *(const float4*)(src + (size_t)(tk * 64 + r + rr) * 256 + tn * 64 + c);
    tile[r + rr][c] = v.x; tile[r + rr][c + 1] = v.y;
    tile[r + rr][c + 2] = v.z; tile[r + rr][c + 3] = v.w;
  }
  __syncthreads();
  for (int rr = 0; rr < 64; rr += 16) {
    int n = r + rr;
    ushort4 o;
    o.x = f2h(tile[c + 0][n]); o.y = f2h(tile[c + 1][n]);
    o.z = f2h(tile[c + 2][n]); o.w = f2h(tile[c + 3][n]);
    *(ushort4*)(WT + (size_t)wv * 65536 + (size_t)(tn * 64 + n) * 256 + tk * 64 + c) = o;
  }
}

// ---------------- projection GEMM: hout = GT^T@W + bias + res; ut = hout^T ---
__global__ __launch_bounds__(256, 2) void gemm_gt(const unsigned short* __restrict__ GT,
    const unsigned short* __restrict__ Wt, const float* __restrict__ bias,
    const unsigned short* __restrict__ res, unsigned short* __restrict__ hout,
    unsigned short* __restrict__ ut_next) {
  __shared__ __align__(16) unsigned short smem[18432];
  unsigned short* As = smem;          // [128][72]
  unsigned short* Bs = smem + 9216;   // [128][72]
  int tid = threadIdx.x;
  int bc = blockIdx.x;
  int m0 = bc * 128, n0 = blockIdx.y * 128;
  int lane = tid & 63, w = tid >> 6;
  int wm = (w & 1) << 6, wn = (w >> 1) << 6;
  int rb = tid >> 3, cb = (tid & 7) << 3;
  int dr = tid >> 2, sg = (tid & 3) << 5;
  f32x4 acc[4][4];
#pragma unroll
  for (int mf = 0; mf < 4; ++mf)
#pragma unroll
    for (int nf = 0; nf < 4; ++nf) acc[mf][nf] = (f32x4){0.f, 0.f, 0.f, 0.f};

  uint4 gv[4], bv[4];
  {
    const uint4* grow = (const uint4*)(GT + ((size_t)(dr * 256 + bc)) * 128 + sg);
    gv[0] = grow[0]; gv[1] = grow[1]; gv[2] = grow[2]; gv[3] = grow[3];
#pragma unroll
    for (int rr = 0; rr < 4; ++rr)
      bv[rr] = *(const uint4*)(Wt + (size_t)(n0 + rb + rr * 32) * 256 + cb);
  }
  for (int kb = 0; kb < 4; ++kb) {
    __syncthreads();
    const unsigned short* pv = (const unsigned short*)gv;
#pragma unroll
    for (int i = 0; i < 32; ++i) As[(sg + i) * 72 + dr] = pv[i];
#pragma unroll
    for (int rr = 0; rr < 4; ++rr) *(uint4*)&Bs[(rb + rr * 32) * 72 + cb] = bv[rr];
    __syncthreads();
    if (kb < 3) {
      int k0 = (kb + 1) << 6;
      const uint4* grow = (const uint4*)(GT + ((size_t)((k0 + dr) * 256 + bc)) * 128 + sg);
      gv[0] = grow[0]; gv[1] = grow[1]; gv[2] = grow[2]; gv[3] = grow[3];
#pragma unroll
      for (int rr = 0; rr < 4; ++rr)
        bv[rr] = *(const uint4*)(Wt + (size_t)(n0 + rb + rr * 32) * 256 + k0 + cb);
    }
#pragma unroll
    for (int kw = 0; kw < 2; ++kw) {
      int ko = (kw << 5) + ((lane >> 4) << 3);
      half8 af[4], bfr[4];
#pragma unroll
      for (int mf = 0; mf < 4; ++mf)
        af[mf] = *(const half8*)&As[(wm + (mf << 4) + (lane & 15)) * 72 + ko];
#pragma unroll
      for (int nf = 0; nf < 4; ++nf)
        bfr[nf] = *(const half8*)&Bs[(wn + (nf << 4) + (lane & 15)) * 72 + ko];
#pragma unroll
      for (int mf = 0; mf < 4; ++mf)
#pragma unroll
        for (int nf = 0; nf < 4; ++nf)
          acc[mf][nf] = __builtin_amdgcn_mfma_f32_16x16x32_f16(af[mf], bfr[nf], acc[mf][nf], 0, 0, 0);
    }
  }
  int cn = lane & 15, rq = lane >> 4;
  __syncthreads();
  unsigned short* epi = smem;   // [128][136]
#pragma unroll
  for (int nf = 0; nf < 4; ++nf) {
    int nl = wn + (nf << 4) + cn;
    float bv2 = bias[n0 + nl];
#pragma unroll
    for (int mf = 0; mf < 4; ++mf)
#pragma unroll
      for (int r = 0; r < 4; ++r) {
        int ml = wm + (mf << 4) + (rq << 2) + r;
        float v = acc[mf][nf][r] + bv2 + h2f(res[(size_t)(m0 + ml) * 256 + n0 + nl]);
        epi[ml * 136 + nl] = f2h(v);
      }
  }
  __syncthreads();
  {
    int mr = tid >> 1, hf = (tid & 1) << 6;
    unsigned short* dst = hout + (size_t)(m0 + mr) * 256 + n0 + hf;
    const unsigned short* srow = epi + mr * 136 + hf;
#pragma unroll
    for (int k = 0; k < 8; ++k) *(uint4*)(dst + k * 8) = *(const uint4*)(srow + k * 8);
  }
  if (ut_next) {
    int nl = tid >> 1, h2 = (tid & 1) << 6;
    unsigned short* dst = ut_next + ((size_t)(n0 + nl) * 256 + bc) * 128 + h2;
#pragma unroll
    for (int k = 0; k < 8; ++k) {
      unsigned short v8[8];
#pragma unroll
      for (int e = 0; e < 8; ++e) v8[e] = epi[(h2 + k * 8 + e) * 136 + nl];
      *(uint4*)(dst + k * 8) = *(uint4*)v8;
    }
  }
}

// ---------------- FFN GEMM (row-major fp16 A): out = relu(A@W + b [+ res]) ---
__global__ __launch_bounds__(256, 2) void gemm_ffn(const unsigned short* __restrict__ A,
    const unsigned short* __restrict__ Wt, const float* __restrict__ bias,
    const unsigned short* __restrict__ res, unsigned short* __restrict__ outp) {
  __shared__ __align__(16) unsigned short smem[18432];
  unsigned short* As = smem;
  unsigned short* Bs = smem + 9216;
  int tid = threadIdx.x;
  int m0 = blockIdx.x * 128, n0 = blockIdx.y * 128;
  int lane = tid & 63, w = tid >> 6;
  int wm = (w & 1) << 6, wn = (w >> 1) << 6;
  int r0 = tid >> 3;
  int c0 = (tid & 7) << 3;
  f32x4 acc[4][4];
#pragma unroll
  for (int mf = 0; mf < 4; ++mf)
#pragma unroll
    for (int nf = 0; nf < 4; ++nf) acc[mf][nf] = (f32x4){0.f, 0.f, 0.f, 0.f};

  uint4 av[4], bv[4];
#pragma unroll
  for (int rr = 0; rr < 4; ++rr) {
    int r = r0 + rr * 32;
    av[rr] = *(const uint4*)(A + (size_t)(m0 + r) * 256 + c0);
    bv[rr] = *(const uint4*)(Wt + (size_t)(n0 + r) * 256 + c0);
  }
  for (int kb = 0; kb < 4; ++kb) {
    __syncthreads();
#pragma unroll
    for (int rr = 0; rr < 4; ++rr) {
      int r = r0 + rr * 32;
      *(uint4*)&As[r * 72 + c0] = av[rr];
      *(uint4*)&Bs[r * 72 + c0] = bv[rr];
    }
    __syncthreads();
    if (kb < 3) {
      int k0 = (kb + 1) << 6;
#pragma unroll
      for (int rr = 0; rr < 4; ++rr) {
        int r = r0 + rr * 32;
        av[rr] = *(const uint4*)(A + (size_t)(m0 + r) * 256 + k0 + c0);
        bv[rr] = *(const uint4*)(Wt + (size_t)(n0 + r) * 256 + k0 + c0);
      }
    }
#pragma unroll
    for (int kw = 0; kw < 2; ++kw) {
      int ko = (kw << 5) + ((lane >> 4) << 3);
      half8 af[4], bfr[4];
#pragma unroll
      for (int mf = 0; mf < 4; ++mf)
        af[mf] = *(const half8*)&As[(wm + (mf << 4) + (lane & 15)) * 72 + ko];
#pragma unroll
      for (int nf = 0; nf < 4; ++nf)
        bfr[nf] = *(const half8*)&Bs[(wn + (nf << 4) + (lane & 15)) * 72 + ko];
#pragma unroll
      for (int mf = 0; mf < 4; ++mf)
#pragma unroll
        for (int nf = 0; nf < 4; ++nf)
          acc[mf][nf] = __builtin_amdgcn_mfma_f32_16x16x32_f16(af[mf], bfr[nf], acc[mf][nf], 0, 0, 0);
    }
  }
  int cn = lane & 15, rq = lane >> 4;
  __syncthreads();
  unsigned short* epi = smem;   // [128][136]
#pragma unroll
  for (int nf = 0; nf < 4; ++nf) {
    int nl = wn + (nf << 4) + cn;
#pragma unroll
    for (int mf = 0; mf < 4; ++mf)
#pragma unroll
      for (int r = 0; r < 4; ++r) {
        int ml = wm + (mf << 4) + (rq << 2) + r;
        epi[ml * 136 + nl] = f2h(acc[mf][nf][r]);
      }
  }
  __syncthreads();
  int mr = tid >> 1, hf = (tid & 1) << 6;
  unsigned short* dst = outp + (size_t)(m0 + mr) * 256 + n0 + hf;
#pragma unroll
  for (int k = 0; k < 8; ++k) {
    uint4 c = *(const uint4*)&epi[mr * 136 + hf + k * 8];
    uint4 rv = (uint4){0, 0, 0, 0};
    if (res) rv = *(const uint4*)(res + (size_t)(m0 + mr) * 256 + n0 + hf + k * 8);
    const unsigned short* cp = (const unsigned short*)&c;
    const unsigned short* rp = (const unsigned short*)&rv;
    unsigned short o8[8];
#pragma unroll
    for (int e = 0; e < 8; ++e) {
      float v = h2f(cp[e]) + bias[n0 + hf + k * 8 + e];
      if (res) v += h2f(rp[e]);
      o8[e] = f2h(fmaxf(v, 0.f));
    }
    *(uint4*)(dst + k * 8) = *(uint4*)o8;
  }
}

// ---------------- head ------------------------
__global__ void head1_kernel(const unsigned short* __restrict__ H, float* __restrict__ part) {
  int b = blockIdx.x, ls = blockIdx.y, d = threadIdx.x;
  const unsigned short* p = H + ((size_t)(b * L_ + ls * 128)) * D_ + d;
  float sum = 0.f;
  for (int l = 0; l < 128; ++l) sum += h2f(p[(size_t)l * D_]);
  part[(b * 16 + ls) * D_ + d] = sum;
}

__global__ void head2_kernel(const float* __restrict__ part, const float* __restrict__ fcW,
                             const float* __restrict__ fcb, float* __restrict__ out) {
  int b = blockIdx.x, d = threadIdx.x;
  float sum = 0.f;
  for (int i = 0; i < 16; ++i) sum += part[(b * 16 + i) * D_ + d];
  __shared__ float meanv[D_];
  meanv[d] = sum * (1.0f / (float)L_);
  __syncthreads();
  if (d < 2) {
    float accv = fcb[d];
    for (int k = 0; k < D_; ++k) accv = fmaf(meanv[k], fcW[k * 2 + d], accv);
    out[b * 2 + d] = accv;
  }
}

extern "C" void kernel_launch(void* const* d_in, const int* in_sizes, int n_in,
                              void* d_out, int out_size, void* d_ws, size_t ws_size,
                              hipStream_t stream) {
  const float* x      = (const float*)d_in[0];
  const float* W_emb  = (const float*)d_in[1];
  const float* b_emb  = (const float*)d_in[2];
  const float* log_dt = (const float*)d_in[3];
  const float* logAre = (const float*)d_in[4];
  const float* Aim    = (const float*)d_in[5];
  const float* Cre    = (const float*)d_in[6];
  const float* Cim    = (const float*)d_in[7];
  const float* Dskip  = (const float*)d_in[8];
  const float* Wout   = (const float*)d_in[9];
  const float* bout   = (const float*)d_in[10];
  const float* gamma_ = (const float*)d_in[11];
  const float* beta_  = (const float*)d_in[12];
  const float* fW1    = (const float*)d_in[13];
  const float* fb1    = (const float*)d_in[14];
  const float* fW2    = (const float*)d_in[15];
  const float* fb2    = (const float*)d_in[16];
  const float* fcW    = (const float*)d_in[17];
  const float* fcb    = (const float*)d_in[18];
  float* outp = (float*)d_out;

  const size_t HSZ = (size_t)B_ * L_ * D_;   // 8388608
  // ---- workspace layout (~223 MB) ----
  float* WB     = (float*)d_ws;                         // 196608 f
  float* C2B    = WB + (size_t)NBLK_ * D_ * 128;        // 196608 f
  float* WLB    = C2B + (size_t)NBLK_ * D_ * 128;       // 196608 f
  float* PbetaA = WLB + (size_t)NBLK_ * D_ * N_ * 2;    // 196608 f
  float* SbetaA = PbetaA + (size_t)NBLK_ * 32768;       // 196608 f
  unsigned short* H   = (unsigned short*)(SbetaA + (size_t)NBLK_ * 32768);
  unsigned short* R   = H + HSZ;
  unsigned short* UT  = R + HSZ;
  unsigned short* SL  = UT + HSZ;   // GT and FFN-intermediate alias SL
  unsigned short* GT  = SL;
  unsigned short* Gbf = SL;
  unsigned short* TnA = SL + HSZ;
  unsigned short* EnA = TnA + (size_t)NBLK_ * 4194304;
  unsigned short* FnA = EnA + (size_t)NBLK_ * 4194304;
  unsigned short* WT  = FnA + (size_t)NBLK_ * 4194304;  // 524288 us

  precompute_kernel<<<(NBLK_ * D_ * N_ + 255) / 256, 256, 0, stream>>>(
      log_dt, logAre, Aim, Cre, Cim, WB, C2B, WLB);
  wprep_kernel<<<128, 256, 0, stream>>>(Wout, fW1, fW2, WT);
  build_all<<<NBLK_ * 256, 256, 0, stream>>>(WB, C2B, WLB, gamma_, beta_, Dskip,
                                             TnA, EnA, FnA, PbetaA, SbetaA);
  embed_kernel<<<(B_ * L_ * D_ + 255) / 256, 256, 0, stream>>>(x, W_emb, b_emb, H);
  trans_h_ut<<<1024, 256, 0, stream>>>(H, UT);

  const unsigned short* hin_t[6]  = {H, H, H, H, R, H};
  unsigned short*       hout_t[6] = {H, H, H, R, H, H};
  for (int i = 0; i < 6; ++i) {
    scan_gemm_state<<<512, 256, 0, stream>>>(UT, FnA, SbetaA, SL, i);
    pass2_kernel<<<1024, 256, 0, stream>>>(SL, WLB, i);
    scan_gemm_out<<<512, 256, 0, stream>>>(UT, SL, TnA, EnA, PbetaA, GT, i);
    gemm_gt<<<dim3(256, 2), 256, 0, stream>>>(
        GT, WT + (size_t)i * 65536, bout + i * D_, hin_t[i], hout_t[i],
        (i < 5) ? UT : nullptr);
  }
  // feedforward of the FS4Ddeq block + skip from R
  gemm_ffn<<<dim3(256, 2), 256, 0, stream>>>(
      H, WT + (size_t)6 * 65536, fb1, nullptr, Gbf);
  gemm_ffn<<<dim3(256, 2), 256, 0, stream>>>(
      Gbf, WT + (size_t)7 * 65536, fb2, R, H);
  head1_kernel<<<dim3(16, 16), 256, 0, stream>>>(H, WB);
  head2_kernel<<<16, 256, 0, stream>>>(WB, fcW, fcb, outp);
}

// Round 9
// 633.573 us; speedup vs baseline: 2.8065x; 1.0968x over previous
//
#include <hip/hip_runtime.h>
#include <hip/hip_fp16.h>
#include <math.h>

#define B_ 16
#define L_ 2048
#define D_ 256
#define N_ 64
#define NBLK_ 6
#define LC_ 128
#define NC_ 16

typedef _Float16 half8 __attribute__((ext_vector_type(8)));
typedef float f32x4 __attribute__((ext_vector_type(4)));

__device__ __forceinline__ unsigned short f2h(float f) {
  _Float16 h = (_Float16)f;
  return *(unsigned short*)&h;
}
__device__ __forceinline__ float h2f(unsigned short u) {
  _Float16 h = *(_Float16*)&u;
  return (float)h;
}

// ---------------- precompute per-layer SSM params ----------------
__global__ void precompute_kernel(const float* __restrict__ log_dt,
                                  const float* __restrict__ logAre,
                                  const float* __restrict__ Aim,
                                  const float* __restrict__ Cre,
                                  const float* __restrict__ Cim,
                                  float* __restrict__ wbuf,
                                  float* __restrict__ c2buf,
                                  float* __restrict__ wlbuf) {
  int idx = blockIdx.x * blockDim.x + threadIdx.x;
  if (idx >= NBLK_ * D_ * N_) return;
  int blk = idx >> 14;
  int rem = idx & 16383;
  int d = rem >> 6;
  int n = rem & 63;
  float dt   = expf(log_dt[blk * D_ + d]);
  float are  = -expf(logAre[idx]);
  float aim  = Aim[idx];
  float dtar = dt * are, dtai = dt * aim;
  float er = expf(dtar);
  float wr = er * cosf(dtai);
  float wi = er * sinf(dtai);
  float inv = 1.0f / (are * are + aim * aim);
  float wm1r = wr - 1.0f;
  float br = (wm1r * are + wi * aim) * inv;
  float bi = (wi * are - wm1r * aim) * inv;
  float crv = Cre[idx], civ = Cim[idx];
  float c2r = 2.0f * (crv * br - civ * bi);
  float c2i = 2.0f * (crv * bi + civ * br);
  float eL = expf((float)LC_ * dtar);
  float angL = (float)LC_ * dtai;
  float* wb = wbuf + (size_t)((blk << 8) + d) * 128;
  wb[n] = wr; wb[64 + n] = wi;
  float* cb = c2buf + (size_t)((blk << 8) + d) * 128;
  cb[n] = c2r; cb[64 + n] = c2i;
  wlbuf[2 * idx] = eL * cosf(angL); wlbuf[2 * idx + 1] = eL * sinf(angL);
}

// ---------------- build ALL layers' scan matrices in one dispatch ------------
__global__ __launch_bounds__(256) void build_all(
    const float* __restrict__ WB, const float* __restrict__ C2B,
    const float* __restrict__ WLB,
    const float* __restrict__ gamma_, const float* __restrict__ beta_,
    const float* __restrict__ dskip,
    unsigned short* __restrict__ TnA, unsigned short* __restrict__ EnA,
    unsigned short* __restrict__ FnA, float* __restrict__ PbetaA,
    float* __restrict__ SbetaA) {
  __shared__ float Pr[128][65];
  __shared__ float Pi_[128][65];
  __shared__ float wc[256];
  __shared__ float Kt[128];
  int bid = blockIdx.x;
  int blk = bid >> 8, d = bid & 255;
  int t = threadIdx.x;
  if (t < 128) wc[t] = WB[(size_t)((blk << 8) + d) * 128 + t];
  else         wc[t] = C2B[(size_t)((blk << 8) + d) * 128 + (t - 128)];
  __syncthreads();
  int n = t & 63, tj = t >> 6;
  float wr = wc[n], wi = wc[64 + n];
  float gd = gamma_[blk * D_ + d], bd = beta_[blk * D_ + d], dsk = dskip[blk * D_ + d];
  {
    int j0 = tj << 5;
    float pr = 1.f, pi = 0.f, br = wr, bi = wi;
    int e = j0;
    while (e) {
      if (e & 1) { float tt = pr * br - pi * bi; pi = pr * bi + pi * br; pr = tt; }
      float t2 = br * br - bi * bi; bi = 2.f * br * bi; br = t2;
      e >>= 1;
    }
#pragma unroll 4
    for (int k = 0; k < 32; ++k) {
      Pr[j0 + k][n] = pr; Pi_[j0 + k][n] = pi;
      float tt = pr * wr - pi * wi; pi = pr * wi + pi * wr; pr = tt;
    }
  }
  __syncthreads();
  if (t < 128) {
    float kc = 0.f;
    for (int nn = 0; nn < 64; ++nn)
      kc += wc[128 + nn] * Pr[t][nn] - wc[192 + nn] * Pi_[t][nn];
    Kt[t] = kc + (t == 0 ? dsk : 0.f);
  }
  size_t mbase = (size_t)(blk * 256 + d) * 16384;
#pragma unroll
  for (int r8 = 0; r8 < 8; ++r8) {
    int task = t + (r8 << 8);
    int j = task >> 4, g = task & 15;
    int half = g >> 3, n0 = (g & 7) << 3;
    unsigned short v[8];
#pragma unroll
    for (int i = 0; i < 8; ++i) {
      int nn = n0 + i;
      float pr = Pr[j][nn], pi = Pi_[j][nn];
      float wwr = wc[nn], wwi = wc[64 + nn];
      float qr = pr * wwr - pi * wwi, qi = pr * wwi + pi * wwr;
      float cr = wc[128 + nn], ci = wc[192 + nn];
      v[i] = f2h(half == 0 ? (cr * qr - ci * qi) : (cr * qi + ci * qr));
    }
    *(uint4*)(EnA + mbase + (size_t)j * 128 + (half << 6) + n0) = *(uint4*)v;
  }
#pragma unroll
  for (int r8 = 0; r8 < 8; ++r8) {
    int task = t + (r8 << 8);
    int n2 = task >> 4, tb = task & 15;
    int half = n2 >> 6, nn = n2 & 63;
    int tau0 = tb << 3;
    unsigned short v[8];
#pragma unroll
    for (int i = 0; i < 8; ++i) {
      int j = 127 - (tau0 + i);
      v[i] = f2h(half == 0 ? (gd * Pr[j][nn]) : (-gd * Pi_[j][nn]));
    }
    *(uint4*)(FnA + mbase + (size_t)n2 * 128 + tau0) = *(uint4*)v;
  }
  __syncthreads();
  if (t < 128) {
    float ps = 0.f;
    for (int t2 = 0; t2 <= t; ++t2) ps += Kt[t2];
    PbetaA[((size_t)blk * 256 + d) * 128 + t] = bd * ps;
  }
  if (t >= 128 && t < 192) {
    int nn = t - 128;
    const float* wlp = WLB + (((size_t)((blk << 8) + d)) * 64 + nn) * 2;
    float wlr = wlp[0], wli = wlp[1];
    float wwr = wc[nn], wwi = wc[64 + nn];
    float nr = wlr - 1.f, ni = wli, dr2 = wwr - 1.f, di = wwi;
    float iv = 1.f / (dr2 * dr2 + di * di);
    SbetaA[((size_t)blk * 256 + d) * 128 + nn]      = bd * ((nr * dr2 + ni * di) * iv);
    SbetaA[((size_t)blk * 256 + d) * 128 + 64 + nn] = bd * (-((ni * dr2 - nr * di) * iv));
  }
  int chunk = t & 15, rg = t >> 4;
#pragma unroll
  for (int it = 0; it < 8; ++it) {
    int trow = (it << 4) + rg;
    int tau0 = chunk << 3;
    unsigned short v[8];
#pragma unroll
    for (int i = 0; i < 8; ++i) {
      int tau = tau0 + i;
      v[i] = (tau <= trow) ? f2h(gd * Kt[trow - tau]) : (unsigned short)0;
    }
    *(uint4*)(TnA + mbase + (size_t)trow * 128 + tau0) = *(uint4*)v;
  }
}

// ---------------- embedding -> fp16 H ----------
__global__ void embed_kernel(const float* __restrict__ x, const float* __restrict__ wemb,
                             const float* __restrict__ bemb, unsigned short* __restrict__ H) {
  int tid = blockIdx.x * blockDim.x + threadIdx.x;
  if (tid >= B_ * L_ * D_) return;
  int d = tid & (D_ - 1);
  int lg = tid >> 8;
  H[tid] = f2h(fmaf(x[lg], wemb[d], bemb[d]));
}

// ---------------- transpose H [b][l][d] fp16 -> UT [d][bc][tau] fp16 ---------
__global__ __launch_bounds__(256) void trans_h_ut(const unsigned short* __restrict__ H,
                                                  unsigned short* __restrict__ UT) {
  __shared__ __align__(16) unsigned short lds[64][136];
  int bi = blockIdx.x;
  int bc = bi >> 2, dq = bi & 3;
  int b = bc >> 4, ch = bc & 15;
  int tid = threadIdx.x;
  const unsigned short* src = H + ((size_t)(b * L_ + ch * 128)) * D_ + dq * 64;
  int tau0 = tid >> 4;
  int dl = (tid & 15) << 2;
  for (int tt = 0; tt < 128; tt += 16) {
    ushort4 v = *(const ushort4*)(src + (size_t)(tt + tau0) * D_ + dl);
    lds[dl + 0][tt + tau0] = v.x;
    lds[dl + 1][tt + tau0] = v.y;
    lds[dl + 2][tt + tau0] = v.z;
    lds[dl + 3][tt + tau0] = v.w;
  }
  __syncthreads();
  int r = tid >> 2, seg = (tid & 3) << 5;
  unsigned short* dst = UT + ((size_t)((dq * 64 + r) * 256 + bc)) * 128 + seg;
  const unsigned short* srow = &lds[r][seg];
  *(uint4*)(dst + 0)  = *(const uint4*)(srow + 0);
  *(uint4*)(dst + 8)  = *(const uint4*)(srow + 8);
  *(uint4*)(dst + 16) = *(const uint4*)(srow + 16);
  *(uint4*)(dst + 24) = *(const uint4*)(srow + 24);
}

// ---------------- fused scan: scanA + chunk-combine + scanB, one block per d -
// LDS: SL[256][136] fp16 local/entering states; staging As/Bs 128x40.
// Phase1: SL = UT[d] @ Fn^T + Sbeta.  Phase2: in-LDS exclusive chunk combine.
// Phase3: GT[d] = gelu(UT@Tn^T + SL@En^T + Pbeta), SL A-operand read directly
// from LDS; epilogue reuses freed SL rows for the coalesced-store transpose.
__global__ __launch_bounds__(256) void scan_fused(
    const unsigned short* __restrict__ UT, const unsigned short* __restrict__ FnA,
    const unsigned short* __restrict__ TnA, const unsigned short* __restrict__ EnA,
    const float* __restrict__ SbetaA, const float* __restrict__ PbetaA,
    const float* __restrict__ WLB, unsigned short* __restrict__ GT, int blk) {
  __shared__ __align__(16) unsigned short SLl[256 * 136];
  __shared__ __align__(16) unsigned short AsB[128 * 40];
  __shared__ __align__(16) unsigned short BsB[128 * 40];
  _Float16* As = (_Float16*)AsB;
  _Float16* Bs = (_Float16*)BsB;
  int d = blockIdx.x;
  int tid = threadIdx.x, lane = tid & 63, w = tid >> 6;
  int wm = (w & 1) << 6, wn = (w >> 1) << 6;
  int r = tid & 127, sg = (tid >> 7) << 4;
  int cn = lane & 15, rq = lane >> 4;
  int ko = (lane >> 4) << 3;
  const unsigned short* Au = UT + (size_t)d * 256 * 128;
  const unsigned short* Bf = FnA + (size_t)(blk * 256 + d) * 16384;
  const unsigned short* Bt = TnA + (size_t)(blk * 256 + d) * 16384;
  const unsigned short* Be = EnA + (size_t)(blk * 256 + d) * 16384;
  size_t pb = ((size_t)blk * 256 + d) * 128;

  // ---------- phase 1: SL = UT @ Fn^T + Sbeta ----------
  for (int mh = 0; mh < 2; ++mh) {
    const unsigned short* Ab = Au + (size_t)(mh << 7) * 128;
    f32x4 acc[4][4];
#pragma unroll
    for (int a = 0; a < 4; ++a)
#pragma unroll
      for (int b2 = 0; b2 < 4; ++b2) acc[a][b2] = (f32x4){0.f, 0.f, 0.f, 0.f};
    uint4 a0 = *(const uint4*)(Ab + (size_t)r * 128 + sg);
    uint4 a1 = *(const uint4*)(Ab + (size_t)r * 128 + sg + 8);
    uint4 b0 = *(const uint4*)(Bf + (size_t)r * 128 + sg);
    uint4 b1 = *(const uint4*)(Bf + (size_t)r * 128 + sg + 8);
    for (int kc = 0; kc < 128; kc += 32) {
      __syncthreads();
      *(uint4*)&As[r * 40 + sg] = a0; *(uint4*)&As[r * 40 + sg + 8] = a1;
      *(uint4*)&Bs[r * 40 + sg] = b0; *(uint4*)&Bs[r * 40 + sg + 8] = b1;
      __syncthreads();
      if (kc < 96) {
        a0 = *(const uint4*)(Ab + (size_t)r * 128 + kc + 32 + sg);
        a1 = *(const uint4*)(Ab + (size_t)r * 128 + kc + 32 + sg + 8);
        b0 = *(const uint4*)(Bf + (size_t)r * 128 + kc + 32 + sg);
        b1 = *(const uint4*)(Bf + (size_t)r * 128 + kc + 32 + sg + 8);
      }
      half8 af[4], bf4[4];
#pragma unroll
      for (int mf = 0; mf < 4; ++mf) af[mf] = *(const half8*)&As[(wm + (mf << 4) + cn) * 40 + ko];
#pragma unroll
      for (int nf = 0; nf < 4; ++nf) bf4[nf] = *(const half8*)&Bs[(wn + (nf << 4) + cn) * 40 + ko];
#pragma unroll
      for (int mf = 0; mf < 4; ++mf)
#pragma unroll
        for (int nf = 0; nf < 4; ++nf)
          acc[mf][nf] = __builtin_amdgcn_mfma_f32_16x16x32_f16(af[mf], bf4[nf], acc[mf][nf], 0, 0, 0);
    }
#pragma unroll
    for (int nf = 0; nf < 4; ++nf) {
      int nl = wn + (nf << 4) + cn;
      float sb = SbetaA[pb + nl];
#pragma unroll
      for (int mf = 0; mf < 4; ++mf)
#pragma unroll
        for (int rr = 0; rr < 4; ++rr) {
          int row = (mh << 7) + wm + (mf << 4) + (rq << 2) + rr;
          SLl[row * 136 + nl] = f2h(acc[mf][nf][rr] + sb);
        }
    }
  }
  __syncthreads();

  // ---------- phase 2: exclusive chunk-state combine in LDS ----------
  for (int task = tid; task < 1024; task += 256) {
    int b = task >> 6, n = task & 63;
    const float* wlp = WLB + (((size_t)((blk << 8) + d)) * 64 + n) * 2;
    float wlr = wlp[0], wli = wlp[1];
    float Sr = 0.f, Sj = 0.f;
    for (int c = 0; c < NC_; ++c) {
      int row = (b << 4) + c;
      float tr2 = h2f(SLl[row * 136 + n]);
      float tj  = h2f(SLl[row * 136 + 64 + n]);
      SLl[row * 136 + n]      = f2h(Sr);
      SLl[row * 136 + 64 + n] = f2h(Sj);
      float nSr = fmaf(wlr, Sr, fmaf(wli, Sj, tr2));
      Sj = fmaf(-wli, Sr, fmaf(wlr, Sj, tj));
      Sr = nSr;
    }
  }
  __syncthreads();

  // ---------- phase 3: GT = gelu(UT@Tn^T + SL@En^T + Pbeta) ----------
  for (int mh = 0; mh < 2; ++mh) {
    const unsigned short* Ab = Au + (size_t)(mh << 7) * 128;
    const _Float16* SA = (const _Float16*)SLl + (size_t)(mh << 7) * 136;
    f32x4 acc[4][4];
#pragma unroll
    for (int a = 0; a < 4; ++a)
#pragma unroll
      for (int b2 = 0; b2 < 4; ++b2) acc[a][b2] = (f32x4){0.f, 0.f, 0.f, 0.f};
    uint4 a0 = *(const uint4*)(Ab + (size_t)r * 128 + sg);
    uint4 a1 = *(const uint4*)(Ab + (size_t)r * 128 + sg + 8);
    uint4 b0 = *(const uint4*)(Bt + (size_t)r * 128 + sg);
    uint4 b1 = *(const uint4*)(Bt + (size_t)r * 128 + sg + 8);
    for (int kb = 0; kb < 8; ++kb) {
      __syncthreads();
      if (kb < 4) { *(uint4*)&As[r * 40 + sg] = a0; *(uint4*)&As[r * 40 + sg + 8] = a1; }
      *(uint4*)&Bs[r * 40 + sg] = b0; *(uint4*)&Bs[r * 40 + sg + 8] = b1;
      __syncthreads();
      if (kb < 3) {
        int kc = (kb + 1) << 5;
        a0 = *(const uint4*)(Ab + (size_t)r * 128 + kc + sg);
        a1 = *(const uint4*)(Ab + (size_t)r * 128 + kc + sg + 8);
        b0 = *(const uint4*)(Bt + (size_t)r * 128 + kc + sg);
        b1 = *(const uint4*)(Bt + (size_t)r * 128 + kc + sg + 8);
      } else if (kb < 7) {
        int kc = (kb - 3) << 5;   // En chunk for k2 = kb+1
        b0 = *(const uint4*)(Be + (size_t)r * 128 + kc + sg);
        b1 = *(const uint4*)(Be + (size_t)r * 128 + kc + sg + 8);
      }
      half8 af[4], bf4[4];
      if (kb < 4) {
#pragma unroll
        for (int mf = 0; mf < 4; ++mf) af[mf] = *(const half8*)&As[(wm + (mf << 4) + cn) * 40 + ko];
      } else {
        int kof = ((kb - 4) << 5) + ko;
#pragma unroll
        for (int mf = 0; mf < 4; ++mf) af[mf] = *(const half8*)&SA[(wm + (mf << 4) + cn) * 136 + kof];
      }
#pragma unroll
      for (int nf = 0; nf < 4; ++nf) bf4[nf] = *(const half8*)&Bs[(wn + (nf << 4) + cn) * 40 + ko];
#pragma unroll
      for (int mf = 0; mf < 4; ++mf)
#pragma unroll
        for (int nf = 0; nf < 4; ++nf)
          acc[mf][nf] = __builtin_amdgcn_mfma_f32_16x16x32_f16(af[mf], bf4[nf], acc[mf][nf], 0, 0, 0);
    }
    __syncthreads();   // all waves done reading SL rows of this mh
    unsigned short* epi = SLl + (size_t)(mh << 7) * 136;
#pragma unroll
    for (int nf = 0; nf < 4; ++nf) {
      int nl = wn + (nf << 4) + cn;
      float pb2 = PbetaA[pb + nl];
#pragma unroll
      for (int mf = 0; mf < 4; ++mf)
#pragma unroll
        for (int rr = 0; rr < 4; ++rr) {
          int ml = wm + (mf << 4) + (rq << 2) + rr;
          float xx = acc[mf][nf][rr] + pb2;
          float x3 = xx * xx * xx;
          float inner = 0.7978845608028654f * fmaf(0.044715f, x3, xx);
          float e = __expf(-2.f * fabsf(inner));
          float th = (1.f - e) / (1.f + e);
          th = copysignf(th, inner);
          epi[ml * 136 + nl] = f2h(0.5f * xx * (1.f + th));
        }
    }
    __syncthreads();
    int mr = tid >> 1, hf = (tid & 1) << 6;
    size_t gb = ((size_t)d * 256 + (mh << 7) + mr) * 128 + hf;
#pragma unroll
    for (int k = 0; k < 8; ++k)
      *(uint4*)(GT + gb + k * 8) = *(const uint4*)&epi[mr * 136 + hf + k * 8];
  }
}

// ---------------- W prep: WT[w][n][k] = fp16(W_w[k][n]) ----------------------
__global__ void wprep_kernel(const float* __restrict__ Wout, const float* __restrict__ fW1,
                             const float* __restrict__ fW2, unsigned short* __restrict__ WT) {
  __shared__ float tile[64][65];
  int wv = blockIdx.x >> 4;
  int tk = (blockIdx.x >> 2) & 3;
  int tn = blockIdx.x & 3;
  const float* src = (wv < 6) ? (Wout + (size_t)wv * 65536) : (wv == 6 ? fW1 : fW2);
  int r = threadIdx.x >> 4;
  int c = (threadIdx.x & 15) << 2;
  for (int rr = 0; rr < 64; rr += 16) {
    float4 v = *(const float4*)(src + (size_t)(tk * 64 + r + rr) * 256 + tn * 64 + c);
    tile[r + rr][c] = v.x; tile[r + rr][c + 1] = v.y;
    tile[r + rr][c + 2] = v.z; tile[r + rr][c + 3] = v.w;
  }
  __syncthreads();
  for (int rr = 0; rr < 64; rr += 16) {
    int n = r + rr;
    ushort4 o;
    o.x = f2h(tile[c + 0][n]); o.y = f2h(tile[c + 1][n]);
    o.z = f2h(tile[c + 2][n]); o.w = f2h(tile[c + 3][n]);
    *(ushort4*)(WT + (size_t)wv * 65536 + (size_t)(tn * 64 + n) * 256 + tk * 64 + c) = o;
  }
}

// ---------------- projection GEMM: hout = GT^T@W + bias + res; ut = hout^T ---
// 1-D grid of 512: bc = bid&255, n-half = bid>>8 (pairs land on same XCD).
__global__ __launch_bounds__(256, 2) void gemm_gt(const unsigned short* __restrict__ GT,
    const unsigned short* __restrict__ Wt, const float* __restrict__ bias,
    const unsigned short* __restrict__ res, unsigned short* __restrict__ hout,
    unsigned short* __restrict__ ut_next) {
  __shared__ __align__(16) unsigned short smem[18432];
  unsigned short* As = smem;
  unsigned short* Bs = smem + 9216;
  int tid = threadIdx.x;
  int bid = blockIdx.x;
  int bc = bid & 255;
  int m0 = bc * 128, n0 = (bid >> 8) << 7;
  int lane = tid & 63, w = tid >> 6;
  int wm = (w & 1) << 6, wn = (w >> 1) << 6;
  int rb = tid >> 3, cb = (tid & 7) << 3;
  int dr = tid >> 2, sg = (tid & 3) << 5;
  f32x4 acc[4][4];
#pragma unroll
  for (int mf = 0; mf < 4; ++mf)
#pragma unroll
    for (int nf = 0; nf < 4; ++nf) acc[mf][nf] = (f32x4){0.f, 0.f, 0.f, 0.f};

  uint4 gv[4], bv[4];
  {
    const uint4* grow = (const uint4*)(GT + ((size_t)(dr * 256 + bc)) * 128 + sg);
    gv[0] = grow[0]; gv[1] = grow[1]; gv[2] = grow[2]; gv[3] = grow[3];
#pragma unroll
    for (int rr = 0; rr < 4; ++rr)
      bv[rr] = *(const uint4*)(Wt + (size_t)(n0 + rb + rr * 32) * 256 + cb);
  }
  for (int kb = 0; kb < 4; ++kb) {
    __syncthreads();
    const unsigned short* pv = (const unsigned short*)gv;
#pragma unroll
    for (int i = 0; i < 32; ++i) As[(sg + i) * 72 + dr] = pv[i];
#pragma unroll
    for (int rr = 0; rr < 4; ++rr) *(uint4*)&Bs[(rb + rr * 32) * 72 + cb] = bv[rr];
    __syncthreads();
    if (kb < 3) {
      int k0 = (kb + 1) << 6;
      const uint4* grow = (const uint4*)(GT + ((size_t)((k0 + dr) * 256 + bc)) * 128 + sg);
      gv[0] = grow[0]; gv[1] = grow[1]; gv[2] = grow[2]; gv[3] = grow[3];
#pragma unroll
      for (int rr = 0; rr < 4; ++rr)
        bv[rr] = *(const uint4*)(Wt + (size_t)(n0 + rb + rr * 32) * 256 + k0 + cb);
    }
#pragma unroll
    for (int kw = 0; kw < 2; ++kw) {
      int ko = (kw << 5) + ((lane >> 4) << 3);
      half8 af[4], bfr[4];
#pragma unroll
      for (int mf = 0; mf < 4; ++mf)
        af[mf] = *(const half8*)&As[(wm + (mf << 4) + (lane & 15)) * 72 + ko];
#pragma unroll
      for (int nf = 0; nf < 4; ++nf)
        bfr[nf] = *(const half8*)&Bs[(wn + (nf << 4) + (lane & 15)) * 72 + ko];
#pragma unroll
      for (int mf = 0; mf < 4; ++mf)
#pragma unroll
        for (int nf = 0; nf < 4; ++nf)
          acc[mf][nf] = __builtin_amdgcn_mfma_f32_16x16x32_f16(af[mf], bfr[nf], acc[mf][nf], 0, 0, 0);
    }
  }
  int cn = lane & 15, rq = lane >> 4;
  __syncthreads();
  unsigned short* epi = smem;   // [128][136]
#pragma unroll
  for (int nf = 0; nf < 4; ++nf) {
    int nl = wn + (nf << 4) + cn;
    float bv2 = bias[n0 + nl];
#pragma unroll
    for (int mf = 0; mf < 4; ++mf)
#pragma unroll
      for (int r = 0; r < 4; ++r) {
        int ml = wm + (mf << 4) + (rq << 2) + r;
        float v = acc[mf][nf][r] + bv2 + h2f(res[(size_t)(m0 + ml) * 256 + n0 + nl]);
        epi[ml * 136 + nl] = f2h(v);
      }
  }
  __syncthreads();
  {
    int mr = tid >> 1, hf = (tid & 1) << 6;
    unsigned short* dst = hout + (size_t)(m0 + mr) * 256 + n0 + hf;
    const unsigned short* srow = epi + mr * 136 + hf;
#pragma unroll
    for (int k = 0; k < 8; ++k) *(uint4*)(dst + k * 8) = *(const uint4*)(srow + k * 8);
  }
  if (ut_next) {
    int nl = tid >> 1, h2 = (tid & 1) << 6;
    unsigned short* dst = ut_next + ((size_t)(n0 + nl) * 256 + bc) * 128 + h2;
#pragma unroll
    for (int k = 0; k < 8; ++k) {
      unsigned short v8[8];
#pragma unroll
      for (int e = 0; e < 8; ++e) v8[e] = epi[(h2 + k * 8 + e) * 136 + nl];
      *(uint4*)(dst + k * 8) = *(uint4*)v8;
    }
  }
}

// ---------------- FFN GEMM: out = relu(A@W + b [+ res]), XCD-paired grid -----
__global__ __launch_bounds__(256, 2) void gemm_ffn(const unsigned short* __restrict__ A,
    const unsigned short* __restrict__ Wt, const float* __restrict__ bias,
    const unsigned short* __restrict__ res, unsigned short* __restrict__ outp) {
  __shared__ __align__(16) unsigned short smem[18432];
  unsigned short* As = smem;
  unsigned short* Bs = smem + 9216;
  int tid = threadIdx.x;
  int bid = blockIdx.x;
  int m0 = (bid & 255) << 7, n0 = (bid >> 8) << 7;
  int lane = tid & 63, w = tid >> 6;
  int wm = (w & 1) << 6, wn = (w >> 1) << 6;
  int r0 = tid >> 3;
  int c0 = (tid & 7) << 3;
  f32x4 acc[4][4];
#pragma unroll
  for (int mf = 0; mf < 4; ++mf)
#pragma unroll
    for (int nf = 0; nf < 4; ++nf) acc[mf][nf] = (f32x4){0.f, 0.f, 0.f, 0.f};

  uint4 av[4], bv[4];
#pragma unroll
  for (int rr = 0; rr < 4; ++rr) {
    int r = r0 + rr * 32;
    av[rr] = *(const uint4*)(A + (size_t)(m0 + r) * 256 + c0);
    bv[rr] = *(const uint4*)(Wt + (size_t)(n0 + r) * 256 + c0);
  }
  for (int kb = 0; kb < 4; ++kb) {
    __syncthreads();
#pragma unroll
    for (int rr = 0; rr < 4; ++rr) {
      int r = r0 + rr * 32;
      *(uint4*)&As[r * 72 + c0] = av[rr];
      *(uint4*)&Bs[r * 72 + c0] = bv[rr];
    }
    __syncthreads();
    if (kb < 3) {
      int k0 = (kb + 1) << 6;
#pragma unroll
      for (int rr = 0; rr < 4; ++rr) {
        int r = r0 + rr * 32;
        av[rr] = *(const uint4*)(A + (size_t)(m0 + r) * 256 + k0 + c0);
        bv[rr] = *(const uint4*)(Wt + (size_t)(n0 + r) * 256 + k0 + c0);
      }
    }
#pragma unroll
    for (int kw = 0; kw < 2; ++kw) {
      int ko = (kw << 5) + ((lane >> 4) << 3);
      half8 af[4], bfr[4];
#pragma unroll
      for (int mf = 0; mf < 4; ++mf)
        af[mf] = *(const half8*)&As[(wm + (mf << 4) + (lane & 15)) * 72 + ko];
#pragma unroll
      for (int nf = 0; nf < 4; ++nf)
        bfr[nf] = *(const half8*)&Bs[(wn + (nf << 4) + (lane & 15)) * 72 + ko];
#pragma unroll
      for (int mf = 0; mf < 4; ++mf)
#pragma unroll
        for (int nf = 0; nf < 4; ++nf)
          acc[mf][nf] = __builtin_amdgcn_mfma_f32_16x16x32_f16(af[mf], bfr[nf], acc[mf][nf], 0, 0, 0);
    }
  }
  int cn = lane & 15, rq = lane >> 4;
  __syncthreads();
  unsigned short* epi = smem;
#pragma unroll
  for (int nf = 0; nf < 4; ++nf) {
    int nl = wn + (nf << 4) + cn;
#pragma unroll
    for (int mf = 0; mf < 4; ++mf)
#pragma unroll
      for (int r = 0; r < 4; ++r) {
        int ml = wm + (mf << 4) + (rq << 2) + r;
        epi[ml * 136 + nl] = f2h(acc[mf][nf][r]);
      }
  }
  __syncthreads();
  int mr = tid >> 1, hf = (tid & 1) << 6;
  unsigned short* dst = outp + (size_t)(m0 + mr) * 256 + n0 + hf;
#pragma unroll
  for (int k = 0; k < 8; ++k) {
    uint4 c = *(const uint4*)&epi[mr * 136 + hf + k * 8];
    uint4 rv = (uint4){0, 0, 0, 0};
    if (res) rv = *(const uint4*)(res + (size_t)(m0 + mr) * 256 + n0 + hf + k * 8);
    const unsigned short* cp = (const unsigned short*)&c;
    const unsigned short* rp = (const unsigned short*)&rv;
    unsigned short o8[8];
#pragma unroll
    for (int e = 0; e < 8; ++e) {
      float v = h2f(cp[e]) + bias[n0 + hf + k * 8 + e];
      if (res) v += h2f(rp[e]);
      o8[e] = f2h(fmaxf(v, 0.f));
    }
    *(uint4*)(dst + k * 8) = *(uint4*)o8;
  }
}

// ---------------- head ------------------------
__global__ void head1_kernel(const unsigned short* __restrict__ H, float* __restrict__ part) {
  int b = blockIdx.x, ls = blockIdx.y, d = threadIdx.x;
  const unsigned short* p = H + ((size_t)(b * L_ + ls * 128)) * D_ + d;
  float sum = 0.f;
  for (int l = 0; l < 128; ++l) sum += h2f(p[(size_t)l * D_]);
  part[(b * 16 + ls) * D_ + d] = sum;
}

__global__ void head2_kernel(const float* __restrict__ part, const float* __restrict__ fcW,
                             const float* __restrict__ fcb, float* __restrict__ out) {
  int b = blockIdx.x, d = threadIdx.x;
  float sum = 0.f;
  for (int i = 0; i < 16; ++i) sum += part[(b * 16 + i) * D_ + d];
  __shared__ float meanv[D_];
  meanv[d] = sum * (1.0f / (float)L_);
  __syncthreads();
  if (d < 2) {
    float accv = fcb[d];
    for (int k = 0; k < D_; ++k) accv = fmaf(meanv[k], fcW[k * 2 + d], accv);
    out[b * 2 + d] = accv;
  }
}

extern "C" void kernel_launch(void* const* d_in, const int* in_sizes, int n_in,
                              void* d_out, int out_size, void* d_ws, size_t ws_size,
                              hipStream_t stream) {
  const float* x      = (const float*)d_in[0];
  const float* W_emb  = (const float*)d_in[1];
  const float* b_emb  = (const float*)d_in[2];
  const float* log_dt = (const float*)d_in[3];
  const float* logAre = (const float*)d_in[4];
  const float* Aim    = (const float*)d_in[5];
  const float* Cre    = (const float*)d_in[6];
  const float* Cim    = (const float*)d_in[7];
  const float* Dskip  = (const float*)d_in[8];
  const float* Wout   = (const float*)d_in[9];
  const float* bout   = (const float*)d_in[10];
  const float* gamma_ = (const float*)d_in[11];
  const float* beta_  = (const float*)d_in[12];
  const float* fW1    = (const float*)d_in[13];
  const float* fb1    = (const float*)d_in[14];
  const float* fW2    = (const float*)d_in[15];
  const float* fb2    = (const float*)d_in[16];
  const float* fcW    = (const float*)d_in[17];
  const float* fcb    = (const float*)d_in[18];
  float* outp = (float*)d_out;

  const size_t HSZ = (size_t)B_ * L_ * D_;   // 8388608
  float* WB     = (float*)d_ws;
  float* C2B    = WB + (size_t)NBLK_ * D_ * 128;
  float* WLB    = C2B + (size_t)NBLK_ * D_ * 128;
  float* PbetaA = WLB + (size_t)NBLK_ * D_ * N_ * 2;
  float* SbetaA = PbetaA + (size_t)NBLK_ * 32768;
  unsigned short* H   = (unsigned short*)(SbetaA + (size_t)NBLK_ * 32768);
  unsigned short* R   = H + HSZ;
  unsigned short* UT  = R + HSZ;
  unsigned short* GT  = UT + HSZ;
  unsigned short* Gbf = GT;     // FFN intermediate aliases GT (dead after layer 5)
  unsigned short* TnA = GT + HSZ;
  unsigned short* EnA = TnA + (size_t)NBLK_ * 4194304;
  unsigned short* FnA = EnA + (size_t)NBLK_ * 4194304;
  unsigned short* WT  = FnA + (size_t)NBLK_ * 4194304;

  precompute_kernel<<<(NBLK_ * D_ * N_ + 255) / 256, 256, 0, stream>>>(
      log_dt, logAre, Aim, Cre, Cim, WB, C2B, WLB);
  wprep_kernel<<<128, 256, 0, stream>>>(Wout, fW1, fW2, WT);
  build_all<<<NBLK_ * 256, 256, 0, stream>>>(WB, C2B, WLB, gamma_, beta_, Dskip,
                                             TnA, EnA, FnA, PbetaA, SbetaA);
  embed_kernel<<<(B_ * L_ * D_ + 255) / 256, 256, 0, stream>>>(x, W_emb, b_emb, H);
  trans_h_ut<<<1024, 256, 0, stream>>>(H, UT);

  const unsigned short* hin_t[6]  = {H, H, H, H, R, H};
  unsigned short*       hout_t[6] = {H, H, H, R, H, H};
  for (int i = 0; i < 6; ++i) {
    scan_fused<<<256, 256, 0, stream>>>(UT, FnA, TnA, EnA, SbetaA, PbetaA, WLB, GT, i);
    gemm_gt<<<512, 256, 0, stream>>>(
        GT, WT + (size_t)i * 65536, bout + i * D_, hin_t[i], hout_t[i],
        (i < 5) ? UT : nullptr);
  }
  // feedforward of the FS4Ddeq block + skip from R
  gemm_ffn<<<512, 256, 0, stream>>>(H, WT + (size_t)6 * 65536, fb1, nullptr, Gbf);
  gemm_ffn<<<512, 256, 0, stream>>>(Gbf, WT + (size_t)7 * 65536, fb2, R, H);
  head1_kernel<<<dim3(16, 16), 256, 0, stream>>>(H, WB);
  head2_kernel<<<16, 256, 0, stream>>>(WB, fcW, fcb, outp);
}

// Round 10
// 610.529 us; speedup vs baseline: 2.9124x; 1.0377x over previous
//
#include <hip/hip_runtime.h>
#include <hip/hip_fp16.h>
#include <math.h>

#define B_ 16
#define L_ 2048
#define D_ 256
#define N_ 64
#define NBLK_ 6
#define LC_ 128
#define NC_ 16

typedef _Float16 half8 __attribute__((ext_vector_type(8)));
typedef float f32x4 __attribute__((ext_vector_type(4)));

__device__ __forceinline__ unsigned short f2h(float f) {
  _Float16 h = (_Float16)f;
  return *(unsigned short*)&h;
}
__device__ __forceinline__ float h2f(unsigned short u) {
  _Float16 h = *(_Float16*)&u;
  return (float)h;
}

// ---------------- precompute per-layer SSM params ----------------
__global__ void precompute_kernel(const float* __restrict__ log_dt,
                                  const float* __restrict__ logAre,
                                  const float* __restrict__ Aim,
                                  const float* __restrict__ Cre,
                                  const float* __restrict__ Cim,
                                  float* __restrict__ wbuf,
                                  float* __restrict__ c2buf,
                                  float* __restrict__ wlbuf) {
  int idx = blockIdx.x * blockDim.x + threadIdx.x;
  if (idx >= NBLK_ * D_ * N_) return;
  int blk = idx >> 14;
  int rem = idx & 16383;
  int d = rem >> 6;
  int n = rem & 63;
  float dt   = expf(log_dt[blk * D_ + d]);
  float are  = -expf(logAre[idx]);
  float aim  = Aim[idx];
  float dtar = dt * are, dtai = dt * aim;
  float er = expf(dtar);
  float wr = er * cosf(dtai);
  float wi = er * sinf(dtai);
  float inv = 1.0f / (are * are + aim * aim);
  float wm1r = wr - 1.0f;
  float br = (wm1r * are + wi * aim) * inv;
  float bi = (wi * are - wm1r * aim) * inv;
  float crv = Cre[idx], civ = Cim[idx];
  float c2r = 2.0f * (crv * br - civ * bi);
  float c2i = 2.0f * (crv * bi + civ * br);
  float eL = expf((float)LC_ * dtar);
  float angL = (float)LC_ * dtai;
  float* wb = wbuf + (size_t)((blk << 8) + d) * 128;
  wb[n] = wr; wb[64 + n] = wi;
  float* cb = c2buf + (size_t)((blk << 8) + d) * 128;
  cb[n] = c2r; cb[64 + n] = c2i;
  wlbuf[2 * idx] = eL * cosf(angL); wlbuf[2 * idx + 1] = eL * sinf(angL);
}

// ---------------- embedding -> fp16 H ----------
__global__ void embed_kernel(const float* __restrict__ x, const float* __restrict__ wemb,
                             const float* __restrict__ bemb, unsigned short* __restrict__ H) {
  int tid = blockIdx.x * blockDim.x + threadIdx.x;
  if (tid >= B_ * L_ * D_) return;
  int d = tid & (D_ - 1);
  int lg = tid >> 8;
  H[tid] = f2h(fmaf(x[lg], wemb[d], bemb[d]));
}

// ---------------- transpose H [b][l][d] fp16 -> UT [d][bc][tau] fp16 ---------
__global__ __launch_bounds__(256) void trans_h_ut(const unsigned short* __restrict__ H,
                                                  unsigned short* __restrict__ UT) {
  __shared__ __align__(16) unsigned short lds[64][136];
  int bi = blockIdx.x;
  int bc = bi >> 2, dq = bi & 3;
  int b = bc >> 4, ch = bc & 15;
  int tid = threadIdx.x;
  const unsigned short* src = H + ((size_t)(b * L_ + ch * 128)) * D_ + dq * 64;
  int tau0 = tid >> 4;
  int dl = (tid & 15) << 2;
  for (int tt = 0; tt < 128; tt += 16) {
    ushort4 v = *(const ushort4*)(src + (size_t)(tt + tau0) * D_ + dl);
    lds[dl + 0][tt + tau0] = v.x;
    lds[dl + 1][tt + tau0] = v.y;
    lds[dl + 2][tt + tau0] = v.z;
    lds[dl + 3][tt + tau0] = v.w;
  }
  __syncthreads();
  int r = tid >> 2, seg = (tid & 3) << 5;
  unsigned short* dst = UT + ((size_t)((dq * 64 + r) * 256 + bc)) * 128 + seg;
  const unsigned short* srow = &lds[r][seg];
  *(uint4*)(dst + 0)  = *(const uint4*)(srow + 0);
  *(uint4*)(dst + 8)  = *(const uint4*)(srow + 8);
  *(uint4*)(dst + 16) = *(const uint4*)(srow + 16);
  *(uint4*)(dst + 24) = *(const uint4*)(srow + 24);
}

// ---------------- fully-fused scan: matrices generated in LDS ---------------
// One block per d. Phase 0: powers w^j -> Fn (Bm1), En (Bm2), K, Pbeta, Sbeta
// all in LDS. Phase 1: SL = UT@Fn^T + Sbeta (B resident). Phase 2: in-LDS
// chunk combine. Then Bm1 overwritten with Toeplitz Tn. Phase 3:
// GT = gelu(UT@Tn^T + SL@En^T + Pbeta), SL A-operand direct from LDS.
__global__ __launch_bounds__(256) void scan_fused(
    const unsigned short* __restrict__ UT,
    const float* __restrict__ WB, const float* __restrict__ C2B,
    const float* __restrict__ WLB,
    const float* __restrict__ gamma_, const float* __restrict__ beta_,
    const float* __restrict__ dskip,
    unsigned short* __restrict__ GT, int blk) {
  __shared__ __align__(16) unsigned short SLl[256 * 136];   // 69632 B
  __shared__ __align__(16) unsigned short Bm1[128 * 136];   // 34816 B (Fn -> Tn)
  __shared__ __align__(16) unsigned short Bm2[128 * 136];   // 34816 B (En)
  __shared__ __align__(16) unsigned short AsB[128 * 40];    // 10240 B
  __shared__ float wc[256];
  __shared__ float Kt[128];
  __shared__ float Pb[128];
  __shared__ float Sb[128];
  _Float16* As = (_Float16*)AsB;
  int d = blockIdx.x;
  int tid = threadIdx.x, lane = tid & 63, w = tid >> 6;
  int wm = (w & 1) << 6, wn = (w >> 1) << 6;
  int r = tid & 127, sg = (tid >> 7) << 4;
  int cn = lane & 15, rq = lane >> 4;
  int ko = (lane >> 4) << 3;
  const unsigned short* Au = UT + (size_t)d * 256 * 128;

  // ---------- phase 0: generate Fn, En, K, Sbeta, Pbeta in LDS ----------
  if (tid < 128) wc[tid] = WB[(size_t)((blk << 8) + d) * 128 + tid];
  else           wc[tid] = C2B[(size_t)((blk << 8) + d) * 128 + (tid - 128)];
  __syncthreads();
  int n = tid & 63, tj = tid >> 6;
  float gd = gamma_[blk * D_ + d], bd = beta_[blk * D_ + d], dsk = dskip[blk * D_ + d];
  {
    float wr = wc[n], wi = wc[64 + n];
    float c2r = wc[128 + n], c2i = wc[192 + n];
    int j0 = tj << 5;
    float pr = 1.f, pi = 0.f, br = wr, bi = wi;
    int e = j0;
    while (e) {
      if (e & 1) { float tt = pr * br - pi * bi; pi = pr * bi + pi * br; pr = tt; }
      float t2 = br * br - bi * bi; bi = 2.f * br * bi; br = t2;
      e >>= 1;
    }
    for (int k2 = 0; k2 < 32; ++k2) {
      int j = j0 + k2;
      Bm1[n * 136 + (127 - j)]        = f2h(gd * pr);
      Bm1[(64 + n) * 136 + (127 - j)] = f2h(-gd * pi);
      float qr = pr * wr - pi * wi, qi = pr * wi + pi * wr;   // w^{j+1}
      Bm2[j * 136 + n]      = f2h(c2r * qr - c2i * qi);
      Bm2[j * 136 + 64 + n] = f2h(c2r * qi + c2i * qr);
      float kc = c2r * pr - c2i * pi;
#pragma unroll
      for (int off = 1; off < 64; off <<= 1) kc += __shfl_xor(kc, off);
      if (n == 0) Kt[j] = kc + (j == 0 ? dsk : 0.f);
      pr = qr; pi = qi;
    }
  }
  if (tid < 64) {
    const float* wlp = WLB + (((size_t)((blk << 8) + d)) * 64 + tid) * 2;
    float wlr = wlp[0], wli = wlp[1];
    float nr = wlr - 1.f, ni = wli;
    float dr2 = wc[tid] - 1.f, di = wc[64 + tid];
    float iv = 1.f / (dr2 * dr2 + di * di);
    Sb[tid]      = bd * ((nr * dr2 + ni * di) * iv);
    Sb[64 + tid] = bd * (-((ni * dr2 - nr * di) * iv));
  }
  __syncthreads();
  if (tid < 128) {
    float ps = 0.f;
    for (int t2 = 0; t2 <= tid; ++t2) ps += Kt[t2];
    Pb[tid] = bd * ps;
  }
  // no barrier needed yet for Pb (used only in phase-3 epilogue, many barriers between)

  // ---------- phase 1: SL = UT @ Fn^T + Sbeta (Fn resident in Bm1) ----------
  for (int mh = 0; mh < 2; ++mh) {
    const unsigned short* Ab = Au + (size_t)(mh << 7) * 128;
    f32x4 acc[4][4];
#pragma unroll
    for (int a = 0; a < 4; ++a)
#pragma unroll
      for (int b2 = 0; b2 < 4; ++b2) acc[a][b2] = (f32x4){0.f, 0.f, 0.f, 0.f};
    uint4 a0 = *(const uint4*)(Ab + (size_t)r * 128 + sg);
    uint4 a1 = *(const uint4*)(Ab + (size_t)r * 128 + sg + 8);
    for (int kc = 0; kc < 128; kc += 32) {
      __syncthreads();
      *(uint4*)&As[r * 40 + sg] = a0; *(uint4*)&As[r * 40 + sg + 8] = a1;
      __syncthreads();
      if (kc < 96) {
        a0 = *(const uint4*)(Ab + (size_t)r * 128 + kc + 32 + sg);
        a1 = *(const uint4*)(Ab + (size_t)r * 128 + kc + 32 + sg + 8);
      }
      half8 af[4], bf4[4];
#pragma unroll
      for (int mf = 0; mf < 4; ++mf) af[mf] = *(const half8*)&As[(wm + (mf << 4) + cn) * 40 + ko];
#pragma unroll
      for (int nf = 0; nf < 4; ++nf)
        bf4[nf] = *(const half8*)((const _Float16*)Bm1 + (wn + (nf << 4) + cn) * 136 + kc + ko);
#pragma unroll
      for (int mf = 0; mf < 4; ++mf)
#pragma unroll
        for (int nf = 0; nf < 4; ++nf)
          acc[mf][nf] = __builtin_amdgcn_mfma_f32_16x16x32_f16(af[mf], bf4[nf], acc[mf][nf], 0, 0, 0);
    }
#pragma unroll
    for (int nf = 0; nf < 4; ++nf) {
      int nl = wn + (nf << 4) + cn;
      float sb = Sb[nl];
#pragma unroll
      for (int mf = 0; mf < 4; ++mf)
#pragma unroll
        for (int rr = 0; rr < 4; ++rr) {
          int row = (mh << 7) + wm + (mf << 4) + (rq << 2) + rr;
          SLl[row * 136 + nl] = f2h(acc[mf][nf][rr] + sb);
        }
    }
  }
  __syncthreads();

  // ---------- phase 2: exclusive chunk-state combine in LDS ----------
  for (int task = tid; task < 1024; task += 256) {
    int b = task >> 6, nn = task & 63;
    const float* wlp = WLB + (((size_t)((blk << 8) + d)) * 64 + nn) * 2;
    float wlr = wlp[0], wli = wlp[1];
    float Sr = 0.f, Sj = 0.f;
    for (int c = 0; c < NC_; ++c) {
      int row = (b << 4) + c;
      float tr2 = h2f(SLl[row * 136 + nn]);
      float tj2 = h2f(SLl[row * 136 + 64 + nn]);
      SLl[row * 136 + nn]      = f2h(Sr);
      SLl[row * 136 + 64 + nn] = f2h(Sj);
      float nSr = fmaf(wlr, Sr, fmaf(wli, Sj, tr2));
      Sj = fmaf(-wli, Sr, fmaf(wlr, Sj, tj2));
      Sr = nSr;
    }
  }
  __syncthreads();

  // ---------- Tn generation into Bm1 (Fn dead) ----------
  {
    int chunk = tid & 15, rg = tid >> 4;
#pragma unroll
    for (int it = 0; it < 8; ++it) {
      int trow = (it << 4) + rg;
      int tau0 = chunk << 3;
      unsigned short v[8];
#pragma unroll
      for (int i = 0; i < 8; ++i) {
        int tau = tau0 + i;
        v[i] = (tau <= trow) ? f2h(gd * Kt[trow - tau]) : (unsigned short)0;
      }
      *(uint4*)(Bm1 + (size_t)trow * 136 + tau0) = *(uint4*)v;
    }
  }
  __syncthreads();

  // ---------- phase 3: GT = gelu(UT@Tn^T + SL@En^T + Pbeta) ----------
  for (int mh = 0; mh < 2; ++mh) {
    const unsigned short* Ab = Au + (size_t)(mh << 7) * 128;
    const _Float16* SA = (const _Float16*)SLl + (size_t)(mh << 7) * 136;
    f32x4 acc[4][4];
#pragma unroll
    for (int a = 0; a < 4; ++a)
#pragma unroll
      for (int b2 = 0; b2 < 4; ++b2) acc[a][b2] = (f32x4){0.f, 0.f, 0.f, 0.f};
    uint4 a0 = *(const uint4*)(Ab + (size_t)r * 128 + sg);
    uint4 a1 = *(const uint4*)(Ab + (size_t)r * 128 + sg + 8);
    for (int kb = 0; kb < 8; ++kb) {
      int kc = (kb & 3) << 5;
      half8 af[4], bf4[4];
      if (kb < 4) {
        __syncthreads();
        *(uint4*)&As[r * 40 + sg] = a0; *(uint4*)&As[r * 40 + sg + 8] = a1;
        __syncthreads();
        if (kb < 3) {
          int kc2 = (kb + 1) << 5;
          a0 = *(const uint4*)(Ab + (size_t)r * 128 + kc2 + sg);
          a1 = *(const uint4*)(Ab + (size_t)r * 128 + kc2 + sg + 8);
        }
#pragma unroll
        for (int mf = 0; mf < 4; ++mf) af[mf] = *(const half8*)&As[(wm + (mf << 4) + cn) * 40 + ko];
#pragma unroll
        for (int nf = 0; nf < 4; ++nf)
          bf4[nf] = *(const half8*)((const _Float16*)Bm1 + (wn + (nf << 4) + cn) * 136 + kc + ko);
      } else {
#pragma unroll
        for (int mf = 0; mf < 4; ++mf)
          af[mf] = *(const half8*)&SA[(wm + (mf << 4) + cn) * 136 + kc + ko];
#pragma unroll
        for (int nf = 0; nf < 4; ++nf)
          bf4[nf] = *(const half8*)((const _Float16*)Bm2 + (wn + (nf << 4) + cn) * 136 + kc + ko);
      }
#pragma unroll
      for (int mf = 0; mf < 4; ++mf)
#pragma unroll
        for (int nf = 0; nf < 4; ++nf)
          acc[mf][nf] = __builtin_amdgcn_mfma_f32_16x16x32_f16(af[mf], bf4[nf], acc[mf][nf], 0, 0, 0);
    }
    __syncthreads();   // all waves done reading SL rows of this mh
    unsigned short* epi = SLl + (size_t)(mh << 7) * 136;
#pragma unroll
    for (int nf = 0; nf < 4; ++nf) {
      int nl = wn + (nf << 4) + cn;
      float pb2 = Pb[nl];
#pragma unroll
      for (int mf = 0; mf < 4; ++mf)
#pragma unroll
        for (int rr = 0; rr < 4; ++rr) {
          int ml = wm + (mf << 4) + (rq << 2) + rr;
          float xx = acc[mf][nf][rr] + pb2;
          float x3 = xx * xx * xx;
          float inner = 0.7978845608028654f * fmaf(0.044715f, x3, xx);
          float e = __expf(-2.f * fabsf(inner));
          float th = (1.f - e) / (1.f + e);
          th = copysignf(th, inner);
          epi[ml * 136 + nl] = f2h(0.5f * xx * (1.f + th));
        }
    }
    __syncthreads();
    int mr = tid >> 1, hf = (tid & 1) << 6;
    size_t gb = ((size_t)d * 256 + (mh << 7) + mr) * 128 + hf;
#pragma unroll
    for (int k = 0; k < 8; ++k)
      *(uint4*)(GT + gb + k * 8) = *(const uint4*)&epi[mr * 136 + hf + k * 8];
  }
}

// ---------------- W prep: WT[w][n][k] = fp16(W_w[k][n]) ----------------------
__global__ void wprep_kernel(const float* __restrict__ Wout, const float* __restrict__ fW1,
                             const float* __restrict__ fW2, unsigned short* __restrict__ WT) {
  __shared__ float tile[64][65];
  int wv = blockIdx.x >> 4;
  int tk = (blockIdx.x >> 2) & 3;
  int tn = blockIdx.x & 3;
  const float* src = (wv < 6) ? (Wout + (size_t)wv * 65536) : (wv == 6 ? fW1 : fW2);
  int r = threadIdx.x >> 4;
  int c = (threadIdx.x & 15) << 2;
  for (int rr = 0; rr < 64; rr += 16) {
    float4 v = *(const float4*)(src + (size_t)(tk * 64 + r + rr) * 256 + tn * 64 + c);
    tile[r + rr][c] = v.x; tile[r + rr][c + 1] = v.y;
    tile[r + rr][c + 2] = v.z; tile[r + rr][c + 3] = v.w;
  }
  __syncthreads();
  for (int rr = 0; rr < 64; rr += 16) {
    int n = r + rr;
    ushort4 o;
    o.x = f2h(tile[c + 0][n]); o.y = f2h(tile[c + 1][n]);
    o.z = f2h(tile[c + 2][n]); o.w = f2h(tile[c + 3][n]);
    *(ushort4*)(WT + (size_t)wv * 65536 + (size_t)(tn * 64 + n) * 256 + tk * 64 + c) = o;
  }
}

// ---------------- projection GEMM: hout = GT^T@W + bias + res; ut = hout^T ---
__global__ __launch_bounds__(256, 2) void gemm_gt(const unsigned short* __restrict__ GT,
    const unsigned short* __restrict__ Wt, const float* __restrict__ bias,
    const unsigned short* __restrict__ res, unsigned short* __restrict__ hout,
    unsigned short* __restrict__ ut_next) {
  __shared__ __align__(16) unsigned short smem[18432];
  unsigned short* As = smem;
  unsigned short* Bs = smem + 9216;
  int tid = threadIdx.x;
  int bid = blockIdx.x;
  int bc = bid & 255;
  int m0 = bc * 128, n0 = (bid >> 8) << 7;
  int lane = tid & 63, w = tid >> 6;
  int wm = (w & 1) << 6, wn = (w >> 1) << 6;
  int rb = tid >> 3, cb = (tid & 7) << 3;
  int dr = tid >> 2, sg = (tid & 3) << 5;
  f32x4 acc[4][4];
#pragma unroll
  for (int mf = 0; mf < 4; ++mf)
#pragma unroll
    for (int nf = 0; nf < 4; ++nf) acc[mf][nf] = (f32x4){0.f, 0.f, 0.f, 0.f};

  uint4 gv[4], bv[4];
  {
    const uint4* grow = (const uint4*)(GT + ((size_t)(dr * 256 + bc)) * 128 + sg);
    gv[0] = grow[0]; gv[1] = grow[1]; gv[2] = grow[2]; gv[3] = grow[3];
#pragma unroll
    for (int rr = 0; rr < 4; ++rr)
      bv[rr] = *(const uint4*)(Wt + (size_t)(n0 + rb + rr * 32) * 256 + cb);
  }
  for (int kb = 0; kb < 4; ++kb) {
    __syncthreads();
    const unsigned short* pv = (const unsigned short*)gv;
#pragma unroll
    for (int i = 0; i < 32; ++i) As[(sg + i) * 72 + dr] = pv[i];
#pragma unroll
    for (int rr = 0; rr < 4; ++rr) *(uint4*)&Bs[(rb + rr * 32) * 72 + cb] = bv[rr];
    __syncthreads();
    if (kb < 3) {
      int k0 = (kb + 1) << 6;
      const uint4* grow = (const uint4*)(GT + ((size_t)((k0 + dr) * 256 + bc)) * 128 + sg);
      gv[0] = grow[0]; gv[1] = grow[1]; gv[2] = grow[2]; gv[3] = grow[3];
#pragma unroll
      for (int rr = 0; rr < 4; ++rr)
        bv[rr] = *(const uint4*)(Wt + (size_t)(n0 + rb + rr * 32) * 256 + k0 + cb);
    }
#pragma unroll
    for (int kw = 0; kw < 2; ++kw) {
      int ko = (kw << 5) + ((lane >> 4) << 3);
      half8 af[4], bfr[4];
#pragma unroll
      for (int mf = 0; mf < 4; ++mf)
        af[mf] = *(const half8*)&As[(wm + (mf << 4) + (lane & 15)) * 72 + ko];
#pragma unroll
      for (int nf = 0; nf < 4; ++nf)
        bfr[nf] = *(const half8*)&Bs[(wn + (nf << 4) + (lane & 15)) * 72 + ko];
#pragma unroll
      for (int mf = 0; mf < 4; ++mf)
#pragma unroll
        for (int nf = 0; nf < 4; ++nf)
          acc[mf][nf] = __builtin_amdgcn_mfma_f32_16x16x32_f16(af[mf], bfr[nf], acc[mf][nf], 0, 0, 0);
    }
  }
  int cn = lane & 15, rq = lane >> 4;
  __syncthreads();
  unsigned short* epi = smem;   // [128][136]
#pragma unroll
  for (int nf = 0; nf < 4; ++nf) {
    int nl = wn + (nf << 4) + cn;
    float bv2 = bias[n0 + nl];
#pragma unroll
    for (int mf = 0; mf < 4; ++mf)
#pragma unroll
      for (int r = 0; r < 4; ++r) {
        int ml = wm + (mf << 4) + (rq << 2) + r;
        float v = acc[mf][nf][r] + bv2 + h2f(res[(size_t)(m0 + ml) * 256 + n0 + nl]);
        epi[ml * 136 + nl] = f2h(v);
      }
  }
  __syncthreads();
  {
    int mr = tid >> 1, hf = (tid & 1) << 6;
    unsigned short* dst = hout + (size_t)(m0 + mr) * 256 + n0 + hf;
    const unsigned short* srow = epi + mr * 136 + hf;
#pragma unroll
    for (int k = 0; k < 8; ++k) *(uint4*)(dst + k * 8) = *(const uint4*)(srow + k * 8);
  }
  if (ut_next) {
    int nl = tid >> 1, h2 = (tid & 1) << 6;
    unsigned short* dst = ut_next + ((size_t)(n0 + nl) * 256 + bc) * 128 + h2;
#pragma unroll
    for (int k = 0; k < 8; ++k) {
      unsigned short v8[8];
#pragma unroll
      for (int e = 0; e < 8; ++e) v8[e] = epi[(h2 + k * 8 + e) * 136 + nl];
      *(uint4*)(dst + k * 8) = *(uint4*)v8;
    }
  }
}

// ---------------- FFN GEMM: out = relu(A@W + b [+ res]), XCD-paired grid -----
__global__ __launch_bounds__(256, 2) void gemm_ffn(const unsigned short* __restrict__ A,
    const unsigned short* __restrict__ Wt, const float* __restrict__ bias,
    const unsigned short* __restrict__ res, unsigned short* __restrict__ outp) {
  __shared__ __align__(16) unsigned short smem[18432];
  unsigned short* As = smem;
  unsigned short* Bs = smem + 9216;
  int tid = threadIdx.x;
  int bid = blockIdx.x;
  int m0 = (bid & 255) << 7, n0 = (bid >> 8) << 7;
  int lane = tid & 63, w = tid >> 6;
  int wm = (w & 1) << 6, wn = (w >> 1) << 6;
  int r0 = tid >> 3;
  int c0 = (tid & 7) << 3;
  f32x4 acc[4][4];
#pragma unroll
  for (int mf = 0; mf < 4; ++mf)
#pragma unroll
    for (int nf = 0; nf < 4; ++nf) acc[mf][nf] = (f32x4){0.f, 0.f, 0.f, 0.f};

  uint4 av[4], bv[4];
#pragma unroll
  for (int rr = 0; rr < 4; ++rr) {
    int r = r0 + rr * 32;
    av[rr] = *(const uint4*)(A + (size_t)(m0 + r) * 256 + c0);
    bv[rr] = *(const uint4*)(Wt + (size_t)(n0 + r) * 256 + c0);
  }
  for (int kb = 0; kb < 4; ++kb) {
    __syncthreads();
#pragma unroll
    for (int rr = 0; rr < 4; ++rr) {
      int r = r0 + rr * 32;
      *(uint4*)&As[r * 72 + c0] = av[rr];
      *(uint4*)&Bs[r * 72 + c0] = bv[rr];
    }
    __syncthreads();
    if (kb < 3) {
      int k0 = (kb + 1) << 6;
#pragma unroll
      for (int rr = 0; rr < 4; ++rr) {
        int r = r0 + rr * 32;
        av[rr] = *(const uint4*)(A + (size_t)(m0 + r) * 256 + k0 + c0);
        bv[rr] = *(const uint4*)(Wt + (size_t)(n0 + r) * 256 + k0 + c0);
      }
    }
#pragma unroll
    for (int kw = 0; kw < 2; ++kw) {
      int ko = (kw << 5) + ((lane >> 4) << 3);
      half8 af[4], bfr[4];
#pragma unroll
      for (int mf = 0; mf < 4; ++mf)
        af[mf] = *(const half8*)&As[(wm + (mf << 4) + (lane & 15)) * 72 + ko];
#pragma unroll
      for (int nf = 0; nf < 4; ++nf)
        bfr[nf] = *(const half8*)&Bs[(wn + (nf << 4) + (lane & 15)) * 72 + ko];
#pragma unroll
      for (int mf = 0; mf < 4; ++mf)
#pragma unroll
        for (int nf = 0; nf < 4; ++nf)
          acc[mf][nf] = __builtin_amdgcn_mfma_f32_16x16x32_f16(af[mf], bfr[nf], acc[mf][nf], 0, 0, 0);
    }
  }
  int cn = lane & 15, rq = lane >> 4;
  __syncthreads();
  unsigned short* epi = smem;
#pragma unroll
  for (int nf = 0; nf < 4; ++nf) {
    int nl = wn + (nf << 4) + cn;
#pragma unroll
    for (int r = 0; r < 4; ++r) {
#pragma unroll
      for (int mf = 0; mf < 4; ++mf) {
        int ml = wm + (mf << 4) + (rq << 2) + r;
        epi[ml * 136 + nl] = f2h(acc[mf][nf][r]);
      }
    }
  }
  __syncthreads();
  int mr = tid >> 1, hf = (tid & 1) << 6;
  unsigned short* dst = outp + (size_t)(m0 + mr) * 256 + n0 + hf;
#pragma unroll
  for (int k = 0; k < 8; ++k) {
    uint4 c = *(const uint4*)&epi[mr * 136 + hf + k * 8];
    uint4 rv = (uint4){0, 0, 0, 0};
    if (res) rv = *(const uint4*)(res + (size_t)(m0 + mr) * 256 + n0 + hf + k * 8);
    const unsigned short* cp = (const unsigned short*)&c;
    const unsigned short* rp = (const unsigned short*)&rv;
    unsigned short o8[8];
#pragma unroll
    for (int e = 0; e < 8; ++e) {
      float v = h2f(cp[e]) + bias[n0 + hf + k * 8 + e];
      if (res) v += h2f(rp[e]);
      o8[e] = f2h(fmaxf(v, 0.f));
    }
    *(uint4*)(dst + k * 8) = *(uint4*)o8;
  }
}

// ---------------- head ------------------------
__global__ void head1_kernel(const unsigned short* __restrict__ H, float* __restrict__ part) {
  int b = blockIdx.x, ls = blockIdx.y, d = threadIdx.x;
  const unsigned short* p = H + ((size_t)(b * L_ + ls * 128)) * D_ + d;
  float sum = 0.f;
  for (int l = 0; l < 128; ++l) sum += h2f(p[(size_t)l * D_]);
  part[(b * 16 + ls) * D_ + d] = sum;
}

__global__ void head2_kernel(const float* __restrict__ part, const float* __restrict__ fcW,
                             const float* __restrict__ fcb, float* __restrict__ out) {
  int b = blockIdx.x, d = threadIdx.x;
  float sum = 0.f;
  for (int i = 0; i < 16; ++i) sum += part[(b * 16 + i) * D_ + d];
  __shared__ float meanv[D_];
  meanv[d] = sum * (1.0f / (float)L_);
  __syncthreads();
  if (d < 2) {
    float accv = fcb[d];
    for (int k = 0; k < D_; ++k) accv = fmaf(meanv[k], fcW[k * 2 + d], accv);
    out[b * 2 + d] = accv;
  }
}

extern "C" void kernel_launch(void* const* d_in, const int* in_sizes, int n_in,
                              void* d_out, int out_size, void* d_ws, size_t ws_size,
                              hipStream_t stream) {
  const float* x      = (const float*)d_in[0];
  const float* W_emb  = (const float*)d_in[1];
  const float* b_emb  = (const float*)d_in[2];
  const float* log_dt = (const float*)d_in[3];
  const float* logAre = (const float*)d_in[4];
  const float* Aim    = (const float*)d_in[5];
  const float* Cre    = (const float*)d_in[6];
  const float* Cim    = (const float*)d_in[7];
  const float* Dskip  = (const float*)d_in[8];
  const float* Wout   = (const float*)d_in[9];
  const float* bout   = (const float*)d_in[10];
  const float* gamma_ = (const float*)d_in[11];
  const float* beta_  = (const float*)d_in[12];
  const float* fW1    = (const float*)d_in[13];
  const float* fb1    = (const float*)d_in[14];
  const float* fW2    = (const float*)d_in[15];
  const float* fb2    = (const float*)d_in[16];
  const float* fcW    = (const float*)d_in[17];
  const float* fcb    = (const float*)d_in[18];
  float* outp = (float*)d_out;

  const size_t HSZ = (size_t)B_ * L_ * D_;   // 8388608
  float* WB     = (float*)d_ws;                          // 196608 f
  float* C2B    = WB + (size_t)NBLK_ * D_ * 128;         // 196608 f
  float* WLB    = C2B + (size_t)NBLK_ * D_ * 128;        // 196608 f
  unsigned short* H   = (unsigned short*)(WLB + (size_t)NBLK_ * D_ * N_ * 2);
  unsigned short* R   = H + HSZ;
  unsigned short* UT  = R + HSZ;
  unsigned short* GT  = UT + HSZ;
  unsigned short* Gbf = GT;     // FFN intermediate aliases GT (dead after layer 5)
  unsigned short* WT  = GT + HSZ;                        // 524288 us

  precompute_kernel<<<(NBLK_ * D_ * N_ + 255) / 256, 256, 0, stream>>>(
      log_dt, logAre, Aim, Cre, Cim, WB, C2B, WLB);
  wprep_kernel<<<128, 256, 0, stream>>>(Wout, fW1, fW2, WT);
  embed_kernel<<<(B_ * L_ * D_ + 255) / 256, 256, 0, stream>>>(x, W_emb, b_emb, H);
  trans_h_ut<<<1024, 256, 0, stream>>>(H, UT);

  const unsigned short* hin_t[6]  = {H, H, H, H, R, H};
  unsigned short*       hout_t[6] = {H, H, H, R, H, H};
  for (int i = 0; i < 6; ++i) {
    scan_fused<<<256, 256, 0, stream>>>(UT, WB, C2B, WLB, gamma_, beta_, Dskip, GT, i);
    gemm_gt<<<512, 256, 0, stream>>>(
        GT, WT + (size_t)i * 65536, bout + i * D_, hin_t[i], hout_t[i],
        (i < 5) ? UT : nullptr);
  }
  // feedforward of the FS4Ddeq block + skip from R
  gemm_ffn<<<512, 256, 0, stream>>>(H, WT + (size_t)6 * 65536, fb1, nullptr, Gbf);
  gemm_ffn<<<512, 256, 0, stream>>>(Gbf, WT + (size_t)7 * 65536, fb2, R, H);
  head1_kernel<<<dim3(16, 16), 256, 0, stream>>>(H, WB);
  head2_kernel<<<16, 256, 0, stream>>>(WB, fcW, fcb, outp);
}

// Round 11
// 566.813 us; speedup vs baseline: 3.1370x; 1.0771x over previous
//
#include <hip/hip_runtime.h>
#include <hip/hip_fp16.h>
#include <math.h>

#define B_ 16
#define L_ 2048
#define D_ 256
#define N_ 64
#define NBLK_ 6
#define LC_ 128
#define NC_ 16

typedef _Float16 half8 __attribute__((ext_vector_type(8)));
typedef float f32x4 __attribute__((ext_vector_type(4)));

__device__ __forceinline__ unsigned short f2h(float f) {
  _Float16 h = (_Float16)f;
  return *(unsigned short*)&h;
}
__device__ __forceinline__ float h2f(unsigned short u) {
  _Float16 h = *(_Float16*)&u;
  return (float)h;
}

// ---------------- precompute per-layer SSM params ----------------
__global__ void precompute_kernel(const float* __restrict__ log_dt,
                                  const float* __restrict__ logAre,
                                  const float* __restrict__ Aim,
                                  const float* __restrict__ Cre,
                                  const float* __restrict__ Cim,
                                  float* __restrict__ wbuf,
                                  float* __restrict__ c2buf,
                                  float* __restrict__ wlbuf) {
  int idx = blockIdx.x * blockDim.x + threadIdx.x;
  if (idx >= NBLK_ * D_ * N_) return;
  int blk = idx >> 14;
  int rem = idx & 16383;
  int d = rem >> 6;
  int n = rem & 63;
  float dt   = expf(log_dt[blk * D_ + d]);
  float are  = -expf(logAre[idx]);
  float aim  = Aim[idx];
  float dtar = dt * are, dtai = dt * aim;
  float er = expf(dtar);
  float wr = er * cosf(dtai);
  float wi = er * sinf(dtai);
  float inv = 1.0f / (are * are + aim * aim);
  float wm1r = wr - 1.0f;
  float br = (wm1r * are + wi * aim) * inv;
  float bi = (wi * are - wm1r * aim) * inv;
  float crv = Cre[idx], civ = Cim[idx];
  float c2r = 2.0f * (crv * br - civ * bi);
  float c2i = 2.0f * (crv * bi + civ * br);
  float eL = expf((float)LC_ * dtar);
  float angL = (float)LC_ * dtai;
  float* wb = wbuf + (size_t)((blk << 8) + d) * 128;
  wb[n] = wr; wb[64 + n] = wi;
  float* cb = c2buf + (size_t)((blk << 8) + d) * 128;
  cb[n] = c2r; cb[64 + n] = c2i;
  wlbuf[2 * idx] = eL * cosf(angL); wlbuf[2 * idx + 1] = eL * sinf(angL);
}

// ---------------- embedding -> fp16 H ----------
__global__ void embed_kernel(const float* __restrict__ x, const float* __restrict__ wemb,
                             const float* __restrict__ bemb, unsigned short* __restrict__ H) {
  int tid = blockIdx.x * blockDim.x + threadIdx.x;
  if (tid >= B_ * L_ * D_) return;
  int d = tid & (D_ - 1);
  int lg = tid >> 8;
  H[tid] = f2h(fmaf(x[lg], wemb[d], bemb[d]));
}

// ---------------- transpose H [b][l][d] fp16 -> UT [d][bc][tau] fp16 ---------
__global__ __launch_bounds__(256) void trans_h_ut(const unsigned short* __restrict__ H,
                                                  unsigned short* __restrict__ UT) {
  __shared__ __align__(16) unsigned short lds[64][136];
  int bi = blockIdx.x;
  int bc = bi >> 2, dq = bi & 3;
  int b = bc >> 4, ch = bc & 15;
  int tid = threadIdx.x;
  const unsigned short* src = H + ((size_t)(b * L_ + ch * 128)) * D_ + dq * 64;
  int tau0 = tid >> 4;
  int dl = (tid & 15) << 2;
  for (int tt = 0; tt < 128; tt += 16) {
    ushort4 v = *(const ushort4*)(src + (size_t)(tt + tau0) * D_ + dl);
    lds[dl + 0][tt + tau0] = v.x;
    lds[dl + 1][tt + tau0] = v.y;
    lds[dl + 2][tt + tau0] = v.z;
    lds[dl + 3][tt + tau0] = v.w;
  }
  __syncthreads();
  int r = tid >> 2, seg = (tid & 3) << 5;
  unsigned short* dst = UT + ((size_t)((dq * 64 + r) * 256 + bc)) * 128 + seg;
  const unsigned short* srow = &lds[r][seg];
  *(uint4*)(dst + 0)  = *(const uint4*)(srow + 0);
  *(uint4*)(dst + 8)  = *(const uint4*)(srow + 8);
  *(uint4*)(dst + 16) = *(const uint4*)(srow + 16);
  *(uint4*)(dst + 24) = *(const uint4*)(srow + 24);
}

// ---------------- fully-fused scan, 512 threads (8 waves) per block ----------
// One block per d. Phase 0: powers w^j -> Fn (Bm1), En (Bm2), K, Pbeta, Sbeta
// in LDS. Phase 1: SL = UT@Fn^T + Sbeta (single 256-row m-pass, 8 waves as
// 4m x 2n of 64x64). Phase 2: in-LDS chunk combine. Tn overwrites Bm1.
// Phase 3: GT = gelu(UT@Tn^T + SL@En^T + Pbeta), SL A-operand direct from LDS.
__global__ __launch_bounds__(512) void scan_fused(
    const unsigned short* __restrict__ UT,
    const float* __restrict__ WB, const float* __restrict__ C2B,
    const float* __restrict__ WLB,
    const float* __restrict__ gamma_, const float* __restrict__ beta_,
    const float* __restrict__ dskip,
    unsigned short* __restrict__ GT, int blk) {
  __shared__ __align__(16) unsigned short SLl[256 * 136];   // 69632 B
  __shared__ __align__(16) unsigned short Bm1[128 * 136];   // 34816 B (Fn -> Tn)
  __shared__ __align__(16) unsigned short Bm2[128 * 136];   // 34816 B (En)
  __shared__ __align__(16) unsigned short AsB[256 * 40];    // 20480 B
  __shared__ float wc[256];
  __shared__ float Kt[128];
  __shared__ float Pb[128];
  __shared__ float Sb[128];
  _Float16* As = (_Float16*)AsB;
  int d = blockIdx.x;
  int tid = threadIdx.x, lane = tid & 63, w = tid >> 6;   // w: 0..7
  int wm = (w & 3) << 6;    // 0,64,128,192
  int wn = (w >> 2) << 6;   // 0,64
  int r = tid & 255, sg = (tid >> 8) << 4;
  int cn = lane & 15, rq = lane >> 4;
  int ko = rq << 3;
  const unsigned short* Au = UT + (size_t)d * 256 * 128;

  // ---------- phase 0: generate Fn, En, K, Sbeta in LDS ----------
  if (tid < 128) wc[tid] = WB[(size_t)((blk << 8) + d) * 128 + tid];
  else if (tid < 256) wc[tid] = C2B[(size_t)((blk << 8) + d) * 128 + (tid - 128)];
  __syncthreads();
  int n = tid & 63;
  float gd = gamma_[blk * D_ + d], bd = beta_[blk * D_ + d], dsk = dskip[blk * D_ + d];
  {
    float wr = wc[n], wi = wc[64 + n];
    float c2r = wc[128 + n], c2i = wc[192 + n];
    int j0 = (tid >> 6) << 4;   // wave w handles j = j0..j0+15
    float pr = 1.f, pi = 0.f, br = wr, bi = wi;
    int e = j0;
    while (e) {
      if (e & 1) { float tt = pr * br - pi * bi; pi = pr * bi + pi * br; pr = tt; }
      float t2 = br * br - bi * bi; bi = 2.f * br * bi; br = t2;
      e >>= 1;
    }
    for (int k2 = 0; k2 < 16; ++k2) {
      int j = j0 + k2;
      Bm1[n * 136 + (127 - j)]        = f2h(gd * pr);
      Bm1[(64 + n) * 136 + (127 - j)] = f2h(-gd * pi);
      float qr = pr * wr - pi * wi, qi = pr * wi + pi * wr;   // w^{j+1}
      Bm2[j * 136 + n]      = f2h(c2r * qr - c2i * qi);
      Bm2[j * 136 + 64 + n] = f2h(c2r * qi + c2i * qr);
      float kc = c2r * pr - c2i * pi;
#pragma unroll
      for (int off = 1; off < 64; off <<= 1) kc += __shfl_xor(kc, off);
      if (n == 0) Kt[j] = kc + (j == 0 ? dsk : 0.f);
      pr = qr; pi = qi;
    }
  }
  if (tid < 64) {
    const float* wlp = WLB + (((size_t)((blk << 8) + d)) * 64 + tid) * 2;
    float wlr = wlp[0], wli = wlp[1];
    float nr = wlr - 1.f, ni = wli;
    float dr2 = wc[tid] - 1.f, di = wc[64 + tid];
    float iv = 1.f / (dr2 * dr2 + di * di);
    Sb[tid]      = bd * ((nr * dr2 + ni * di) * iv);
    Sb[64 + tid] = bd * (-((ni * dr2 - nr * di) * iv));
  }
  __syncthreads();
  if (tid < 128) {
    float ps = 0.f;
    for (int t2 = 0; t2 <= tid; ++t2) ps += Kt[t2];
    Pb[tid] = bd * ps;
  }
  // Pb read only in phase-3 epilogue (many barriers from here to there)

  // ---------- phase 1: SL = UT @ Fn^T + Sbeta (Fn resident in Bm1) ----------
  {
    f32x4 acc[4][4];
#pragma unroll
    for (int a = 0; a < 4; ++a)
#pragma unroll
      for (int b2 = 0; b2 < 4; ++b2) acc[a][b2] = (f32x4){0.f, 0.f, 0.f, 0.f};
    uint4 a0 = *(const uint4*)(Au + (size_t)r * 128 + sg);
    uint4 a1 = *(const uint4*)(Au + (size_t)r * 128 + sg + 8);
    for (int kc = 0; kc < 128; kc += 32) {
      __syncthreads();
      *(uint4*)&As[r * 40 + sg] = a0; *(uint4*)&As[r * 40 + sg + 8] = a1;
      __syncthreads();
      if (kc < 96) {
        a0 = *(const uint4*)(Au + (size_t)r * 128 + kc + 32 + sg);
        a1 = *(const uint4*)(Au + (size_t)r * 128 + kc + 32 + sg + 8);
      }
      half8 af[4], bf4[4];
#pragma unroll
      for (int mf = 0; mf < 4; ++mf) af[mf] = *(const half8*)&As[(wm + (mf << 4) + cn) * 40 + ko];
#pragma unroll
      for (int nf = 0; nf < 4; ++nf)
        bf4[nf] = *(const half8*)((const _Float16*)Bm1 + (wn + (nf << 4) + cn) * 136 + kc + ko);
#pragma unroll
      for (int mf = 0; mf < 4; ++mf)
#pragma unroll
        for (int nf = 0; nf < 4; ++nf)
          acc[mf][nf] = __builtin_amdgcn_mfma_f32_16x16x32_f16(af[mf], bf4[nf], acc[mf][nf], 0, 0, 0);
    }
#pragma unroll
    for (int nf = 0; nf < 4; ++nf) {
      int nl = wn + (nf << 4) + cn;
      float sb = Sb[nl];
#pragma unroll
      for (int mf = 0; mf < 4; ++mf)
#pragma unroll
        for (int rr = 0; rr < 4; ++rr) {
          int row = wm + (mf << 4) + (rq << 2) + rr;
          SLl[row * 136 + nl] = f2h(acc[mf][nf][rr] + sb);
        }
    }
  }
  __syncthreads();

  // ---------- phase 2: exclusive chunk-state combine in LDS ----------
  for (int task = tid; task < 1024; task += 512) {
    int b = task >> 6, nn = task & 63;
    const float* wlp = WLB + (((size_t)((blk << 8) + d)) * 64 + nn) * 2;
    float wlr = wlp[0], wli = wlp[1];
    float Sr = 0.f, Sj = 0.f;
    for (int c = 0; c < NC_; ++c) {
      int row = (b << 4) + c;
      float tr2 = h2f(SLl[row * 136 + nn]);
      float tj2 = h2f(SLl[row * 136 + 64 + nn]);
      SLl[row * 136 + nn]      = f2h(Sr);
      SLl[row * 136 + 64 + nn] = f2h(Sj);
      float nSr = fmaf(wlr, Sr, fmaf(wli, Sj, tr2));
      Sj = fmaf(-wli, Sr, fmaf(wlr, Sj, tj2));
      Sr = nSr;
    }
  }
  __syncthreads();

  // ---------- Tn generation into Bm1 (Fn dead) ----------
  {
    int chunk = tid & 15, rg = tid >> 4;   // rg 0..31
#pragma unroll
    for (int it = 0; it < 4; ++it) {
      int trow = (it << 5) + rg;
      int tau0 = chunk << 3;
      unsigned short v[8];
#pragma unroll
      for (int i = 0; i < 8; ++i) {
        int tau = tau0 + i;
        v[i] = (tau <= trow) ? f2h(gd * Kt[trow - tau]) : (unsigned short)0;
      }
      *(uint4*)(Bm1 + (size_t)trow * 136 + tau0) = *(uint4*)v;
    }
  }
  __syncthreads();

  // ---------- phase 3: GT = gelu(UT@Tn^T + SL@En^T + Pbeta) ----------
  {
    f32x4 acc[4][4];
#pragma unroll
    for (int a = 0; a < 4; ++a)
#pragma unroll
      for (int b2 = 0; b2 < 4; ++b2) acc[a][b2] = (f32x4){0.f, 0.f, 0.f, 0.f};
    uint4 a0 = *(const uint4*)(Au + (size_t)r * 128 + sg);
    uint4 a1 = *(const uint4*)(Au + (size_t)r * 128 + sg + 8);
    for (int kb = 0; kb < 8; ++kb) {
      int kc = (kb & 3) << 5;
      half8 af[4], bf4[4];
      if (kb < 4) {
        __syncthreads();
        *(uint4*)&As[r * 40 + sg] = a0; *(uint4*)&As[r * 40 + sg + 8] = a1;
        __syncthreads();
        if (kb < 3) {
          int kc2 = (kb + 1) << 5;
          a0 = *(const uint4*)(Au + (size_t)r * 128 + kc2 + sg);
          a1 = *(const uint4*)(Au + (size_t)r * 128 + kc2 + sg + 8);
        }
#pragma unroll
        for (int mf = 0; mf < 4; ++mf) af[mf] = *(const half8*)&As[(wm + (mf << 4) + cn) * 40 + ko];
#pragma unroll
        for (int nf = 0; nf < 4; ++nf)
          bf4[nf] = *(const half8*)((const _Float16*)Bm1 + (wn + (nf << 4) + cn) * 136 + kc + ko);
      } else {
#pragma unroll
        for (int mf = 0; mf < 4; ++mf)
          af[mf] = *(const half8*)((const _Float16*)SLl + (wm + (mf << 4) + cn) * 136 + kc + ko);
#pragma unroll
        for (int nf = 0; nf < 4; ++nf)
          bf4[nf] = *(const half8*)((const _Float16*)Bm2 + (wn + (nf << 4) + cn) * 136 + kc + ko);
      }
#pragma unroll
      for (int mf = 0; mf < 4; ++mf)
#pragma unroll
        for (int nf = 0; nf < 4; ++nf)
          acc[mf][nf] = __builtin_amdgcn_mfma_f32_16x16x32_f16(af[mf], bf4[nf], acc[mf][nf], 0, 0, 0);
    }
    __syncthreads();   // all waves done reading SLl
    unsigned short* epi = SLl;
#pragma unroll
    for (int nf = 0; nf < 4; ++nf) {
      int nl = wn + (nf << 4) + cn;
      float pb2 = Pb[nl];
#pragma unroll
      for (int mf = 0; mf < 4; ++mf)
#pragma unroll
        for (int rr = 0; rr < 4; ++rr) {
          int ml = wm + (mf << 4) + (rq << 2) + rr;
          float xx = acc[mf][nf][rr] + pb2;
          float x3 = xx * xx * xx;
          float inner = 0.7978845608028654f * fmaf(0.044715f, x3, xx);
          float e = __expf(-2.f * fabsf(inner));
          float th = (1.f - e) / (1.f + e);
          th = copysignf(th, inner);
          epi[ml * 136 + nl] = f2h(0.5f * xx * (1.f + th));
        }
    }
    __syncthreads();
    int mr = tid >> 1, hf = (tid & 1) << 6;
    size_t gb = ((size_t)d * 256 + mr) * 128 + hf;
#pragma unroll
    for (int k = 0; k < 8; ++k)
      *(uint4*)(GT + gb + k * 8) = *(const uint4*)&epi[mr * 136 + hf + k * 8];
  }
}

// ---------------- W prep: WT[w][n][k] = fp16(W_w[k][n]) ----------------------
__global__ void wprep_kernel(const float* __restrict__ Wout, const float* __restrict__ fW1,
                             const float* __restrict__ fW2, unsigned short* __restrict__ WT) {
  __shared__ float tile[64][65];
  int wv = blockIdx.x >> 4;
  int tk = (blockIdx.x >> 2) & 3;
  int tn = blockIdx.x & 3;
  const float* src = (wv < 6) ? (Wout + (size_t)wv * 65536) : (wv == 6 ? fW1 : fW2);
  int r = threadIdx.x >> 4;
  int c = (threadIdx.x & 15) << 2;
  for (int rr = 0; rr < 64; rr += 16) {
    float4 v = *(const float4*)(src + (size_t)(tk * 64 + r + rr) * 256 + tn * 64 + c);
    tile[r + rr][c] = v.x; tile[r + rr][c + 1] = v.y;
    tile[r + rr][c + 2] = v.z; tile[r + rr][c + 3] = v.w;
  }
  __syncthreads();
  for (int rr = 0; rr < 64; rr += 16) {
    int n = r + rr;
    ushort4 o;
    o.x = f2h(tile[c + 0][n]); o.y = f2h(tile[c + 1][n]);
    o.z = f2h(tile[c + 2][n]); o.w = f2h(tile[c + 3][n]);
    *(ushort4*)(WT + (size_t)wv * 65536 + (size_t)(tn * 64 + n) * 256 + tk * 64 + c) = o;
  }
}

// ---------------- projection GEMM: hout = GT^T@W + bias + res; ut = hout^T ---
__global__ __launch_bounds__(256, 2) void gemm_gt(const unsigned short* __restrict__ GT,
    const unsigned short* __restrict__ Wt, const float* __restrict__ bias,
    const unsigned short* __restrict__ res, unsigned short* __restrict__ hout,
    unsigned short* __restrict__ ut_next) {
  __shared__ __align__(16) unsigned short smem[18432];
  unsigned short* As = smem;
  unsigned short* Bs = smem + 9216;
  int tid = threadIdx.x;
  int bid = blockIdx.x;
  int bc = bid & 255;
  int m0 = bc * 128, n0 = (bid >> 8) << 7;
  int lane = tid & 63, w = tid >> 6;
  int wm = (w & 1) << 6, wn = (w >> 1) << 6;
  int rb = tid >> 3, cb = (tid & 7) << 3;
  int dr = tid >> 2, sg = (tid & 3) << 5;
  f32x4 acc[4][4];
#pragma unroll
  for (int mf = 0; mf < 4; ++mf)
#pragma unroll
    for (int nf = 0; nf < 4; ++nf) acc[mf][nf] = (f32x4){0.f, 0.f, 0.f, 0.f};

  uint4 gv[4], bv[4];
  {
    const uint4* grow = (const uint4*)(GT + ((size_t)(dr * 256 + bc)) * 128 + sg);
    gv[0] = grow[0]; gv[1] = grow[1]; gv[2] = grow[2]; gv[3] = grow[3];
#pragma unroll
    for (int rr = 0; rr < 4; ++rr)
      bv[rr] = *(const uint4*)(Wt + (size_t)(n0 + rb + rr * 32) * 256 + cb);
  }
  for (int kb = 0; kb < 4; ++kb) {
    __syncthreads();
    const unsigned short* pv = (const unsigned short*)gv;
#pragma unroll
    for (int i = 0; i < 32; ++i) As[(sg + i) * 72 + dr] = pv[i];
#pragma unroll
    for (int rr = 0; rr < 4; ++rr) *(uint4*)&Bs[(rb + rr * 32) * 72 + cb] = bv[rr];
    __syncthreads();
    if (kb < 3) {
      int k0 = (kb + 1) << 6;
      const uint4* grow = (const uint4*)(GT + ((size_t)((k0 + dr) * 256 + bc)) * 128 + sg);
      gv[0] = grow[0]; gv[1] = grow[1]; gv[2] = grow[2]; gv[3] = grow[3];
#pragma unroll
      for (int rr = 0; rr < 4; ++rr)
        bv[rr] = *(const uint4*)(Wt + (size_t)(n0 + rb + rr * 32) * 256 + k0 + cb);
    }
#pragma unroll
    for (int kw = 0; kw < 2; ++kw) {
      int ko = (kw << 5) + ((lane >> 4) << 3);
      half8 af[4], bfr[4];
#pragma unroll
      for (int mf = 0; mf < 4; ++mf)
        af[mf] = *(const half8*)&As[(wm + (mf << 4) + (lane & 15)) * 72 + ko];
#pragma unroll
      for (int nf = 0; nf < 4; ++nf)
        bfr[nf] = *(const half8*)&Bs[(wn + (nf << 4) + (lane & 15)) * 72 + ko];
#pragma unroll
      for (int mf = 0; mf < 4; ++mf)
#pragma unroll
        for (int nf = 0; nf < 4; ++nf)
          acc[mf][nf] = __builtin_amdgcn_mfma_f32_16x16x32_f16(af[mf], bfr[nf], acc[mf][nf], 0, 0, 0);
    }
  }
  int cn = lane & 15, rq = lane >> 4;
  __syncthreads();
  unsigned short* epi = smem;   // [128][136]
#pragma unroll
  for (int nf = 0; nf < 4; ++nf) {
    int nl = wn + (nf << 4) + cn;
    float bv2 = bias[n0 + nl];
#pragma unroll
    for (int mf = 0; mf < 4; ++mf)
#pragma unroll
      for (int r = 0; r < 4; ++r) {
        int ml = wm + (mf << 4) + (rq << 2) + r;
        float v = acc[mf][nf][r] + bv2 + h2f(res[(size_t)(m0 + ml) * 256 + n0 + nl]);
        epi[ml * 136 + nl] = f2h(v);
      }
  }
  __syncthreads();
  {
    int mr = tid >> 1, hf = (tid & 1) << 6;
    unsigned short* dst = hout + (size_t)(m0 + mr) * 256 + n0 + hf;
    const unsigned short* srow = epi + mr * 136 + hf;
#pragma unroll
    for (int k = 0; k < 8; ++k) *(uint4*)(dst + k * 8) = *(const uint4*)(srow + k * 8);
  }
  if (ut_next) {
    int nl = tid >> 1, h2 = (tid & 1) << 6;
    unsigned short* dst = ut_next + ((size_t)(n0 + nl) * 256 + bc) * 128 + h2;
#pragma unroll
    for (int k = 0; k < 8; ++k) {
      unsigned short v8[8];
#pragma unroll
      for (int e = 0; e < 8; ++e) v8[e] = epi[(h2 + k * 8 + e) * 136 + nl];
      *(uint4*)(dst + k * 8) = *(uint4*)v8;
    }
  }
}

// ---------------- FFN GEMM: out = relu(A@W + b [+ res]), XCD-paired grid -----
__global__ __launch_bounds__(256, 2) void gemm_ffn(const unsigned short* __restrict__ A,
    const unsigned short* __restrict__ Wt, const float* __restrict__ bias,
    const unsigned short* __restrict__ res, unsigned short* __restrict__ outp) {
  __shared__ __align__(16) unsigned short smem[18432];
  unsigned short* As = smem;
  unsigned short* Bs = smem + 9216;
  int tid = threadIdx.x;
  int bid = blockIdx.x;
  int m0 = (bid & 255) << 7, n0 = (bid >> 8) << 7;
  int lane = tid & 63, w = tid >> 6;
  int wm = (w & 1) << 6, wn = (w >> 1) << 6;
  int r0 = tid >> 3;
  int c0 = (tid & 7) << 3;
  f32x4 acc[4][4];
#pragma unroll
  for (int mf = 0; mf < 4; ++mf)
#pragma unroll
    for (int nf = 0; nf < 4; ++nf) acc[mf][nf] = (f32x4){0.f, 0.f, 0.f, 0.f};

  uint4 av[4], bv[4];
#pragma unroll
  for (int rr = 0; rr < 4; ++rr) {
    int r = r0 + rr * 32;
    av[rr] = *(const uint4*)(A + (size_t)(m0 + r) * 256 + c0);
    bv[rr] = *(const uint4*)(Wt + (size_t)(n0 + r) * 256 + c0);
  }
  for (int kb = 0; kb < 4; ++kb) {
    __syncthreads();
#pragma unroll
    for (int rr = 0; rr < 4; ++rr) {
      int r = r0 + rr * 32;
      *(uint4*)&As[r * 72 + c0] = av[rr];
      *(uint4*)&Bs[r * 72 + c0] = bv[rr];
    }
    __syncthreads();
    if (kb < 3) {
      int k0 = (kb + 1) << 6;
#pragma unroll
      for (int rr = 0; rr < 4; ++rr) {
        int r = r0 + rr * 32;
        av[rr] = *(const uint4*)(A + (size_t)(m0 + r) * 256 + k0 + c0);
        bv[rr] = *(const uint4*)(Wt + (size_t)(n0 + r) * 256 + k0 + c0);
      }
    }
#pragma unroll
    for (int kw = 0; kw < 2; ++kw) {
      int ko = (kw << 5) + ((lane >> 4) << 3);
      half8 af[4], bfr[4];
#pragma unroll
      for (int mf = 0; mf < 4; ++mf)
        af[mf] = *(const half8*)&As[(wm + (mf << 4) + (lane & 15)) * 72 + ko];
#pragma unroll
      for (int nf = 0; nf < 4; ++nf)
        bfr[nf] = *(const half8*)&Bs[(wn + (nf << 4) + (lane & 15)) * 72 + ko];
#pragma unroll
      for (int mf = 0; mf < 4; ++mf)
#pragma unroll
        for (int nf = 0; nf < 4; ++nf)
          acc[mf][nf] = __builtin_amdgcn_mfma_f32_16x16x32_f16(af[mf], bfr[nf], acc[mf][nf], 0, 0, 0);
    }
  }
  int cn = lane & 15, rq = lane >> 4;
  __syncthreads();
  unsigned short* epi = smem;
#pragma unroll
  for (int nf = 0; nf < 4; ++nf) {
    int nl = wn + (nf << 4) + cn;
#pragma unroll
    for (int r = 0; r < 4; ++r) {
#pragma unroll
      for (int mf = 0; mf < 4; ++mf) {
        int ml = wm + (mf << 4) + (rq << 2) + r;
        epi[ml * 136 + nl] = f2h(acc[mf][nf][r]);
      }
    }
  }
  __syncthreads();
  int mr = tid >> 1, hf = (tid & 1) << 6;
  unsigned short* dst = outp + (size_t)(m0 + mr) * 256 + n0 + hf;
#pragma unroll
  for (int k = 0; k < 8; ++k) {
    uint4 c = *(const uint4*)&epi[mr * 136 + hf + k * 8];
    uint4 rv = (uint4){0, 0, 0, 0};
    if (res) rv = *(const uint4*)(res + (size_t)(m0 + mr) * 256 + n0 + hf + k * 8);
    const unsigned short* cp = (const unsigned short*)&c;
    const unsigned short* rp = (const unsigned short*)&rv;
    unsigned short o8[8];
#pragma unroll
    for (int e = 0; e < 8; ++e) {
      float v = h2f(cp[e]) + bias[n0 + hf + k * 8 + e];
      if (res) v += h2f(rp[e]);
      o8[e] = f2h(fmaxf(v, 0.f));
    }
    *(uint4*)(dst + k * 8) = *(uint4*)o8;
  }
}

// ---------------- head ------------------------
__global__ void head1_kernel(const unsigned short* __restrict__ H, float* __restrict__ part) {
  int b = blockIdx.x, ls = blockIdx.y, d = threadIdx.x;
  const unsigned short* p = H + ((size_t)(b * L_ + ls * 128)) * D_ + d;
  float sum = 0.f;
  for (int l = 0; l < 128; ++l) sum += h2f(p[(size_t)l * D_]);
  part[(b * 16 + ls) * D_ + d] = sum;
}

__global__ void head2_kernel(const float* __restrict__ part, const float* __restrict__ fcW,
                             const float* __restrict__ fcb, float* __restrict__ out) {
  int b = blockIdx.x, d = threadIdx.x;
  float sum = 0.f;
  for (int i = 0; i < 16; ++i) sum += part[(b * 16 + i) * D_ + d];
  __shared__ float meanv[D_];
  meanv[d] = sum * (1.0f / (float)L_);
  __syncthreads();
  if (d < 2) {
    float accv = fcb[d];
    for (int k = 0; k < D_; ++k) accv = fmaf(meanv[k], fcW[k * 2 + d], accv);
    out[b * 2 + d] = accv;
  }
}

extern "C" void kernel_launch(void* const* d_in, const int* in_sizes, int n_in,
                              void* d_out, int out_size, void* d_ws, size_t ws_size,
                              hipStream_t stream) {
  const float* x      = (const float*)d_in[0];
  const float* W_emb  = (const float*)d_in[1];
  const float* b_emb  = (const float*)d_in[2];
  const float* log_dt = (const float*)d_in[3];
  const float* logAre = (const float*)d_in[4];
  const float* Aim    = (const float*)d_in[5];
  const float* Cre    = (const float*)d_in[6];
  const float* Cim    = (const float*)d_in[7];
  const float* Dskip  = (const float*)d_in[8];
  const float* Wout   = (const float*)d_in[9];
  const float* bout   = (const float*)d_in[10];
  const float* gamma_ = (const float*)d_in[11];
  const float* beta_  = (const float*)d_in[12];
  const float* fW1    = (const float*)d_in[13];
  const float* fb1    = (const float*)d_in[14];
  const float* fW2    = (const float*)d_in[15];
  const float* fb2    = (const float*)d_in[16];
  const float* fcW    = (const float*)d_in[17];
  const float* fcb    = (const float*)d_in[18];
  float* outp = (float*)d_out;

  const size_t HSZ = (size_t)B_ * L_ * D_;   // 8388608
  float* WB     = (float*)d_ws;                          // 196608 f
  float* C2B    = WB + (size_t)NBLK_ * D_ * 128;         // 196608 f
  float* WLB    = C2B + (size_t)NBLK_ * D_ * 128;        // 196608 f
  unsigned short* H   = (unsigned short*)(WLB + (size_t)NBLK_ * D_ * N_ * 2);
  unsigned short* R   = H + HSZ;
  unsigned short* UT  = R + HSZ;
  unsigned short* GT  = UT + HSZ;
  unsigned short* Gbf = GT;     // FFN intermediate aliases GT (dead after layer 5)
  unsigned short* WT  = GT + HSZ;                        // 524288 us

  precompute_kernel<<<(NBLK_ * D_ * N_ + 255) / 256, 256, 0, stream>>>(
      log_dt, logAre, Aim, Cre, Cim, WB, C2B, WLB);
  wprep_kernel<<<128, 256, 0, stream>>>(Wout, fW1, fW2, WT);
  embed_kernel<<<(B_ * L_ * D_ + 255) / 256, 256, 0, stream>>>(x, W_emb, b_emb, H);
  trans_h_ut<<<1024, 256, 0, stream>>>(H, UT);

  const unsigned short* hin_t[6]  = {H, H, H, H, R, H};
  unsigned short*       hout_t[6] = {H, H, H, R, H, H};
  for (int i = 0; i < 6; ++i) {
    scan_fused<<<256, 512, 0, stream>>>(UT, WB, C2B, WLB, gamma_, beta_, Dskip, GT, i);
    gemm_gt<<<512, 256, 0, stream>>>(
        GT, WT + (size_t)i * 65536, bout + i * D_, hin_t[i], hout_t[i],
        (i < 5) ? UT : nullptr);
  }
  // feedforward of the FS4Ddeq block + skip from R
  gemm_ffn<<<512, 256, 0, stream>>>(H, WT + (size_t)6 * 65536, fb1, nullptr, Gbf);
  gemm_ffn<<<512, 256, 0, stream>>>(Gbf, WT + (size_t)7 * 65536, fb2, R, H);
  head1_kernel<<<dim3(16, 16), 256, 0, stream>>>(H, WB);
  head2_kernel<<<16, 256, 0, stream>>>(WB, fcW, fcb, outp);
}

// Round 12
// 541.504 us; speedup vs baseline: 3.2836x; 1.0467x over previous
//
#include <hip/hip_runtime.h>
#include <hip/hip_fp16.h>
#include <math.h>

#define B_ 16
#define L_ 2048
#define D_ 256
#define N_ 64
#define NBLK_ 6
#define LC_ 128
#define NC_ 16

typedef _Float16 half8 __attribute__((ext_vector_type(8)));
typedef float f32x4 __attribute__((ext_vector_type(4)));

__device__ __forceinline__ unsigned short f2h(float f) {
  _Float16 h = (_Float16)f;
  return *(unsigned short*)&h;
}
__device__ __forceinline__ float h2f(unsigned short u) {
  _Float16 h = *(_Float16*)&u;
  return (float)h;
}

// ---------------- precompute per-layer SSM params ----------------
__global__ void precompute_kernel(const float* __restrict__ log_dt,
                                  const float* __restrict__ logAre,
                                  const float* __restrict__ Aim,
                                  const float* __restrict__ Cre,
                                  const float* __restrict__ Cim,
                                  float* __restrict__ wbuf,
                                  float* __restrict__ c2buf,
                                  float* __restrict__ wlbuf) {
  int idx = blockIdx.x * blockDim.x + threadIdx.x;
  if (idx >= NBLK_ * D_ * N_) return;
  int blk = idx >> 14;
  int rem = idx & 16383;
  int d = rem >> 6;
  int n = rem & 63;
  float dt   = expf(log_dt[blk * D_ + d]);
  float are  = -expf(logAre[idx]);
  float aim  = Aim[idx];
  float dtar = dt * are, dtai = dt * aim;
  float er = expf(dtar);
  float wr = er * cosf(dtai);
  float wi = er * sinf(dtai);
  float inv = 1.0f / (are * are + aim * aim);
  float wm1r = wr - 1.0f;
  float br = (wm1r * are + wi * aim) * inv;
  float bi = (wi * are - wm1r * aim) * inv;
  float crv = Cre[idx], civ = Cim[idx];
  float c2r = 2.0f * (crv * br - civ * bi);
  float c2i = 2.0f * (crv * bi + civ * br);
  float eL = expf((float)LC_ * dtar);
  float angL = (float)LC_ * dtai;
  float* wb = wbuf + (size_t)((blk << 8) + d) * 128;
  wb[n] = wr; wb[64 + n] = wi;
  float* cb = c2buf + (size_t)((blk << 8) + d) * 128;
  cb[n] = c2r; cb[64 + n] = c2i;
  wlbuf[2 * idx] = eL * cosf(angL); wlbuf[2 * idx + 1] = eL * sinf(angL);
}

// ---------------- fused embedding + transpose: x -> H (fp16) and UT ----------
__global__ __launch_bounds__(256) void embed_trans(const float* __restrict__ x,
    const float* __restrict__ wemb, const float* __restrict__ bemb,
    unsigned short* __restrict__ H, unsigned short* __restrict__ UT) {
  __shared__ __align__(16) unsigned short lds[64][136];
  int bi = blockIdx.x;          // bc*4 + dq
  int bc = bi >> 2, dq = bi & 3;
  int b = bc >> 4, ch = bc & 15;
  int tid = threadIdx.x;
  int tau0 = tid >> 4;
  int dl = (tid & 15) << 2;
  float w4[4], b4[4];
#pragma unroll
  for (int i = 0; i < 4; ++i) {
    w4[i] = wemb[dq * 64 + dl + i];
    b4[i] = bemb[dq * 64 + dl + i];
  }
  for (int tt = 0; tt < 128; tt += 16) {
    int l = ch * 128 + tt + tau0;
    float xv = x[b * L_ + l];
    ushort4 hv;
    float v0 = fmaf(xv, w4[0], b4[0]);
    float v1 = fmaf(xv, w4[1], b4[1]);
    float v2 = fmaf(xv, w4[2], b4[2]);
    float v3 = fmaf(xv, w4[3], b4[3]);
    hv.x = f2h(v0); hv.y = f2h(v1); hv.z = f2h(v2); hv.w = f2h(v3);
    lds[dl + 0][tt + tau0] = hv.x;
    lds[dl + 1][tt + tau0] = hv.y;
    lds[dl + 2][tt + tau0] = hv.z;
    lds[dl + 3][tt + tau0] = hv.w;
    *(ushort4*)(H + ((size_t)(b * L_ + l)) * D_ + dq * 64 + dl) = hv;
  }
  __syncthreads();
  int r = tid >> 2, seg = (tid & 3) << 5;
  unsigned short* dst = UT + ((size_t)((dq * 64 + r) * 256 + bc)) * 128 + seg;
  const unsigned short* srow = &lds[r][seg];
  *(uint4*)(dst + 0)  = *(const uint4*)(srow + 0);
  *(uint4*)(dst + 8)  = *(const uint4*)(srow + 8);
  *(uint4*)(dst + 16) = *(const uint4*)(srow + 16);
  *(uint4*)(dst + 24) = *(const uint4*)(srow + 24);
}

// ---------------- fully-fused scan, 512 threads, register-resident A ---------
// One block per d. A-fragments (UT rows of this wave's m-tile) loaded ONCE from
// global into 16 half8 regs, in flight during phase-0 generation. Phases:
// 0: gen Fn(Bm1)/En(Bm2)/Kt/Sb in LDS.  1: SL = UT@Fn^T + Sb (0 barriers).
// 2: in-LDS chunk combine (pipelined) + Pb prefix.  Tn overwrites Bm1.
// 3: GT = gelu(UT@Tn^T + SL@En^T + Pb) (0 barriers), epi reuses SL.
__global__ __launch_bounds__(512) void scan_fused(
    const unsigned short* __restrict__ UT,
    const float* __restrict__ WB, const float* __restrict__ C2B,
    const float* __restrict__ WLB,
    const float* __restrict__ gamma_, const float* __restrict__ beta_,
    const float* __restrict__ dskip,
    unsigned short* __restrict__ GT, int blk) {
  __shared__ __align__(16) unsigned short SLl[256 * 136];   // 69632 B
  __shared__ __align__(16) unsigned short Bm1[128 * 136];   // 34816 B (Fn -> Tn)
  __shared__ __align__(16) unsigned short Bm2[128 * 136];   // 34816 B (En)
  __shared__ float wc[256];
  __shared__ float Kt[128];
  __shared__ float Pb[128];
  __shared__ float Sb[128];
  int d = blockIdx.x;
  int tid = threadIdx.x, lane = tid & 63, w = tid >> 6;   // w: 0..7
  int wm = (w & 3) << 6;    // 0,64,128,192
  int wn = (w >> 2) << 6;   // 0,64
  int cn = lane & 15, rq = lane >> 4;
  int ko = rq << 3;
  const unsigned short* Au = UT + (size_t)d * 256 * 128;

  // ---------- A-fragments: direct global loads, issued first ----------
  half8 afr[4][4];
#pragma unroll
  for (int kc2 = 0; kc2 < 4; ++kc2)
#pragma unroll
    for (int mf = 0; mf < 4; ++mf)
      afr[kc2][mf] = *(const half8*)(Au + (size_t)(wm + (mf << 4) + cn) * 128 + (kc2 << 5) + ko);

  // ---------- phase 0: generate Fn, En, Kt, Sb in LDS ----------
  if (tid < 128) wc[tid] = WB[(size_t)((blk << 8) + d) * 128 + tid];
  else if (tid < 256) wc[tid] = C2B[(size_t)((blk << 8) + d) * 128 + (tid - 128)];
  __syncthreads();
  int n = tid & 63;
  float gd = gamma_[blk * D_ + d], bd = beta_[blk * D_ + d], dsk = dskip[blk * D_ + d];
  {
    float wr = wc[n], wi = wc[64 + n];
    float c2r = wc[128 + n], c2i = wc[192 + n];
    int j0 = w << 4;            // wave w handles j = j0..j0+15
    float pr = 1.f, pi = 0.f, br = wr, bi = wi;
    int e = j0;
    while (e) {
      if (e & 1) { float tt = pr * br - pi * bi; pi = pr * bi + pi * br; pr = tt; }
      float t2 = br * br - bi * bi; bi = 2.f * br * bi; br = t2;
      e >>= 1;
    }
    for (int k2 = 0; k2 < 16; ++k2) {
      int j = j0 + k2;
      Bm1[n * 136 + (127 - j)]        = f2h(gd * pr);
      Bm1[(64 + n) * 136 + (127 - j)] = f2h(-gd * pi);
      float qr = pr * wr - pi * wi, qi = pr * wi + pi * wr;   // w^{j+1}
      Bm2[j * 136 + n]      = f2h(c2r * qr - c2i * qi);
      Bm2[j * 136 + 64 + n] = f2h(c2r * qi + c2i * qr);
      float kc = c2r * pr - c2i * pi;
#pragma unroll
      for (int off = 1; off < 64; off <<= 1) kc += __shfl_xor(kc, off);
      if (n == 0) Kt[j] = kc + (j == 0 ? dsk : 0.f);
      pr = qr; pi = qi;
    }
  }
  if (tid < 64) {
    const float* wlp = WLB + (((size_t)((blk << 8) + d)) * 64 + tid) * 2;
    float wlr = wlp[0], wli = wlp[1];
    float nr = wlr - 1.f, ni = wli;
    float dr2 = wc[tid] - 1.f, di = wc[64 + tid];
    float iv = 1.f / (dr2 * dr2 + di * di);
    Sb[tid]      = bd * ((nr * dr2 + ni * di) * iv);
    Sb[64 + tid] = bd * (-((ni * dr2 - nr * di) * iv));
  }
  __syncthreads();   // b1: Bm1/Bm2/Kt/Sb visible

  // ---------- phase 1: SL = UT @ Fn^T + Sb  (zero barriers) ----------
  {
    f32x4 acc[4][4];
#pragma unroll
    for (int a = 0; a < 4; ++a)
#pragma unroll
      for (int b2 = 0; b2 < 4; ++b2) acc[a][b2] = (f32x4){0.f, 0.f, 0.f, 0.f};
#pragma unroll
    for (int kc = 0; kc < 4; ++kc) {
      half8 bf4[4];
#pragma unroll
      for (int nf = 0; nf < 4; ++nf)
        bf4[nf] = *(const half8*)((const _Float16*)Bm1 + (wn + (nf << 4) + cn) * 136 + (kc << 5) + ko);
#pragma unroll
      for (int mf = 0; mf < 4; ++mf)
#pragma unroll
        for (int nf = 0; nf < 4; ++nf)
          acc[mf][nf] = __builtin_amdgcn_mfma_f32_16x16x32_f16(afr[kc][mf], bf4[nf], acc[mf][nf], 0, 0, 0);
    }
#pragma unroll
    for (int nf = 0; nf < 4; ++nf) {
      int nl = wn + (nf << 4) + cn;
      float sb = Sb[nl];
#pragma unroll
      for (int mf = 0; mf < 4; ++mf)
#pragma unroll
        for (int rr = 0; rr < 4; ++rr) {
          int row = wm + (mf << 4) + (rq << 2) + rr;
          SLl[row * 136 + nl] = f2h(acc[mf][nf][rr] + sb);
        }
    }
  }
  __syncthreads();   // b2: SL complete

  // ---------- Pb prefix (Kt written before phase 1; b2 passed) ----------
  if (tid < 128) {
    float ps = 0.f;
    for (int t2 = 0; t2 <= tid; ++t2) ps += Kt[t2];
    Pb[tid] = bd * ps;
  }
  // ---------- phase 2: exclusive chunk-state combine (pipelined) ----------
  for (int task = tid; task < 1024; task += 512) {
    int b = task >> 6, nn = task & 63;
    const float* wlp = WLB + (((size_t)((blk << 8) + d)) * 64 + nn) * 2;
    float wlr = wlp[0], wli = wlp[1];
    float Sr = 0.f, Sj = 0.f;
    int row0 = b << 4;
    float tr2 = h2f(SLl[row0 * 136 + nn]);
    float tj2 = h2f(SLl[row0 * 136 + 64 + nn]);
    for (int c = 0; c < NC_; ++c) {
      int row = row0 + c;
      float ntr = 0.f, ntj = 0.f;
      if (c < NC_ - 1) {
        ntr = h2f(SLl[(row + 1) * 136 + nn]);
        ntj = h2f(SLl[(row + 1) * 136 + 64 + nn]);
      }
      SLl[row * 136 + nn]      = f2h(Sr);
      SLl[row * 136 + 64 + nn] = f2h(Sj);
      float nSr = fmaf(wlr, Sr, fmaf(wli, Sj, tr2));
      Sj = fmaf(-wli, Sr, fmaf(wlr, Sj, tj2));
      Sr = nSr;
      tr2 = ntr; tj2 = ntj;
    }
  }
  __syncthreads();   // b3: combine done (Fn reads done at b2)

  // ---------- Tn generation into Bm1 ----------
  {
    int chunk = tid & 15, rg = tid >> 4;   // rg 0..31
#pragma unroll
    for (int it = 0; it < 4; ++it) {
      int trow = (it << 5) + rg;
      int tau0 = chunk << 3;
      unsigned short v[8];
#pragma unroll
      for (int i = 0; i < 8; ++i) {
        int tau = tau0 + i;
        v[i] = (tau <= trow) ? f2h(gd * Kt[trow - tau]) : (unsigned short)0;
      }
      *(uint4*)(Bm1 + (size_t)trow * 136 + tau0) = *(uint4*)v;
    }
  }
  __syncthreads();   // b4: Tn ready

  // ---------- phase 3: GT = gelu(UT@Tn^T + SL@En^T + Pb)  (zero barriers) ----
  {
    f32x4 acc[4][4];
#pragma unroll
    for (int a = 0; a < 4; ++a)
#pragma unroll
      for (int b2 = 0; b2 < 4; ++b2) acc[a][b2] = (f32x4){0.f, 0.f, 0.f, 0.f};
#pragma unroll
    for (int kb = 0; kb < 8; ++kb) {
      int kc = (kb & 3) << 5;
      half8 af[4], bf4[4];
      if (kb < 4) {
#pragma unroll
        for (int mf = 0; mf < 4; ++mf) af[mf] = afr[kb][mf];
#pragma unroll
        for (int nf = 0; nf < 4; ++nf)
          bf4[nf] = *(const half8*)((const _Float16*)Bm1 + (wn + (nf << 4) + cn) * 136 + kc + ko);
      } else {
#pragma unroll
        for (int mf = 0; mf < 4; ++mf)
          af[mf] = *(const half8*)((const _Float16*)SLl + (wm + (mf << 4) + cn) * 136 + kc + ko);
#pragma unroll
        for (int nf = 0; nf < 4; ++nf)
          bf4[nf] = *(const half8*)((const _Float16*)Bm2 + (wn + (nf << 4) + cn) * 136 + kc + ko);
      }
#pragma unroll
      for (int mf = 0; mf < 4; ++mf)
#pragma unroll
        for (int nf = 0; nf < 4; ++nf)
          acc[mf][nf] = __builtin_amdgcn_mfma_f32_16x16x32_f16(af[mf], bf4[nf], acc[mf][nf], 0, 0, 0);
    }
    __syncthreads();   // b5: all SLl A-reads done
    unsigned short* epi = SLl;
#pragma unroll
    for (int nf = 0; nf < 4; ++nf) {
      int nl = wn + (nf << 4) + cn;
      float pb2 = Pb[nl];
#pragma unroll
      for (int mf = 0; mf < 4; ++mf)
#pragma unroll
        for (int rr = 0; rr < 4; ++rr) {
          int ml = wm + (mf << 4) + (rq << 2) + rr;
          float xx = acc[mf][nf][rr] + pb2;
          float x3 = xx * xx * xx;
          float inner = 0.7978845608028654f * fmaf(0.044715f, x3, xx);
          float e = __expf(-2.f * fabsf(inner));
          float th = (1.f - e) / (1.f + e);
          th = copysignf(th, inner);
          epi[ml * 136 + nl] = f2h(0.5f * xx * (1.f + th));
        }
    }
    __syncthreads();   // b6: epi ready
    int mr = tid >> 1, hf = (tid & 1) << 6;
    size_t gb = ((size_t)d * 256 + mr) * 128 + hf;
#pragma unroll
    for (int k = 0; k < 8; ++k)
      *(uint4*)(GT + gb + k * 8) = *(const uint4*)&epi[mr * 136 + hf + k * 8];
  }
}

// ---------------- W prep: WT[w][n][k] = fp16(W_w[k][n]) ----------------------
__global__ void wprep_kernel(const float* __restrict__ Wout, const float* __restrict__ fW1,
                             const float* __restrict__ fW2, unsigned short* __restrict__ WT) {
  __shared__ float tile[64][65];
  int wv = blockIdx.x >> 4;
  int tk = (blockIdx.x >> 2) & 3;
  int tn = blockIdx.x & 3;
  const float* src = (wv < 6) ? (Wout + (size_t)wv * 65536) : (wv == 6 ? fW1 : fW2);
  int r = threadIdx.x >> 4;
  int c = (threadIdx.x & 15) << 2;
  for (int rr = 0; rr < 64; rr += 16) {
    float4 v = *(const float4*)(src + (size_t)(tk * 64 + r + rr) * 256 + tn * 64 + c);
    tile[r + rr][c] = v.x; tile[r + rr][c + 1] = v.y;
    tile[r + rr][c + 2] = v.z; tile[r + rr][c + 3] = v.w;
  }
  __syncthreads();
  for (int rr = 0; rr < 64; rr += 16) {
    int n = r + rr;
    ushort4 o;
    o.x = f2h(tile[c + 0][n]); o.y = f2h(tile[c + 1][n]);
    o.z = f2h(tile[c + 2][n]); o.w = f2h(tile[c + 3][n]);
    *(ushort4*)(WT + (size_t)wv * 65536 + (size_t)(tn * 64 + n) * 256 + tk * 64 + c) = o;
  }
}

// ---------------- projection GEMM: hout = GT^T@W + bias + res; ut = hout^T ---
__global__ __launch_bounds__(256, 2) void gemm_gt(const unsigned short* __restrict__ GT,
    const unsigned short* __restrict__ Wt, const float* __restrict__ bias,
    const unsigned short* __restrict__ res, unsigned short* __restrict__ hout,
    unsigned short* __restrict__ ut_next) {
  __shared__ __align__(16) unsigned short smem[18432];
  unsigned short* As = smem;
  unsigned short* Bs = smem + 9216;
  int tid = threadIdx.x;
  int bid = blockIdx.x;
  int bc = bid & 255;
  int m0 = bc * 128, n0 = (bid >> 8) << 7;
  int lane = tid & 63, w = tid >> 6;
  int wm = (w & 1) << 6, wn = (w >> 1) << 6;
  int rb = tid >> 3, cb = (tid & 7) << 3;
  int dr = tid >> 2, sg = (tid & 3) << 5;
  f32x4 acc[4][4];
#pragma unroll
  for (int mf = 0; mf < 4; ++mf)
#pragma unroll
    for (int nf = 0; nf < 4; ++nf) acc[mf][nf] = (f32x4){0.f, 0.f, 0.f, 0.f};

  uint4 gv[4], bv[4];
  {
    const uint4* grow = (const uint4*)(GT + ((size_t)(dr * 256 + bc)) * 128 + sg);
    gv[0] = grow[0]; gv[1] = grow[1]; gv[2] = grow[2]; gv[3] = grow[3];
#pragma unroll
    for (int rr = 0; rr < 4; ++rr)
      bv[rr] = *(const uint4*)(Wt + (size_t)(n0 + rb + rr * 32) * 256 + cb);
  }
  for (int kb = 0; kb < 4; ++kb) {
    __syncthreads();
    const unsigned short* pv = (const unsigned short*)gv;
#pragma unroll
    for (int i = 0; i < 32; ++i) As[(sg + i) * 72 + dr] = pv[i];
#pragma unroll
    for (int rr = 0; rr < 4; ++rr) *(uint4*)&Bs[(rb + rr * 32) * 72 + cb] = bv[rr];
    __syncthreads();
    if (kb < 3) {
      int k0 = (kb + 1) << 6;
      const uint4* grow = (const uint4*)(GT + ((size_t)((k0 + dr) * 256 + bc)) * 128 + sg);
      gv[0] = grow[0]; gv[1] = grow[1]; gv[2] = grow[2]; gv[3] = grow[3];
#pragma unroll
      for (int rr = 0; rr < 4; ++rr)
        bv[rr] = *(const uint4*)(Wt + (size_t)(n0 + rb + rr * 32) * 256 + k0 + cb);
    }
#pragma unroll
    for (int kw = 0; kw < 2; ++kw) {
      int ko = (kw << 5) + ((lane >> 4) << 3);
      half8 af[4], bfr[4];
#pragma unroll
      for (int mf = 0; mf < 4; ++mf)
        af[mf] = *(const half8*)&As[(wm + (mf << 4) + (lane & 15)) * 72 + ko];
#pragma unroll
      for (int nf = 0; nf < 4; ++nf)
        bfr[nf] = *(const half8*)&Bs[(wn + (nf << 4) + (lane & 15)) * 72 + ko];
#pragma unroll
      for (int mf = 0; mf < 4; ++mf)
#pragma unroll
        for (int nf = 0; nf < 4; ++nf)
          acc[mf][nf] = __builtin_amdgcn_mfma_f32_16x16x32_f16(af[mf], bfr[nf], acc[mf][nf], 0, 0, 0);
    }
  }
  int cn = lane & 15, rq = lane >> 4;
  __syncthreads();
  unsigned short* epi = smem;   // [128][136]
#pragma unroll
  for (int nf = 0; nf < 4; ++nf) {
    int nl = wn + (nf << 4) + cn;
    float bv2 = bias[n0 + nl];
#pragma unroll
    for (int mf = 0; mf < 4; ++mf)
#pragma unroll
      for (int r = 0; r < 4; ++r) {
        int ml = wm + (mf << 4) + (rq << 2) + r;
        float v = acc[mf][nf][r] + bv2 + h2f(res[(size_t)(m0 + ml) * 256 + n0 + nl]);
        epi[ml * 136 + nl] = f2h(v);
      }
  }
  __syncthreads();
  {
    int mr = tid >> 1, hf = (tid & 1) << 6;
    unsigned short* dst = hout + (size_t)(m0 + mr) * 256 + n0 + hf;
    const unsigned short* srow = epi + mr * 136 + hf;
#pragma unroll
    for (int k = 0; k < 8; ++k) *(uint4*)(dst + k * 8) = *(const uint4*)(srow + k * 8);
  }
  if (ut_next) {
    int nl = tid >> 1, h2 = (tid & 1) << 6;
    unsigned short* dst = ut_next + ((size_t)(n0 + nl) * 256 + bc) * 128 + h2;
#pragma unroll
    for (int k = 0; k < 8; ++k) {
      unsigned short v8[8];
#pragma unroll
      for (int e = 0; e < 8; ++e) v8[e] = epi[(h2 + k * 8 + e) * 136 + nl];
      *(uint4*)(dst + k * 8) = *(uint4*)v8;
    }
  }
}

// ---------------- FFN GEMM: out = relu(A@W + b [+ res]), XCD-paired grid -----
__global__ __launch_bounds__(256, 2) void gemm_ffn(const unsigned short* __restrict__ A,
    const unsigned short* __restrict__ Wt, const float* __restrict__ bias,
    const unsigned short* __restrict__ res, unsigned short* __restrict__ outp) {
  __shared__ __align__(16) unsigned short smem[18432];
  unsigned short* As = smem;
  unsigned short* Bs = smem + 9216;
  int tid = threadIdx.x;
  int bid = blockIdx.x;
  int m0 = (bid & 255) << 7, n0 = (bid >> 8) << 7;
  int lane = tid & 63, w = tid >> 6;
  int wm = (w & 1) << 6, wn = (w >> 1) << 6;
  int r0 = tid >> 3;
  int c0 = (tid & 7) << 3;
  f32x4 acc[4][4];
#pragma unroll
  for (int mf = 0; mf < 4; ++mf)
#pragma unroll
    for (int nf = 0; nf < 4; ++nf) acc[mf][nf] = (f32x4){0.f, 0.f, 0.f, 0.f};

  uint4 av[4], bv[4];
#pragma unroll
  for (int rr = 0; rr < 4; ++rr) {
    int r = r0 + rr * 32;
    av[rr] = *(const uint4*)(A + (size_t)(m0 + r) * 256 + c0);
    bv[rr] = *(const uint4*)(Wt + (size_t)(n0 + r) * 256 + c0);
  }
  for (int kb = 0; kb < 4; ++kb) {
    __syncthreads();
#pragma unroll
    for (int rr = 0; rr < 4; ++rr) {
      int r = r0 + rr * 32;
      *(uint4*)&As[r * 72 + c0] = av[rr];
      *(uint4*)&Bs[r * 72 + c0] = bv[rr];
    }
    __syncthreads();
    if (kb < 3) {
      int k0 = (kb + 1) << 6;
#pragma unroll
      for (int rr = 0; rr < 4; ++rr) {
        int r = r0 + rr * 32;
        av[rr] = *(const uint4*)(A + (size_t)(m0 + r) * 256 + k0 + c0);
        bv[rr] = *(const uint4*)(Wt + (size_t)(n0 + r) * 256 + k0 + c0);
      }
    }
#pragma unroll
    for (int kw = 0; kw < 2; ++kw) {
      int ko = (kw << 5) + ((lane >> 4) << 3);
      half8 af[4], bfr[4];
#pragma unroll
      for (int mf = 0; mf < 4; ++mf)
        af[mf] = *(const half8*)&As[(wm + (mf << 4) + (lane & 15)) * 72 + ko];
#pragma unroll
      for (int nf = 0; nf < 4; ++nf)
        bfr[nf] = *(const half8*)&Bs[(wn + (nf << 4) + (lane & 15)) * 72 + ko];
#pragma unroll
      for (int mf = 0; mf < 4; ++mf)
#pragma unroll
        for (int nf = 0; nf < 4; ++nf)
          acc[mf][nf] = __builtin_amdgcn_mfma_f32_16x16x32_f16(af[mf], bfr[nf], acc[mf][nf], 0, 0, 0);
    }
  }
  int cn = lane & 15, rq = lane >> 4;
  __syncthreads();
  unsigned short* epi = smem;
#pragma unroll
  for (int nf = 0; nf < 4; ++nf) {
    int nl = wn + (nf << 4) + cn;
#pragma unroll
    for (int r = 0; r < 4; ++r) {
#pragma unroll
      for (int mf = 0; mf < 4; ++mf) {
        int ml = wm + (mf << 4) + (rq << 2) + r;
        epi[ml * 136 + nl] = f2h(acc[mf][nf][r]);
      }
    }
  }
  __syncthreads();
  int mr = tid >> 1, hf = (tid & 1) << 6;
  unsigned short* dst = outp + (size_t)(m0 + mr) * 256 + n0 + hf;
#pragma unroll
  for (int k = 0; k < 8; ++k) {
    uint4 c = *(const uint4*)&epi[mr * 136 + hf + k * 8];
    uint4 rv = (uint4){0, 0, 0, 0};
    if (res) rv = *(const uint4*)(res + (size_t)(m0 + mr) * 256 + n0 + hf + k * 8);
    const unsigned short* cp = (const unsigned short*)&c;
    const unsigned short* rp = (const unsigned short*)&rv;
    unsigned short o8[8];
#pragma unroll
    for (int e = 0; e < 8; ++e) {
      float v = h2f(cp[e]) + bias[n0 + hf + k * 8 + e];
      if (res) v += h2f(rp[e]);
      o8[e] = f2h(fmaxf(v, 0.f));
    }
    *(uint4*)(dst + k * 8) = *(uint4*)o8;
  }
}

// ---------------- head ------------------------
__global__ void head1_kernel(const unsigned short* __restrict__ H, float* __restrict__ part) {
  int b = blockIdx.x, ls = blockIdx.y, d = threadIdx.x;
  const unsigned short* p = H + ((size_t)(b * L_ + ls * 128)) * D_ + d;
  float sum = 0.f;
  for (int l = 0; l < 128; ++l) sum += h2f(p[(size_t)l * D_]);
  part[(b * 16 + ls) * D_ + d] = sum;
}

__global__ void head2_kernel(const float* __restrict__ part, const float* __restrict__ fcW,
                             const float* __restrict__ fcb, float* __restrict__ out) {
  int b = blockIdx.x, d = threadIdx.x;
  float sum = 0.f;
  for (int i = 0; i < 16; ++i) sum += part[(b * 16 + i) * D_ + d];
  __shared__ float meanv[D_];
  meanv[d] = sum * (1.0f / (float)L_);
  __syncthreads();
  if (d < 2) {
    float accv = fcb[d];
    for (int k = 0; k < D_; ++k) accv = fmaf(meanv[k], fcW[k * 2 + d], accv);
    out[b * 2 + d] = accv;
  }
}

extern "C" void kernel_launch(void* const* d_in, const int* in_sizes, int n_in,
                              void* d_out, int out_size, void* d_ws, size_t ws_size,
                              hipStream_t stream) {
  const float* x      = (const float*)d_in[0];
  const float* W_emb  = (const float*)d_in[1];
  const float* b_emb  = (const float*)d_in[2];
  const float* log_dt = (const float*)d_in[3];
  const float* logAre = (const float*)d_in[4];
  const float* Aim    = (const float*)d_in[5];
  const float* Cre    = (const float*)d_in[6];
  const float* Cim    = (const float*)d_in[7];
  const float* Dskip  = (const float*)d_in[8];
  const float* Wout   = (const float*)d_in[9];
  const float* bout   = (const float*)d_in[10];
  const float* gamma_ = (const float*)d_in[11];
  const float* beta_  = (const float*)d_in[12];
  const float* fW1    = (const float*)d_in[13];
  const float* fb1    = (const float*)d_in[14];
  const float* fW2    = (const float*)d_in[15];
  const float* fb2    = (const float*)d_in[16];
  const float* fcW    = (const float*)d_in[17];
  const float* fcb    = (const float*)d_in[18];
  float* outp = (float*)d_out;

  const size_t HSZ = (size_t)B_ * L_ * D_;   // 8388608
  float* WB     = (float*)d_ws;                          // 196608 f
  float* C2B    = WB + (size_t)NBLK_ * D_ * 128;         // 196608 f
  float* WLB    = C2B + (size_t)NBLK_ * D_ * 128;        // 196608 f
  unsigned short* H   = (unsigned short*)(WLB + (size_t)NBLK_ * D_ * N_ * 2);
  unsigned short* R   = H + HSZ;
  unsigned short* UT  = R + HSZ;
  unsigned short* GT  = UT + HSZ;
  unsigned short* Gbf = GT;     // FFN intermediate aliases GT (dead after layer 5)
  unsigned short* WT  = GT + HSZ;                        // 524288 us

  precompute_kernel<<<(NBLK_ * D_ * N_ + 255) / 256, 256, 0, stream>>>(
      log_dt, logAre, Aim, Cre, Cim, WB, C2B, WLB);
  wprep_kernel<<<128, 256, 0, stream>>>(Wout, fW1, fW2, WT);
  embed_trans<<<1024, 256, 0, stream>>>(x, W_emb, b_emb, H, UT);

  const unsigned short* hin_t[6]  = {H, H, H, H, R, H};
  unsigned short*       hout_t[6] = {H, H, H, R, H, H};
  for (int i = 0; i < 6; ++i) {
    scan_fused<<<256, 512, 0, stream>>>(UT, WB, C2B, WLB, gamma_, beta_, Dskip, GT, i);
    gemm_gt<<<512, 256, 0, stream>>>(
        GT, WT + (size_t)i * 65536, bout + i * D_, hin_t[i], hout_t[i],
        (i < 5) ? UT : nullptr);
  }
  // feedforward of the FS4Ddeq block + skip from R
  gemm_ffn<<<512, 256, 0, stream>>>(H, WT + (size_t)6 * 65536, fb1, nullptr, Gbf);
  gemm_ffn<<<512, 256, 0, stream>>>(Gbf, WT + (size_t)7 * 65536, fb2, R, H);
  head1_kernel<<<dim3(16, 16), 256, 0, stream>>>(H, WB);
  head2_kernel<<<16, 256, 0, stream>>>(WB, fcW, fcb, outp);
}